// Round 20
// baseline (325.391 us; speedup 1.0000x reference)
//
#include <hip/hip_runtime.h>
#include <cmath>

#define PARTITIONABLE 1

// ---------------------------------------------------------------------------
// Problem constants (B=8, S=32 -> N=1025, C=512, NH=8, D=64)
// ---------------------------------------------------------------------------
constexpr int B_ = 8;
constexpr int N_ = 1025;
constexpr int C_ = 512;
constexpr int NH_ = 8;
constexpr int D_ = 64;
constexpr int K3_ = 1536;   // 3*C
constexpr int F_ = 2048;    // 4*C
constexpr int ROWS_ = B_ * N_;  // 8200
constexpr int NXCD_ = 8;
constexpr int WCONV_BLKS_ = (K3_ * C_ + C_ * C_ + F_ * C_ + C_ * F_) / 1024;  // 3072

// ---------------------------------------------------------------------------
// Workspace byte offsets — round-2-proven envelope [0, ~118.5MB)
// ---------------------------------------------------------------------------
constexpr size_t BYTE_XN      = 0;              // xn f32            16,793,600
constexpr size_t BYTE_QKVBF   = 16793600;       // qkv bf16          25,190,400
constexpr size_t BYTE_XNBF    = 41984000;       // xn bf16            8,396,800
constexpr size_t BYTE_HBUF    = 16793600;       // h bf16 (aliases qkv_bf+xn_bf)
constexpr size_t BYTE_WTAIL   = 60882944;       // bf16 weights       6,291,456
constexpr size_t BYTE_ATTNBF  = 67174400;       // attn out bf16      8,396,800
constexpr size_t BYTE_X1NBF   = 75571200;       // ln2 out bf16       8,396,800
constexpr size_t BYTE_XO      = 83968000;       // xo f32            16,793,600
constexpr size_t BYTE_X1      = 100761600;      // kb+vb (attn) then x1 f32  16,793,600
constexpr size_t PLAN_BYTE    = 117555200;      // plan scratch ~0.9 MB

typedef unsigned short u16;
typedef __attribute__((ext_vector_type(4))) unsigned short u16x4;
typedef __attribute__((ext_vector_type(8))) short bf16x8;
typedef __attribute__((ext_vector_type(4))) float f32x4;

__device__ inline u16 f2bf(float f) {
  unsigned u = __float_as_uint(f);
  u = (u + 0x7FFFu + ((u >> 16) & 1u)) >> 16;
  return (u16)u;
}
__device__ inline float bf2f(u16 u) { return __uint_as_float(((unsigned)u) << 16); }

// Bijective XCD-aware block remap: each XCD gets a contiguous logical chunk.
__device__ inline int xcd_swz(int bid, int nwg) {
  const int xcd = bid % NXCD_, i = bid / NXCD_;
  const int q = nwg / NXCD_, r = nwg % NXCD_;
  const int base = (xcd < r) ? xcd * (q + 1) : r * (q + 1) + (xcd - r) * q;
  return base + i;
}

// async global->LDS, 16B per lane (lds dst must be wave-uniform base)
__device__ inline void gload_lds16(const void* g, void* l) {
  __builtin_amdgcn_global_load_lds(
      (const __attribute__((address_space(1))) void*)g,
      (__attribute__((address_space(3))) void*)l, 16, 0, 0);
}

// ---------------------------------------------------------------------------
// Fused LN1 + all-weight bf16 conversion (independent work, one launch).
// Blocks [0, ROWS_): LayerNorm row; blocks [ROWS_, ROWS_+3072): weight conv.
// ---------------------------------------------------------------------------
__global__ __launch_bounds__(256) void ln_wconv_kernel(
    const float* __restrict__ x, const float* __restrict__ w,
    const float* __restrict__ b, float* __restrict__ of, u16* __restrict__ ob,
    const float* __restrict__ w0, const float* __restrict__ w1,
    const float* __restrict__ w2, const float* __restrict__ w3,
    u16* __restrict__ o0, u16* __restrict__ o1,
    u16* __restrict__ o2, u16* __restrict__ o3) {
  __shared__ float red[4];
  if (blockIdx.x >= ROWS_) {
    constexpr int n0 = K3_ * C_, n1 = C_ * C_, n2 = F_ * C_;
    const int idx4 = ((blockIdx.x - ROWS_) * 256 + threadIdx.x) * 4;
    const float* src;
    u16* dst;
    int off;
    if (idx4 < n0) { src = w0; dst = o0; off = idx4; }
    else if (idx4 < n0 + n1) { src = w1; dst = o1; off = idx4 - n0; }
    else if (idx4 < n0 + n1 + n2) { src = w2; dst = o2; off = idx4 - n0 - n1; }
    else { src = w3; dst = o3; off = idx4 - n0 - n1 - n2; }
    const float4 v = *(const float4*)(src + off);
    u16x4 r;
    r.x = f2bf(v.x); r.y = f2bf(v.y); r.z = f2bf(v.z); r.w = f2bf(v.w);
    *(u16x4*)(dst + off) = r;
    return;
  }
  const int r = blockIdx.x;
  const int t = threadIdx.x;
  const float* xr = x + (size_t)r * C_;
  float v0 = xr[t], v1 = xr[t + 256];
  float s = v0 + v1;
#pragma unroll
  for (int o = 32; o; o >>= 1) s += __shfl_down(s, o);
  if ((t & 63) == 0) red[t >> 6] = s;
  __syncthreads();
  const float mean = (red[0] + red[1] + red[2] + red[3]) * (1.0f / 512.0f);
  __syncthreads();
  const float d0 = v0 - mean, d1 = v1 - mean;
  float q = d0 * d0 + d1 * d1;
#pragma unroll
  for (int o = 32; o; o >>= 1) q += __shfl_down(q, o);
  if ((t & 63) == 0) red[t >> 6] = q;
  __syncthreads();
  const float var = (red[0] + red[1] + red[2] + red[3]) * (1.0f / 512.0f);
  const float inv = 1.0f / sqrtf(var + 1e-5f);
  const float r0 = d0 * inv * w[t] + b[t];
  const float r1 = d1 * inv * w[t + 256] + b[t + 256];
  of[(size_t)r * C_ + t] = r0;
  of[(size_t)r * C_ + t + 256] = r1;
  ob[(size_t)r * C_ + t] = f2bf(r0);
  ob[(size_t)r * C_ + t + 256] = f2bf(r1);
}

// ---------------------------------------------------------------------------
// bf16 MFMA GEMM: out[M,N] = A[M,K](bf16) @ W[N,K](bf16)^T (+bias)(+gelu)(+res)
// 128xBN tile (BN=128 or 64), BK=64, 4 waves (2x2), 64x(BN/2) per wave.
// Double-buffered LDS + counted-vmcnt pipeline (T3+T4).
// BN=128 for large-N GEMMs (QKV/FC1); BN=64 ONLY for N=512 outputs.
// PLANQ0 (QKV): guest blocks run plan_q0 verbatim (bit-exact relocation).
// SMAX (proj): guest blocks run plan_softmax verbatim (bit-exact relocation).
// ---------------------------------------------------------------------------
template <int BN, int ACT, bool RES, bool OUTBF, bool QSCALE, bool PLANQ0, bool SMAX>
__global__ __launch_bounds__(256) void gemm_bf_kernel(
    const u16* __restrict__ A, const u16* __restrict__ W,
    const float* __restrict__ bias, const float* __restrict__ resid,
    void* __restrict__ outp, int M, int K, int Nout, int ngemm,
    const float* __restrict__ xnf, const float* __restrict__ qkvwf,
    double* __restrict__ q0o,
    const double* __restrict__ lgtp, double* __restrict__ mxzp) {
  constexpr int WN = BN / 2;       // wave cols: 64 or 32
  constexpr int NJ = WN / 16;      // j-tiles: 4 or 2
  constexpr int BPW = (BN / 8) / 4;  // B chunks per wave: 4 or 2
  __shared__ alignas(16) u16 As[2][128][64];
  __shared__ alignas(16) u16 Bs[2][BN][64];
  if (PLANQ0 && (int)blockIdx.x >= ngemm) {
    const int idx = ((int)blockIdx.x - ngemm) * 256 + threadIdx.x;
    const int b = idx >> 9, hd = idx & 511;
    const float* xr = xnf + (size_t)(b * N_) * C_;
    const float* wr = qkvwf + (size_t)hd * C_;
    double s = 0.0;
    for (int c = 0; c < C_; c += 4) {
      const float4 xv = *(const float4*)(xr + c);
      const float4 wv = *(const float4*)(wr + c);
      s += (double)xv.x * (double)wv.x;
      s += (double)xv.y * (double)wv.y;
      s += (double)xv.z * (double)wv.z;
      s += (double)xv.w * (double)wv.w;
    }
    q0o[idx] = s * 0.125;
    return;
  }
  if (SMAX && (int)blockIdx.x >= ngemm) {
    // plan_softmax body, verbatim (bit-exact relocation)
    __shared__ double red[4];
    const int bh = (int)blockIdx.x - ngemm;
    const int t = threadIdx.x;
    const double* row = lgtp + (size_t)bh * N_;
    double m = -1e300;
    for (int i = t; i < N_; i += 256) m = fmax(m, row[i]);
#pragma unroll
    for (int o = 32; o; o >>= 1) m = fmax(m, __shfl_down(m, o));
    if ((t & 63) == 0) red[t >> 6] = m;
    __syncthreads();
    const double mx = fmax(fmax(red[0], red[1]), fmax(red[2], red[3]));
    __syncthreads();
    double z = 0.0;
    for (int i = t; i < N_; i += 256) z += exp(row[i] - mx);
#pragma unroll
    for (int o = 32; o; o >>= 1) z += __shfl_down(z, o);
    if ((t & 63) == 0) red[t >> 6] = z;
    __syncthreads();
    if (t == 0) {
      mxzp[bh] = mx;
      mxzp[64 + bh] = red[0] + red[1] + red[2] + red[3];
    }
    return;
  }
  const int tid = threadIdx.x;
  const int ny = Nout / BN;
  const int l = xcd_swz(blockIdx.x, ngemm);
  const int m0 = (l / ny) * 128, n0 = (l % ny) * BN;
  const int wave = tid >> 6, lane = tid & 63;
  const int wr = wave >> 1, wc = wave & 1;
  const int lrow = lane & 15, lgrp = lane >> 4;
  const int srow = lane >> 3;                              // row within chunk
  const int soff = (16 * (lane & 7)) ^ (16 * srow);        // swizzled src byte
  const int nk = K >> 6;

  auto stage = [&](int k0, int bufi) {
#pragma unroll
    for (int c = 0; c < 4; ++c) {
      const int q = wave * 4 + c;
      const int row = q * 8 + srow;
      int gm = m0 + row;
      if (gm >= M) gm = M - 1;
      gload_lds16((const char*)(A + (size_t)gm * K + k0) + soff,
                  (char*)&As[bufi][0][0] + (q << 10));
    }
#pragma unroll
    for (int c = 0; c < BPW; ++c) {
      const int q = wave * BPW + c;
      const int row = q * 8 + srow;
      gload_lds16((const char*)(W + (size_t)(n0 + row) * K + k0) + soff,
                  (char*)&Bs[bufi][0][0] + (q << 10));
    }
  };

  f32x4 acc[4][NJ] = {};
  stage(0, 0);
  int buf = 0;
  for (int t = 0; t < nk; ++t) {
    if (t + 1 < nk) {
      stage((t + 1) << 6, buf ^ 1);
      // outstanding = 2*(4+BPW); retire the oldest (4+BPW) = tile t
      if constexpr (BN == 128) asm volatile("s_waitcnt vmcnt(8)" ::: "memory");
      else                     asm volatile("s_waitcnt vmcnt(6)" ::: "memory");
    } else {
      asm volatile("s_waitcnt vmcnt(0)" ::: "memory");
    }
    __builtin_amdgcn_sched_barrier(0);
    __builtin_amdgcn_s_barrier();
    const char* asb = (const char*)&As[buf][0][0];
    const char* bsb = (const char*)&Bs[buf][0][0];
    __builtin_amdgcn_s_setprio(1);
#pragma unroll
    for (int ch = 0; ch < 2; ++ch) {
      bf16x8 af[4], bfv[NJ];
#pragma unroll
      for (int i = 0; i < 4; ++i) {
        const int ra = wr * 64 + i * 16 + lrow;
        const int cb = ch * 64 + lgrp * 16;
        af[i] = *(const bf16x8*)(asb + (ra << 7) + (cb ^ ((ra & 7) << 4)));
      }
#pragma unroll
      for (int j = 0; j < NJ; ++j) {
        const int rb = wc * WN + j * 16 + lrow;
        const int cb = ch * 64 + lgrp * 16;
        bfv[j] = *(const bf16x8*)(bsb + (rb << 7) + (cb ^ ((rb & 7) << 4)));
      }
#pragma unroll
      for (int i = 0; i < 4; ++i)
#pragma unroll
        for (int j = 0; j < NJ; ++j)
          acc[i][j] = __builtin_amdgcn_mfma_f32_16x16x32_bf16(af[i], bfv[j], acc[i][j], 0, 0, 0);
    }
    __builtin_amdgcn_s_setprio(0);
    asm volatile("s_waitcnt lgkmcnt(0)" ::: "memory");
    __builtin_amdgcn_sched_barrier(0);
    __builtin_amdgcn_s_barrier();
    buf ^= 1;
  }
#pragma unroll
  for (int i = 0; i < 4; ++i) {
#pragma unroll
    for (int j = 0; j < NJ; ++j) {
#pragma unroll
      for (int reg = 0; reg < 4; ++reg) {
        const int gm = m0 + wr * 64 + i * 16 + lgrp * 4 + reg;
        if (gm >= M) continue;
        const int gn = n0 + wc * WN + j * 16 + lrow;
        float v = acc[i][j][reg];
        if (bias) v += bias[gn];
        if (ACT == 1) v = 0.5f * v * (1.0f + erff(v * 0.70710678118654752440f));
        if (QSCALE) { if (gn < 512) v *= 0.125f; }
        if (RES) v += resid[(size_t)gm * Nout + gn];
        if (OUTBF) ((u16*)outp)[(size_t)gm * Nout + gn] = f2bf(v);
        else       ((float*)outp)[(size_t)gm * Nout + gn] = v;
      }
    }
  }
}

// ---------------------------------------------------------------------------
// Pack dense K [b][h][1024][64] and V^T [b][h][64][1024] from qkv_bf.
// 1D grid (blocks independent -> order-free flatten). Blocks >= npack run the
// plan_u body verbatim (bit-exact relocation), overlapping the pack.
// ---------------------------------------------------------------------------
__global__ __launch_bounds__(256) void pack_kv_kernel(const u16* __restrict__ qkvbf,
                                                      u16* __restrict__ kb,
                                                      u16* __restrict__ vb,
                                                      const float* __restrict__ qkvwf,
                                                      const double* __restrict__ q0,
                                                      double* __restrict__ u,
                                                      int npack) {
  if ((int)blockIdx.x >= npack) {
    const int idx = ((int)blockIdx.x - npack) * 256 + threadIdx.x;
    const int b = idx >> 12, h = (idx >> 9) & 7, c = idx & 511;
    double s = 0.0;
    for (int d = 0; d < D_; ++d)
      s += q0[b * 512 + h * 64 + d] * (double)qkvwf[(size_t)(512 + h * 64 + d) * C_ + c];
    u[idx] = s;
    return;
  }
  const int tile = blockIdx.x & 15, h = (blockIdx.x >> 4) & 7, b = (int)blockIdx.x >> 7;
  const int t = threadIdx.x;
  __shared__ u16 Vt[64][72];
  const int krow = tile * 64 + (t >> 2);
  const int dseg = (t & 3) * 16;
  const u16* p = qkvbf + (size_t)(b * N_ + krow) * K3_ + 512 + h * D_ + dseg;
  const bf16x8 k0 = *(const bf16x8*)p;
  const bf16x8 k1 = *(const bf16x8*)(p + 8);
  u16* kp = kb + ((size_t)(b * NH_ + h) * 1024 + krow) * 64 + dseg;
  *(bf16x8*)kp = k0;
  *(bf16x8*)(kp + 8) = k1;
  const bf16x8 v0 = *(const bf16x8*)(p + 512);
  const bf16x8 v1 = *(const bf16x8*)(p + 520);
  *(bf16x8*)(&Vt[t >> 2][dseg]) = v0;
  *(bf16x8*)(&Vt[t >> 2][dseg + 8]) = v1;
  __syncthreads();
  const int d = t >> 2, kseg = (t & 3) * 16;
  bf16x8 o0, o1;
#pragma unroll
  for (int i = 0; i < 8; ++i) o0[i] = (short)Vt[kseg + i][d];
#pragma unroll
  for (int i = 0; i < 8; ++i) o1[i] = (short)Vt[kseg + 8 + i][d];
  u16* vp = vb + ((size_t)(b * NH_ + h) * 64 + d) * 1024 + tile * 64 + kseg;
  *(bf16x8*)vp = o0;
  *(bf16x8*)(vp + 8) = o1;
}

// ---------------------------------------------------------------------------
// MFMA flash attention v11 + fused plan_logit guest blocks (r19: heads split
// across threads — each thread computes 4 heads for one row, halving the
// serial f64 chain; per-head c-loop order unchanged -> bit-exact. 48 guests
// (6/batch), hg = t/192 wave-uniform -> LDS reads stay broadcast).
// attn: 704 blocks, LDS 51.5KB, 3 blocks/CU; 704+48=752 <= 768 single fill.
// ---------------------------------------------------------------------------
__global__ __launch_bounds__(384) void attn_mfma_kernel(
    const u16* __restrict__ qkvbf, const u16* __restrict__ kb,
    const u16* __restrict__ vb, const float* __restrict__ rpb,
    u16* __restrict__ attnout,
    const float* __restrict__ xnf, const double* __restrict__ uu,
    double* __restrict__ lgt, int nattn) {
  __shared__ alignas(16) u16 Ks[2][64][64];   // 16KB, XOR-swizzled storage
  __shared__ alignas(16) u16 Vs[2][64][64];   // 16KB, XOR-swizzled storage
  __shared__ alignas(16) u16 Pl[6][16][74];   // 14.2KB; stride 74 breaks conflicts
  __shared__ u16 tab[36 * 63];                // 4.5KB bf16 bias table
  if ((int)blockIdx.x >= nattn) {
    // plan_logit guest: 6 blocks/batch; thread = (row rloc, head-group hg)
    double* ul = (double*)&Ks[0][0][0];       // 4096 f64 = 32KB (aliases Ks)
    const int lb = (int)blockIdx.x - nattn;   // [0, 48)
    const int b = lb / 6, part = lb % 6;
    for (int i = threadIdx.x; i < 4096; i += 384)
      ul[i] = uu[(size_t)b * 4096 + i];
    __syncthreads();
    const int rloc = threadIdx.x % 192;
    const int hg = threadIdx.x / 192;         // 0 or 1 (wave-uniform)
    const int m = part * 192 + rloc;
    if (m >= N_) return;
    const float* xr = xnf + (size_t)(b * N_ + m) * C_;
    const double* ulh = ul + hg * 4 * 512;
    double s[4] = {};
    for (int c = 0; c < C_; c += 4) {
      const float4 xv = *(const float4*)(xr + c);
#pragma unroll
      for (int hh = 0; hh < 4; ++hh) {
        s[hh] += (double)xv.x * ulh[hh * 512 + c];
        s[hh] += (double)xv.y * ulh[hh * 512 + c + 1];
        s[hh] += (double)xv.z * ulh[hh * 512 + c + 2];
        s[hh] += (double)xv.w * ulh[hh * 512 + c + 3];
      }
    }
#pragma unroll
    for (int hh = 0; hh < 4; ++hh)
      lgt[(size_t)(b * 8 + hg * 4 + hh) * N_ + m] = s[hh];
    return;
  }
  const int l = xcd_swz(blockIdx.x, nattn);  // logical = (b*8+h)*11 + qt
  const int qt = l % 11;
  const int bh = l / 11;
  const int h = bh & 7, b = bh >> 3;
  const int wave = threadIdx.x >> 6, lane = threadIdx.x & 63;
  const int lrow = lane & 15, lgrp = lane >> 4;
  const int qblk = qt * 96;
  const int qbase = qblk + wave * 16;

  const u16* kpan = kb + (size_t)(b * NH_ + h) * 1024 * 64;
  const u16* vpan = vb + (size_t)(b * NH_ + h) * 64 * 1024;

  // ---- issue async stage of tile 0 (waves 0-3: K, waves 4-5: V) ----
  if (wave < 4) {
#pragma unroll
    for (int c = 0; c < 2; ++c) {
      const int q = wave * 2 + c;
      const int Y = (q << 10) | (lane << 4);
      const int Ys = Y ^ (((Y >> 7) & 7) << 4);
      gload_lds16((const char*)kpan + Ys, (char*)&Ks[0][0][0] + (q << 10));
    }
  } else {
#pragma unroll
    for (int c = 0; c < 4; ++c) {
      const int q = (wave - 4) * 4 + c;
      const int Y = (q << 10) | (lane << 4);
      const int Ys = Y ^ (((Y >> 7) & 7) << 4);
      const int row = Y >> 7;
      gload_lds16((const char*)vpan + (size_t)row * 2048 + (Ys & 127),
                  (char*)&Vs[0][0][0] + (q << 10));
    }
  }

  // ---- stage rpb sub-table (all threads; bf16) ----
  const int qimin = max(qblk - 1, 0);
  const int qimax = min(qblk + 94, 1023);
  const int qymin = qimin >> 5;
  const int qymax = qimax >> 5;
  const int nrows = qymax - qymin + 32;   // dy in [qymin-31, qymax]  (<=36)
  for (int i = threadIdx.x; i < nrows * 63; i += 384)
    tab[i] = f2bf(rpb[(size_t)(qymin * 63 + i) * NH_ + h]);

  u16 (*pl)[74] = Pl[wave];

  // Q fragments (pre-scaled by 1/8 in the QKV GEMM epilogue)
  bf16x8 qf[2];
  {
    const int qrow = min(qbase + lrow, N_ - 1);
    const u16* qp = qkvbf + (size_t)(b * N_ + qrow) * K3_ + h * D_;
    qf[0] = *(const bf16x8*)(qp + lgrp * 8);
    qf[1] = *(const bf16x8*)(qp + 32 + lgrp * 8);
  }

  const float bias0 = rpb[h];

  // Per-owned-q-row (C-layout rows lgrp*4+reg) bias table anchors
  int AlocR[4];
  bool qclsR[4];
#pragma unroll
  for (int reg = 0; reg < 4; ++reg) {
    const int qr = min(qbase + lgrp * 4 + reg, N_ - 1);
    const int qi = max(qr - 1, 0);
    AlocR[reg] = ((qi >> 5) - qymin + 31) * 63 + (qi & 31) + 31;
    qclsR[reg] = (qr == 0);
  }

  f32x4 psum = {0.f, 0.f, 0.f, 0.f};
  f32x4 o[4] = {};

  __syncthreads();  // full drain: tile-0 stage + tab complete, visible to all

  for (int t = 0; t < 16; ++t) {
    const int buf = t & 1;
    // ---- issue async stage of tile t+1 into buf^1 (role-split) ----
    if (t < 15) {
      const int keybase2 = (t + 1) * 64;
      if (wave < 4) {
#pragma unroll
        for (int c = 0; c < 2; ++c) {
          const int q = wave * 2 + c;
          const int Y = (q << 10) | (lane << 4);
          const int Ys = Y ^ (((Y >> 7) & 7) << 4);
          gload_lds16((const char*)kpan + ((size_t)keybase2 << 7) + Ys,
                      (char*)&Ks[buf ^ 1][0][0] + (q << 10));
        }
        // outstanding: K(t) 2 + K(t+1) 2 -> retire the 2 oldest = K(t)
        asm volatile("s_waitcnt vmcnt(2)" ::: "memory");
      } else {
#pragma unroll
        for (int c = 0; c < 4; ++c) {
          const int q = (wave - 4) * 4 + c;
          const int Y = (q << 10) | (lane << 4);
          const int Ys = Y ^ (((Y >> 7) & 7) << 4);
          const int row = Y >> 7;
          gload_lds16((const char*)vpan + (size_t)row * 2048 + ((size_t)keybase2 << 1) + (Ys & 127),
                      (char*)&Vs[buf ^ 1][0][0] + (q << 10));
        }
        // outstanding: V(t) 4 + V(t+1) 4 -> retire the 4 oldest = V(t)
        asm volatile("s_waitcnt vmcnt(4)" ::: "memory");
      }
    } else {
      asm volatile("s_waitcnt vmcnt(0)" ::: "memory");
    }
    __builtin_amdgcn_sched_barrier(0);
    __builtin_amdgcn_s_barrier();

    const int keybase = t * 64;
    const char* ksb = (const char*)&Ks[buf][0][0];
    const char* vsb = (const char*)&Vs[buf][0][0];

    // ---- S = Q K^T (K tile from swizzled LDS) ----
    f32x4 s[4] = {};
    __builtin_amdgcn_s_setprio(1);
#pragma unroll
    for (int tile = 0; tile < 4; ++tile) {
      const int row = tile * 16 + lrow;
      const int sw = (row & 7) << 4;
      const bf16x8 kf0 = *(const bf16x8*)(ksb + ((row * 128 + lgrp * 16) ^ sw));
      const bf16x8 kf1 = *(const bf16x8*)(ksb + ((row * 128 + 64 + lgrp * 16) ^ sw));
      s[tile] = __builtin_amdgcn_mfma_f32_16x16x32_bf16(qf[0], kf0, s[tile], 0, 0, 0);
      s[tile] = __builtin_amdgcn_mfma_f32_16x16x32_bf16(qf[1], kf1, s[tile], 0, 0, 0);
    }
    __builtin_amdgcn_s_setprio(0);
    // ---- bias + exp + P-write directly from C-layout registers ----
#pragma unroll
    for (int tile = 0; tile < 4; ++tile) {
      const int key = keybase + tile * 16 + lrow;
      const int ki = max(key - 1, 0);
      const int kpart = (ki >> 5) * 63 + (ki & 31);
      const bool kcls = (key == 0);
#pragma unroll
      for (int reg = 0; reg < 4; ++reg) {
        const float bias = (qclsR[reg] || kcls) ? bias0 : bf2f(tab[AlocR[reg] - kpart]);
        const float p = __expf(s[tile][reg] + bias);
        psum[reg] += p;
        pl[lgrp * 4 + reg][tile * 16 + lrow] = f2bf(p);
      }
    }
    // ---- O += P V (V tile from swizzled LDS) ----
    __builtin_amdgcn_s_setprio(1);
#pragma unroll
    for (int ch = 0; ch < 2; ++ch) {
      const bf16x8 pf = *(const bf16x8*)(&pl[lrow][ch * 32 + lgrp * 8]);
#pragma unroll
      for (int dt = 0; dt < 4; ++dt) {
        const int row = dt * 16 + lrow;
        const bf16x8 vf = *(const bf16x8*)(vsb + ((row * 128 + ch * 64 + lgrp * 16) ^ ((row & 7) << 4)));
        o[dt] = __builtin_amdgcn_mfma_f32_16x16x32_bf16(pf, vf, o[dt], 0, 0, 0);
      }
    }
    __builtin_amdgcn_s_setprio(0);
    // all LDS reads of buf must retire before any wave's next stage overwrites it
    asm volatile("s_waitcnt lgkmcnt(0)" ::: "memory");
    __builtin_amdgcn_sched_barrier(0);
    __builtin_amdgcn_s_barrier();
  }

  // ---- deferred row-sum: reduce psum over the 16 lanes of this lgrp ----
#pragma unroll
  for (int reg = 0; reg < 4; ++reg) {
    float v = psum[reg];
    v += __shfl_xor(v, 1);
    v += __shfl_xor(v, 2);
    v += __shfl_xor(v, 4);
    v += __shfl_xor(v, 8);
    psum[reg] = v;
  }

  // ---- tail: key 1024 (image key 1023: ky=31, kx=31) ----
  float ptail;
  {
    const u16* k1p = qkvbf + (size_t)(b * N_ + 1024) * K3_ + 512 + h * D_;
    const bf16x8 k10 = *(const bf16x8*)(k1p + lgrp * 8);
    const bf16x8 k11 = *(const bf16x8*)(k1p + 32 + lgrp * 8);
    float part = 0.f;
#pragma unroll
    for (int i = 0; i < 8; ++i)
      part += bf2f((u16)qf[0][i]) * bf2f((u16)k10[i]) + bf2f((u16)qf[1][i]) * bf2f((u16)k11[i]);
    part += __shfl_xor(part, 16);
    part += __shfl_xor(part, 32);
    // anchor for q-row = this lane's lrow (row-major tail mapping)
    const int q_s = min(qbase + lrow, N_ - 1);
    const int qi_s = max(q_s - 1, 0);
    const int Aloc_s = ((qi_s >> 5) - qymin + 31) * 63 + (qi_s & 31) + 31;
    const float btail = (q_s == 0) ? bias0 : bf2f(tab[Aloc_s - 31 * 63 - 31]);
    ptail = __expf(part + btail);
  }

  float v1024[4];
#pragma unroll
  for (int dt = 0; dt < 4; ++dt)
    v1024[dt] = bf2f(qkvbf[(size_t)(b * N_ + 1024) * K3_ + 1024 + h * D_ + dt * 16 + lrow]);

#pragma unroll
  for (int reg = 0; reg < 4; ++reg) {
    const float pr = __shfl(ptail, lgrp * 4 + reg);
    const int qrow = qbase + lgrp * 4 + reg;
    if (qrow >= N_) continue;
    const float inv = 1.0f / (psum[reg] + pr);
    u16* op = attnout + (size_t)(b * N_ + qrow) * C_ + h * D_ + lrow;
#pragma unroll
    for (int dt = 0; dt < 4; ++dt)
      op[dt * 16] = f2bf((o[dt][reg] + pr * v1024[dt]) * inv);
  }
}

// ---------------------------------------------------------------------------
// JAX threefry2x32 (20 rounds), exact
// ---------------------------------------------------------------------------
__device__ inline void tf2x32(unsigned k0, unsigned k1, unsigned& x0, unsigned& x1) {
  const unsigned ks2 = k0 ^ k1 ^ 0x1BD11BDAu;
  const int r0[4] = {13, 15, 26, 6};
  const int r1[4] = {17, 29, 16, 24};
  x0 += k0; x1 += k1;
#pragma unroll
  for (int i = 0; i < 4; ++i) { x0 += x1; x1 = (x1 << r0[i]) | (x1 >> (32 - r0[i])); x1 ^= x0; }
  x0 += k1; x1 += ks2 + 1u;
#pragma unroll
  for (int i = 0; i < 4; ++i) { x0 += x1; x1 = (x1 << r1[i]) | (x1 >> (32 - r1[i])); x1 ^= x0; }
  x0 += ks2; x1 += k0 + 2u;
#pragma unroll
  for (int i = 0; i < 4; ++i) { x0 += x1; x1 = (x1 << r0[i]) | (x1 >> (32 - r0[i])); x1 ^= x0; }
  x0 += k0; x1 += k1 + 3u;
#pragma unroll
  for (int i = 0; i < 4; ++i) { x0 += x1; x1 = (x1 << r1[i]) | (x1 >> (32 - r1[i])); x1 ^= x0; }
  x0 += k1; x1 += ks2 + 4u;
#pragma unroll
  for (int i = 0; i < 4; ++i) { x0 += x1; x1 = (x1 << r0[i]) | (x1 >> (32 - r0[i])); x1 ^= x0; }
  x0 += ks2; x1 += k0 + 5u;
}

// ---------------------------------------------------------------------------
// Fused plan tail v3 (r20): plan_cls merged in — each thread computes its own
// 8 cls values (val8[b]) directly from lgt/mxz with the IDENTICAL per-element
// serial h-loop and /8.0 (bit-exact vs the separate plan_cls kernel); the
// global cls round-trip and one launch disappear. Sort/counts/threefry
// unchanged (sort key v = val8[0] == old cls[t]).
// ---------------------------------------------------------------------------
__global__ __launch_bounds__(1024) void plan_tail_kernel(
    const double* __restrict__ lgt, const double* __restrict__ mxz,
    const float* __restrict__ tw,
    int* __restrict__ scal, int* __restrict__ sel, int* __restrict__ ii) {
  __shared__ double sv[1024];
  __shared__ int sid[1024];
  __shared__ double dred8[8][16];
  __shared__ double mred8[8][16];
  __shared__ int ired8[8][16];
  __shared__ double stats2[8][2];
  __shared__ int sc3[3];
  const int t = threadIdx.x;
  const int wid = t >> 6, lane = t & 63;

  // ---- cls values for this thread's column t, all 8 batches (bit-exact:
  //      identical expression + serial h order as the old plan_cls) ----
  double val8[8];
#pragma unroll
  for (int b = 0; b < 8; ++b) {
    double s = 0.0;
    for (int h = 0; h < 8; ++h) {
      const int bh = b * 8 + h;
      s += exp(lgt[(size_t)bh * N_ + 1 + t] - mxz[bh]) / mxz[64 + bh];
    }
    val8[b] = s / 8.0;
  }

  // ---- bitonic sort (batch 0), values in registers ----
  double v = val8[0];
  int idx = t;
  for (int k = 2; k <= 1024; k <<= 1) {
    for (int j = k >> 1; j > 0; j >>= 1) {
      const bool desc = ((t & k) == 0);     // same for both partners (j < k)
      const bool iAmLow = (t & j) == 0;
      double ov;
      int oi;
      if (j >= 64) {
        sv[t] = v;
        sid[t] = idx;
        __syncthreads();
        ov = sv[t ^ j];
        oi = sid[t ^ j];
        __syncthreads();
      } else {
        ov = __shfl_xor(v, j);
        oi = __shfl_xor(idx, j);
      }
      // myFirst == original aFirst evaluated from this thread's perspective
      const bool myFirst = (v > ov) || (v == ov && idx < oi);
      const bool keepMine = desc ? (iAmLow == myFirst) : (iAmLow != myFirst);
      if (!keepMine) { v = ov; idx = oi; }
    }
  }
  sel[t] = idx;

  // ---- counts: all 8 batches, trees EXACTLY as the split version ----
#pragma unroll
  for (int b = 0; b < 8; ++b) {
    double s = val8[b];
#pragma unroll
    for (int o = 32; o; o >>= 1) s += __shfl_down(s, o);
    if (lane == 0) dred8[b][wid] = s;
    double mv = val8[b];
#pragma unroll
    for (int o = 32; o; o >>= 1) mv = fmax(mv, __shfl_down(mv, o));
    if (lane == 0) mred8[b][wid] = mv;
  }
  __syncthreads();
  if (t < 8) {
    double tot = 0;
    for (int i = 0; i < 16; ++i) tot += dred8[t][i];
    stats2[t][0] = tot / 1024.0;
    double mx = mred8[t][0];
    for (int i = 1; i < 16; ++i) mx = fmax(mx, mred8[t][i]);
    stats2[t][1] = mx;
  }
  __syncthreads();
#pragma unroll
  for (int b = 0; b < 8; ++b) {
    int c = (val8[b] >= stats2[b][0] && val8[b] <= stats2[b][1]) ? 1 : 0;
#pragma unroll
    for (int o = 32; o; o >>= 1) c += __shfl_down(c, o);
    if (lane == 0) ired8[b][wid] = c;
  }
  __syncthreads();

  if (t == 0) {
    int maxv = 0;
    double sum = 0.0;
    for (int b = 0; b < 8; ++b) {
      int cc = 0;
      for (int i = 0; i < 16; ++i) cc += ired8[b][i];
      maxv = max(maxv, cc);
      sum += (double)cc;
    }
    const double T = sum / 8.0;
    const double sig = 1.0 / (1.0 + exp(-((double)maxv - T) / 8.0));
    const double keepf = 1024.0 * (0.6 + (1.0 - 0.6) * sig);
    const int keep = __double2int_rn(keepf);
    const int remaining = 1024 - keep;
    const float t0 = tw[0], t1 = tw[1];
    const float mw = fmaxf(t0, t1);
    const float e0 = expf(t0 - mw), e1 = expf(t1 - mw);
    const float w0 = e0 / (e0 + e1);
    const int nt = (int)(w0 * (float)remaining);
    const int ni = remaining - nt;
    scal[0] = keep; scal[1] = nt; scal[2] = ni;
    sc3[0] = keep; sc3[1] = nt; sc3[2] = ni;
  }
  __syncthreads();

  const int ni = sc3[2];
  const int size = 8 * ni;
  const unsigned span = 1023u;
  unsigned mult = 65536u % span;
  mult = (mult * mult) % span;
  unsigned f0 = 0u, f1 = 1u;
  tf2x32(0u, 1234u, f0, f1);
#if PARTITIONABLE
  unsigned k1a = 0u, k1b = 0u;
  tf2x32(f0, f1, k1a, k1b);
  unsigned k2a = 0u, k2b = 1u;
  tf2x32(f0, f1, k2a, k2b);
  for (int i = t; i < size; i += 1024) {
    unsigned h0 = 0u, h1 = (unsigned)i;
    tf2x32(k1a, k1b, h0, h1);
    const unsigned hb = h0 ^ h1;
    unsigned l0 = 0u, l1 = (unsigned)i;
    tf2x32(k2a, k2b, l0, l1);
    const unsigned lb = l0 ^ l1;
    ii[i] = (int)(((hb % span) * mult + (lb % span)) % span);
  }
#else
  unsigned a0 = 0u, a1 = 2u;
  tf2x32(f0, f1, a0, a1);
  unsigned b0 = 1u, b1 = 3u;
  tf2x32(f0, f1, b0, b1);
  const int half = size >> 1;
  for (int i = t; i < half; i += 1024) {
    unsigned h0 = (unsigned)i, h1 = (unsigned)(i + half);
    tf2x32(a0, b0, h0, h1);
    unsigned l0 = (unsigned)i, l1 = (unsigned)(i + half);
    tf2x32(a1, b1, l0, l1);
    ii[i]        = (int)(((h0 % span) * mult + (l0 % span)) % span);
    ii[i + half] = (int)(((h1 % span) * mult + (l1 % span)) % span);
  }
#endif
}

// ---------------------------------------------------------------------------
// Fused assemble + LN2: x1 = x + gathered_src; x1n_bf = LN(x1)
// ---------------------------------------------------------------------------
__global__ __launch_bounds__(256) void assemble_ln_kernel(
    const float* __restrict__ x, const float* __restrict__ xn,
    const float* __restrict__ xo, const int* __restrict__ scal,
    const int* __restrict__ sel, const int* __restrict__ ii,
    const float* __restrict__ w, const float* __restrict__ bb,
    float* __restrict__ x1, u16* __restrict__ ob) {
  __shared__ float red[4];
  const int blk = blockIdx.x;
  const int b = blk / N_, tok = blk % N_;
  const int keep = scal[0], nt = scal[1], ni = scal[2];
  const float* src;
  if (tok == 0) {
    src = xo + (size_t)(b * N_) * C_;
  } else if (tok <= keep) {
    src = xo + (size_t)(b * N_ + 1 + sel[tok - 1]) * C_;
  } else if (tok <= keep + nt) {
    src = xn + (size_t)(b * N_ + 1) * C_;
  } else {
    const int j = tok - 1 - keep - nt;
    src = xn + (size_t)(b * N_ + 2 + ii[b * ni + j]) * C_;
  }
  const int t = threadIdx.x;
  const size_t o = (size_t)blk * C_;
  const float v0 = x[o + t] + src[t];
  const float v1 = x[o + t + 256] + src[t + 256];
  x1[o + t] = v0;
  x1[o + t + 256] = v1;
  float s = v0 + v1;
#pragma unroll
  for (int of = 32; of; of >>= 1) s += __shfl_down(s, of);
  if ((t & 63) == 0) red[t >> 6] = s;
  __syncthreads();
  const float mean = (red[0] + red[1] + red[2] + red[3]) * (1.0f / 512.0f);
  __syncthreads();
  const float d0 = v0 - mean, d1 = v1 - mean;
  float q = d0 * d0 + d1 * d1;
#pragma unroll
  for (int of = 32; of; of >>= 1) q += __shfl_down(q, of);
  if ((t & 63) == 0) red[t >> 6] = q;
  __syncthreads();
  const float var = (red[0] + red[1] + red[2] + red[3]) * (1.0f / 512.0f);
  const float inv = 1.0f / sqrtf(var + 1e-5f);
  ob[o + t] = f2bf(d0 * inv * w[t] + bb[t]);
  ob[o + t + 256] = f2bf(d1 * inv * w[t + 256] + bb[t + 256]);
}

// ---------------------------------------------------------------------------
// Host launcher
// ---------------------------------------------------------------------------
extern "C" void kernel_launch(void* const* d_in, const int* in_sizes, int n_in,
                              void* d_out, int out_size, void* d_ws, size_t ws_size,
                              hipStream_t stream) {
  (void)in_sizes; (void)n_in; (void)out_size; (void)ws_size;
  const float* x     = (const float*)d_in[0];
  const float* ln1w  = (const float*)d_in[1];
  const float* ln1b  = (const float*)d_in[2];
  const float* qkvw  = (const float*)d_in[3];
  const float* rpb   = (const float*)d_in[4];
  const float* projw = (const float*)d_in[5];
  const float* projb = (const float*)d_in[6];
  const float* tw    = (const float*)d_in[7];
  const float* ln2w  = (const float*)d_in[8];
  const float* ln2b  = (const float*)d_in[9];
  const float* fc1w  = (const float*)d_in[10];
  const float* fc1b  = (const float*)d_in[11];
  const float* fc2w  = (const float*)d_in[12];
  const float* fc2b  = (const float*)d_in[13];
  float* out = (float*)d_out;
  char* base = (char*)d_ws;

  float* xn       = (float*)(base + BYTE_XN);
  u16*   qkv_bf   = (u16*)(base + BYTE_QKVBF);
  u16*   xn_bf    = (u16*)(base + BYTE_XNBF);
  u16*   hbuf     = (u16*)(base + BYTE_HBUF);
  u16*   wq_bf    = (u16*)(base + BYTE_WTAIL);
  u16*   wp_bf    = wq_bf + K3_ * C_;
  u16*   w1_bf    = wp_bf + C_ * C_;
  u16*   w2_bf    = w1_bf + F_ * C_;
  u16*   attn_bf  = (u16*)(base + BYTE_ATTNBF);
  u16*   x1n_bf   = (u16*)(base + BYTE_X1NBF);
  float* xo       = (float*)(base + BYTE_XO);
  u16*   kbuf     = (u16*)(base + BYTE_X1);
  u16*   vbuf     = kbuf + (size_t)B_ * NH_ * 1024 * 64;
  float* x1       = (float*)(base + BYTE_X1);

  char* pb = base + PLAN_BYTE;
  double* q0  = (double*)pb;
  double* u   = q0 + 4096;
  double* lgt = u + 32768;
  double* mxz = lgt + 65600;
  double* cls = mxz + 128;
  int* counts = (int*)(cls + 8192);
  int* scal   = counts + 8;
  int* sel    = scal + 4;
  int* iibuf  = sel + 1024;

  // 1. fused LN1 (-> xn f32 + xn_bf) + all weight conversions, one launch
  ln_wconv_kernel<<<ROWS_ + WCONV_BLKS_, 256, 0, stream>>>(
      x, ln1w, ln1b, xn, xn_bf,
      qkvw, projw, fc1w, fc2w, wq_bf, wp_bf, w1_bf, w2_bf);
  // 2. QKV GEMM (BN=128, grid 780) + 16 fused plan_q0 blocks (bit-exact)
  gemm_bf_kernel<128, 0, false, true, true, true, false><<<65 * 12 + 16, 256, 0, stream>>>(
      xn_bf, wq_bf, nullptr, nullptr, qkv_bf, ROWS_, C_, K3_, 65 * 12,
      xn, qkvw, q0, nullptr, nullptr);
  // 3. dense K/V^T packs (1D grid 1024) + 128 fused plan_u blocks (bit-exact)
  pack_kv_kernel<<<1024 + 128, 256, 0, stream>>>(
      qkv_bf, kbuf, vbuf, qkvw, q0, u, 1024);
  // 4. MFMA flash attention v11 (704 blocks) + 48 fused plan_logit blocks
  //    (head-split threads halve the serial f64 chain; 752 <= 768 single fill)
  attn_mfma_kernel<<<11 * NH_ * B_ + 48, 384, 0, stream>>>(
      qkv_bf, kbuf, vbuf, rpb, attn_bf, xn, u, lgt, 11 * NH_ * B_);
  // 5. proj (BN=64, grid 520) + 64 fused plan_softmax blocks (bit-exact;
  //    584 <= 768 single fill)
  gemm_bf_kernel<64, 0, false, false, false, false, true><<<65 * 8 + 64, 256, 0, stream>>>(
      attn_bf, wp_bf, projb, nullptr, xo, ROWS_, C_, C_, 65 * 8,
      nullptr, nullptr, nullptr, lgt, mxz);
  // 6. plan tail v3 (cls computed in-kernel + sort + counts + threefry)
  plan_tail_kernel<<<1, 1024, 0, stream>>>(lgt, mxz, tw, scal, sel, iibuf);
  // 7. fused assemble + residual + LN2 -> x1 f32 + x1n_bf
  assemble_ln_kernel<<<ROWS_, 256, 0, stream>>>(
      x, xn, xo, scal, sel, iibuf, ln2w, ln2b, x1, x1n_bf);
  // 8. FC1 + exact GELU -> hbuf bf16 — BN=128, grid 1040
  gemm_bf_kernel<128, 1, false, true, false, false, false><<<65 * 16, 256, 0, stream>>>(
      x1n_bf, w1_bf, fc1b, nullptr, hbuf, ROWS_, C_, F_, 65 * 16,
      nullptr, nullptr, nullptr, nullptr, nullptr);
  // 9. FC2 + bias + residual -> out f32 — BN=64, grid 520
  gemm_bf_kernel<64, 0, true, false, false, false, false><<<65 * 8, 256, 0, stream>>>(
      hbuf, w2_bf, fc2b, x1, out, ROWS_, F_, C_, 65 * 8,
      nullptr, nullptr, nullptr, nullptr, nullptr);
}

// Round 21
// 303.827 us; speedup vs baseline: 1.0710x; 1.0710x over previous
//
#include <hip/hip_runtime.h>
#include <cmath>

#define PARTITIONABLE 1

// ---------------------------------------------------------------------------
// Problem constants (B=8, S=32 -> N=1025, C=512, NH=8, D=64)
// ---------------------------------------------------------------------------
constexpr int B_ = 8;
constexpr int N_ = 1025;
constexpr int C_ = 512;
constexpr int NH_ = 8;
constexpr int D_ = 64;
constexpr int K3_ = 1536;   // 3*C
constexpr int F_ = 2048;    // 4*C
constexpr int ROWS_ = B_ * N_;  // 8200
constexpr int NXCD_ = 8;
constexpr int WCONV_BLKS_ = (K3_ * C_ + C_ * C_ + F_ * C_ + C_ * F_) / 1024;  // 3072

// ---------------------------------------------------------------------------
// Workspace byte offsets — round-2-proven envelope [0, ~118.5MB)
// ---------------------------------------------------------------------------
constexpr size_t BYTE_XN      = 0;              // xn f32            16,793,600
constexpr size_t BYTE_QKVBF   = 16793600;       // qkv bf16          25,190,400
constexpr size_t BYTE_XNBF    = 41984000;       // xn bf16            8,396,800
constexpr size_t BYTE_HBUF    = 16793600;       // h bf16 (aliases qkv_bf+xn_bf)
constexpr size_t BYTE_WTAIL   = 60882944;       // bf16 weights       6,291,456
constexpr size_t BYTE_ATTNBF  = 67174400;       // attn out bf16      8,396,800
constexpr size_t BYTE_X1NBF   = 75571200;       // ln2 out bf16       8,396,800
constexpr size_t BYTE_XO      = 83968000;       // xo f32            16,793,600
constexpr size_t BYTE_X1      = 100761600;      // kb+vb (attn) then x1 f32  16,793,600
constexpr size_t PLAN_BYTE    = 117555200;      // plan scratch ~0.9 MB

typedef unsigned short u16;
typedef __attribute__((ext_vector_type(4))) unsigned short u16x4;
typedef __attribute__((ext_vector_type(8))) short bf16x8;
typedef __attribute__((ext_vector_type(4))) float f32x4;

__device__ inline u16 f2bf(float f) {
  unsigned u = __float_as_uint(f);
  u = (u + 0x7FFFu + ((u >> 16) & 1u)) >> 16;
  return (u16)u;
}
__device__ inline float bf2f(u16 u) { return __uint_as_float(((unsigned)u) << 16); }

// Bijective XCD-aware block remap: each XCD gets a contiguous logical chunk.
__device__ inline int xcd_swz(int bid, int nwg) {
  const int xcd = bid % NXCD_, i = bid / NXCD_;
  const int q = nwg / NXCD_, r = nwg % NXCD_;
  const int base = (xcd < r) ? xcd * (q + 1) : r * (q + 1) + (xcd - r) * q;
  return base + i;
}

// async global->LDS, 16B per lane (lds dst must be wave-uniform base)
__device__ inline void gload_lds16(const void* g, void* l) {
  __builtin_amdgcn_global_load_lds(
      (const __attribute__((address_space(1))) void*)g,
      (__attribute__((address_space(3))) void*)l, 16, 0, 0);
}

// ---------------------------------------------------------------------------
// Fused LN1 + all-weight bf16 conversion (independent work, one launch).
// Blocks [0, ROWS_): LayerNorm row; blocks [ROWS_, ROWS_+3072): weight conv.
// ---------------------------------------------------------------------------
__global__ __launch_bounds__(256) void ln_wconv_kernel(
    const float* __restrict__ x, const float* __restrict__ w,
    const float* __restrict__ b, float* __restrict__ of, u16* __restrict__ ob,
    const float* __restrict__ w0, const float* __restrict__ w1,
    const float* __restrict__ w2, const float* __restrict__ w3,
    u16* __restrict__ o0, u16* __restrict__ o1,
    u16* __restrict__ o2, u16* __restrict__ o3) {
  __shared__ float red[4];
  if (blockIdx.x >= ROWS_) {
    constexpr int n0 = K3_ * C_, n1 = C_ * C_, n2 = F_ * C_;
    const int idx4 = ((blockIdx.x - ROWS_) * 256 + threadIdx.x) * 4;
    const float* src;
    u16* dst;
    int off;
    if (idx4 < n0) { src = w0; dst = o0; off = idx4; }
    else if (idx4 < n0 + n1) { src = w1; dst = o1; off = idx4 - n0; }
    else if (idx4 < n0 + n1 + n2) { src = w2; dst = o2; off = idx4 - n0 - n1; }
    else { src = w3; dst = o3; off = idx4 - n0 - n1 - n2; }
    const float4 v = *(const float4*)(src + off);
    u16x4 r;
    r.x = f2bf(v.x); r.y = f2bf(v.y); r.z = f2bf(v.z); r.w = f2bf(v.w);
    *(u16x4*)(dst + off) = r;
    return;
  }
  const int r = blockIdx.x;
  const int t = threadIdx.x;
  const float* xr = x + (size_t)r * C_;
  float v0 = xr[t], v1 = xr[t + 256];
  float s = v0 + v1;
#pragma unroll
  for (int o = 32; o; o >>= 1) s += __shfl_down(s, o);
  if ((t & 63) == 0) red[t >> 6] = s;
  __syncthreads();
  const float mean = (red[0] + red[1] + red[2] + red[3]) * (1.0f / 512.0f);
  __syncthreads();
  const float d0 = v0 - mean, d1 = v1 - mean;
  float q = d0 * d0 + d1 * d1;
#pragma unroll
  for (int o = 32; o; o >>= 1) q += __shfl_down(q, o);
  if ((t & 63) == 0) red[t >> 6] = q;
  __syncthreads();
  const float var = (red[0] + red[1] + red[2] + red[3]) * (1.0f / 512.0f);
  const float inv = 1.0f / sqrtf(var + 1e-5f);
  const float r0 = d0 * inv * w[t] + b[t];
  const float r1 = d1 * inv * w[t + 256] + b[t + 256];
  of[(size_t)r * C_ + t] = r0;
  of[(size_t)r * C_ + t + 256] = r1;
  ob[(size_t)r * C_ + t] = f2bf(r0);
  ob[(size_t)r * C_ + t + 256] = f2bf(r1);
}

// ---------------------------------------------------------------------------
// bf16 MFMA GEMM: out[M,N] = A[M,K](bf16) @ W[N,K](bf16)^T (+bias)(+gelu)(+res)
// 128xBN tile (BN=128 or 64), BK=64, 4 waves (2x2), 64x(BN/2) per wave.
// Double-buffered LDS + counted-vmcnt pipeline (T3+T4).
// BN=128 for large-N GEMMs (QKV/FC1); BN=64 ONLY for N=512 outputs.
// PLANQ0 (QKV): guest blocks run plan_q0 verbatim (bit-exact relocation).
// SMAX (proj): guest blocks run plan_softmax verbatim (bit-exact relocation).
// ---------------------------------------------------------------------------
template <int BN, int ACT, bool RES, bool OUTBF, bool QSCALE, bool PLANQ0, bool SMAX>
__global__ __launch_bounds__(256) void gemm_bf_kernel(
    const u16* __restrict__ A, const u16* __restrict__ W,
    const float* __restrict__ bias, const float* __restrict__ resid,
    void* __restrict__ outp, int M, int K, int Nout, int ngemm,
    const float* __restrict__ xnf, const float* __restrict__ qkvwf,
    double* __restrict__ q0o,
    const double* __restrict__ lgtp, double* __restrict__ mxzp) {
  constexpr int WN = BN / 2;       // wave cols: 64 or 32
  constexpr int NJ = WN / 16;      // j-tiles: 4 or 2
  constexpr int BPW = (BN / 8) / 4;  // B chunks per wave: 4 or 2
  __shared__ alignas(16) u16 As[2][128][64];
  __shared__ alignas(16) u16 Bs[2][BN][64];
  if (PLANQ0 && (int)blockIdx.x >= ngemm) {
    const int idx = ((int)blockIdx.x - ngemm) * 256 + threadIdx.x;
    const int b = idx >> 9, hd = idx & 511;
    const float* xr = xnf + (size_t)(b * N_) * C_;
    const float* wr = qkvwf + (size_t)hd * C_;
    double s = 0.0;
    for (int c = 0; c < C_; c += 4) {
      const float4 xv = *(const float4*)(xr + c);
      const float4 wv = *(const float4*)(wr + c);
      s += (double)xv.x * (double)wv.x;
      s += (double)xv.y * (double)wv.y;
      s += (double)xv.z * (double)wv.z;
      s += (double)xv.w * (double)wv.w;
    }
    q0o[idx] = s * 0.125;
    return;
  }
  if (SMAX && (int)blockIdx.x >= ngemm) {
    // plan_softmax body, verbatim (bit-exact relocation)
    __shared__ double red[4];
    const int bh = (int)blockIdx.x - ngemm;
    const int t = threadIdx.x;
    const double* row = lgtp + (size_t)bh * N_;
    double m = -1e300;
    for (int i = t; i < N_; i += 256) m = fmax(m, row[i]);
#pragma unroll
    for (int o = 32; o; o >>= 1) m = fmax(m, __shfl_down(m, o));
    if ((t & 63) == 0) red[t >> 6] = m;
    __syncthreads();
    const double mx = fmax(fmax(red[0], red[1]), fmax(red[2], red[3]));
    __syncthreads();
    double z = 0.0;
    for (int i = t; i < N_; i += 256) z += exp(row[i] - mx);
#pragma unroll
    for (int o = 32; o; o >>= 1) z += __shfl_down(z, o);
    if ((t & 63) == 0) red[t >> 6] = z;
    __syncthreads();
    if (t == 0) {
      mxzp[bh] = mx;
      mxzp[64 + bh] = red[0] + red[1] + red[2] + red[3];
    }
    return;
  }
  const int tid = threadIdx.x;
  const int ny = Nout / BN;
  const int l = xcd_swz(blockIdx.x, ngemm);
  const int m0 = (l / ny) * 128, n0 = (l % ny) * BN;
  const int wave = tid >> 6, lane = tid & 63;
  const int wr = wave >> 1, wc = wave & 1;
  const int lrow = lane & 15, lgrp = lane >> 4;
  const int srow = lane >> 3;                              // row within chunk
  const int soff = (16 * (lane & 7)) ^ (16 * srow);        // swizzled src byte
  const int nk = K >> 6;

  auto stage = [&](int k0, int bufi) {
#pragma unroll
    for (int c = 0; c < 4; ++c) {
      const int q = wave * 4 + c;
      const int row = q * 8 + srow;
      int gm = m0 + row;
      if (gm >= M) gm = M - 1;
      gload_lds16((const char*)(A + (size_t)gm * K + k0) + soff,
                  (char*)&As[bufi][0][0] + (q << 10));
    }
#pragma unroll
    for (int c = 0; c < BPW; ++c) {
      const int q = wave * BPW + c;
      const int row = q * 8 + srow;
      gload_lds16((const char*)(W + (size_t)(n0 + row) * K + k0) + soff,
                  (char*)&Bs[bufi][0][0] + (q << 10));
    }
  };

  f32x4 acc[4][NJ] = {};
  stage(0, 0);
  int buf = 0;
  for (int t = 0; t < nk; ++t) {
    if (t + 1 < nk) {
      stage((t + 1) << 6, buf ^ 1);
      // outstanding = 2*(4+BPW); retire the oldest (4+BPW) = tile t
      if constexpr (BN == 128) asm volatile("s_waitcnt vmcnt(8)" ::: "memory");
      else                     asm volatile("s_waitcnt vmcnt(6)" ::: "memory");
    } else {
      asm volatile("s_waitcnt vmcnt(0)" ::: "memory");
    }
    __builtin_amdgcn_sched_barrier(0);
    __builtin_amdgcn_s_barrier();
    const char* asb = (const char*)&As[buf][0][0];
    const char* bsb = (const char*)&Bs[buf][0][0];
    __builtin_amdgcn_s_setprio(1);
#pragma unroll
    for (int ch = 0; ch < 2; ++ch) {
      bf16x8 af[4], bfv[NJ];
#pragma unroll
      for (int i = 0; i < 4; ++i) {
        const int ra = wr * 64 + i * 16 + lrow;
        const int cb = ch * 64 + lgrp * 16;
        af[i] = *(const bf16x8*)(asb + (ra << 7) + (cb ^ ((ra & 7) << 4)));
      }
#pragma unroll
      for (int j = 0; j < NJ; ++j) {
        const int rb = wc * WN + j * 16 + lrow;
        const int cb = ch * 64 + lgrp * 16;
        bfv[j] = *(const bf16x8*)(bsb + (rb << 7) + (cb ^ ((rb & 7) << 4)));
      }
#pragma unroll
      for (int i = 0; i < 4; ++i)
#pragma unroll
        for (int j = 0; j < NJ; ++j)
          acc[i][j] = __builtin_amdgcn_mfma_f32_16x16x32_bf16(af[i], bfv[j], acc[i][j], 0, 0, 0);
    }
    __builtin_amdgcn_s_setprio(0);
    asm volatile("s_waitcnt lgkmcnt(0)" ::: "memory");
    __builtin_amdgcn_sched_barrier(0);
    __builtin_amdgcn_s_barrier();
    buf ^= 1;
  }
#pragma unroll
  for (int i = 0; i < 4; ++i) {
#pragma unroll
    for (int j = 0; j < NJ; ++j) {
#pragma unroll
      for (int reg = 0; reg < 4; ++reg) {
        const int gm = m0 + wr * 64 + i * 16 + lgrp * 4 + reg;
        if (gm >= M) continue;
        const int gn = n0 + wc * WN + j * 16 + lrow;
        float v = acc[i][j][reg];
        if (bias) v += bias[gn];
        if (ACT == 1) v = 0.5f * v * (1.0f + erff(v * 0.70710678118654752440f));
        if (QSCALE) { if (gn < 512) v *= 0.125f; }
        if (RES) v += resid[(size_t)gm * Nout + gn];
        if (OUTBF) ((u16*)outp)[(size_t)gm * Nout + gn] = f2bf(v);
        else       ((float*)outp)[(size_t)gm * Nout + gn] = v;
      }
    }
  }
}

// ---------------------------------------------------------------------------
// Pack dense K [b][h][1024][64] and V^T [b][h][64][1024] from qkv_bf.
// 1D grid (blocks independent -> order-free flatten). Blocks >= npack run the
// plan_u body verbatim (bit-exact relocation), overlapping the pack.
// ---------------------------------------------------------------------------
__global__ __launch_bounds__(256) void pack_kv_kernel(const u16* __restrict__ qkvbf,
                                                      u16* __restrict__ kb,
                                                      u16* __restrict__ vb,
                                                      const float* __restrict__ qkvwf,
                                                      const double* __restrict__ q0,
                                                      double* __restrict__ u,
                                                      int npack) {
  if ((int)blockIdx.x >= npack) {
    const int idx = ((int)blockIdx.x - npack) * 256 + threadIdx.x;
    const int b = idx >> 12, h = (idx >> 9) & 7, c = idx & 511;
    double s = 0.0;
    for (int d = 0; d < D_; ++d)
      s += q0[b * 512 + h * 64 + d] * (double)qkvwf[(size_t)(512 + h * 64 + d) * C_ + c];
    u[idx] = s;
    return;
  }
  const int tile = blockIdx.x & 15, h = (blockIdx.x >> 4) & 7, b = (int)blockIdx.x >> 7;
  const int t = threadIdx.x;
  __shared__ u16 Vt[64][72];
  const int krow = tile * 64 + (t >> 2);
  const int dseg = (t & 3) * 16;
  const u16* p = qkvbf + (size_t)(b * N_ + krow) * K3_ + 512 + h * D_ + dseg;
  const bf16x8 k0 = *(const bf16x8*)p;
  const bf16x8 k1 = *(const bf16x8*)(p + 8);
  u16* kp = kb + ((size_t)(b * NH_ + h) * 1024 + krow) * 64 + dseg;
  *(bf16x8*)kp = k0;
  *(bf16x8*)(kp + 8) = k1;
  const bf16x8 v0 = *(const bf16x8*)(p + 512);
  const bf16x8 v1 = *(const bf16x8*)(p + 520);
  *(bf16x8*)(&Vt[t >> 2][dseg]) = v0;
  *(bf16x8*)(&Vt[t >> 2][dseg + 8]) = v1;
  __syncthreads();
  const int d = t >> 2, kseg = (t & 3) * 16;
  bf16x8 o0, o1;
#pragma unroll
  for (int i = 0; i < 8; ++i) o0[i] = (short)Vt[kseg + i][d];
#pragma unroll
  for (int i = 0; i < 8; ++i) o1[i] = (short)Vt[kseg + 8 + i][d];
  u16* vp = vb + ((size_t)(b * NH_ + h) * 64 + d) * 1024 + tile * 64 + kseg;
  *(bf16x8*)vp = o0;
  *(bf16x8*)(vp + 8) = o1;
}

// ---------------------------------------------------------------------------
// MFMA flash attention v11 + fused plan_logit guest blocks (r19: heads split
// across threads — each thread computes 4 heads for one row, halving the
// serial f64 chain; per-head c-loop order unchanged -> bit-exact. 48 guests
// (6/batch), hg = t/192 wave-uniform -> LDS reads stay broadcast).
// attn: 704 blocks, LDS 51.5KB, 3 blocks/CU; 704+48=752 <= 768 single fill.
// ---------------------------------------------------------------------------
__global__ __launch_bounds__(384) void attn_mfma_kernel(
    const u16* __restrict__ qkvbf, const u16* __restrict__ kb,
    const u16* __restrict__ vb, const float* __restrict__ rpb,
    u16* __restrict__ attnout,
    const float* __restrict__ xnf, const double* __restrict__ uu,
    double* __restrict__ lgt, int nattn) {
  __shared__ alignas(16) u16 Ks[2][64][64];   // 16KB, XOR-swizzled storage
  __shared__ alignas(16) u16 Vs[2][64][64];   // 16KB, XOR-swizzled storage
  __shared__ alignas(16) u16 Pl[6][16][74];   // 14.2KB; stride 74 breaks conflicts
  __shared__ u16 tab[36 * 63];                // 4.5KB bf16 bias table
  if ((int)blockIdx.x >= nattn) {
    // plan_logit guest: 6 blocks/batch; thread = (row rloc, head-group hg)
    double* ul = (double*)&Ks[0][0][0];       // 4096 f64 = 32KB (aliases Ks)
    const int lb = (int)blockIdx.x - nattn;   // [0, 48)
    const int b = lb / 6, part = lb % 6;
    for (int i = threadIdx.x; i < 4096; i += 384)
      ul[i] = uu[(size_t)b * 4096 + i];
    __syncthreads();
    const int rloc = threadIdx.x % 192;
    const int hg = threadIdx.x / 192;         // 0 or 1 (wave-uniform)
    const int m = part * 192 + rloc;
    if (m >= N_) return;
    const float* xr = xnf + (size_t)(b * N_ + m) * C_;
    const double* ulh = ul + hg * 4 * 512;
    double s[4] = {};
    for (int c = 0; c < C_; c += 4) {
      const float4 xv = *(const float4*)(xr + c);
#pragma unroll
      for (int hh = 0; hh < 4; ++hh) {
        s[hh] += (double)xv.x * ulh[hh * 512 + c];
        s[hh] += (double)xv.y * ulh[hh * 512 + c + 1];
        s[hh] += (double)xv.z * ulh[hh * 512 + c + 2];
        s[hh] += (double)xv.w * ulh[hh * 512 + c + 3];
      }
    }
#pragma unroll
    for (int hh = 0; hh < 4; ++hh)
      lgt[(size_t)(b * 8 + hg * 4 + hh) * N_ + m] = s[hh];
    return;
  }
  const int l = xcd_swz(blockIdx.x, nattn);  // logical = (b*8+h)*11 + qt
  const int qt = l % 11;
  const int bh = l / 11;
  const int h = bh & 7, b = bh >> 3;
  const int wave = threadIdx.x >> 6, lane = threadIdx.x & 63;
  const int lrow = lane & 15, lgrp = lane >> 4;
  const int qblk = qt * 96;
  const int qbase = qblk + wave * 16;

  const u16* kpan = kb + (size_t)(b * NH_ + h) * 1024 * 64;
  const u16* vpan = vb + (size_t)(b * NH_ + h) * 64 * 1024;

  // ---- issue async stage of tile 0 (waves 0-3: K, waves 4-5: V) ----
  if (wave < 4) {
#pragma unroll
    for (int c = 0; c < 2; ++c) {
      const int q = wave * 2 + c;
      const int Y = (q << 10) | (lane << 4);
      const int Ys = Y ^ (((Y >> 7) & 7) << 4);
      gload_lds16((const char*)kpan + Ys, (char*)&Ks[0][0][0] + (q << 10));
    }
  } else {
#pragma unroll
    for (int c = 0; c < 4; ++c) {
      const int q = (wave - 4) * 4 + c;
      const int Y = (q << 10) | (lane << 4);
      const int Ys = Y ^ (((Y >> 7) & 7) << 4);
      const int row = Y >> 7;
      gload_lds16((const char*)vpan + (size_t)row * 2048 + (Ys & 127),
                  (char*)&Vs[0][0][0] + (q << 10));
    }
  }

  // ---- stage rpb sub-table (all threads; bf16) ----
  const int qimin = max(qblk - 1, 0);
  const int qimax = min(qblk + 94, 1023);
  const int qymin = qimin >> 5;
  const int qymax = qimax >> 5;
  const int nrows = qymax - qymin + 32;   // dy in [qymin-31, qymax]  (<=36)
  for (int i = threadIdx.x; i < nrows * 63; i += 384)
    tab[i] = f2bf(rpb[(size_t)(qymin * 63 + i) * NH_ + h]);

  u16 (*pl)[74] = Pl[wave];

  // Q fragments (pre-scaled by 1/8 in the QKV GEMM epilogue)
  bf16x8 qf[2];
  {
    const int qrow = min(qbase + lrow, N_ - 1);
    const u16* qp = qkvbf + (size_t)(b * N_ + qrow) * K3_ + h * D_;
    qf[0] = *(const bf16x8*)(qp + lgrp * 8);
    qf[1] = *(const bf16x8*)(qp + 32 + lgrp * 8);
  }

  const float bias0 = rpb[h];

  // Per-owned-q-row (C-layout rows lgrp*4+reg) bias table anchors
  int AlocR[4];
  bool qclsR[4];
#pragma unroll
  for (int reg = 0; reg < 4; ++reg) {
    const int qr = min(qbase + lgrp * 4 + reg, N_ - 1);
    const int qi = max(qr - 1, 0);
    AlocR[reg] = ((qi >> 5) - qymin + 31) * 63 + (qi & 31) + 31;
    qclsR[reg] = (qr == 0);
  }

  f32x4 psum = {0.f, 0.f, 0.f, 0.f};
  f32x4 o[4] = {};

  __syncthreads();  // full drain: tile-0 stage + tab complete, visible to all

  for (int t = 0; t < 16; ++t) {
    const int buf = t & 1;
    // ---- issue async stage of tile t+1 into buf^1 (role-split) ----
    if (t < 15) {
      const int keybase2 = (t + 1) * 64;
      if (wave < 4) {
#pragma unroll
        for (int c = 0; c < 2; ++c) {
          const int q = wave * 2 + c;
          const int Y = (q << 10) | (lane << 4);
          const int Ys = Y ^ (((Y >> 7) & 7) << 4);
          gload_lds16((const char*)kpan + ((size_t)keybase2 << 7) + Ys,
                      (char*)&Ks[buf ^ 1][0][0] + (q << 10));
        }
        // outstanding: K(t) 2 + K(t+1) 2 -> retire the 2 oldest = K(t)
        asm volatile("s_waitcnt vmcnt(2)" ::: "memory");
      } else {
#pragma unroll
        for (int c = 0; c < 4; ++c) {
          const int q = (wave - 4) * 4 + c;
          const int Y = (q << 10) | (lane << 4);
          const int Ys = Y ^ (((Y >> 7) & 7) << 4);
          const int row = Y >> 7;
          gload_lds16((const char*)vpan + (size_t)row * 2048 + ((size_t)keybase2 << 1) + (Ys & 127),
                      (char*)&Vs[buf ^ 1][0][0] + (q << 10));
        }
        // outstanding: V(t) 4 + V(t+1) 4 -> retire the 4 oldest = V(t)
        asm volatile("s_waitcnt vmcnt(4)" ::: "memory");
      }
    } else {
      asm volatile("s_waitcnt vmcnt(0)" ::: "memory");
    }
    __builtin_amdgcn_sched_barrier(0);
    __builtin_amdgcn_s_barrier();

    const int keybase = t * 64;
    const char* ksb = (const char*)&Ks[buf][0][0];
    const char* vsb = (const char*)&Vs[buf][0][0];

    // ---- S = Q K^T (K tile from swizzled LDS) ----
    f32x4 s[4] = {};
    __builtin_amdgcn_s_setprio(1);
#pragma unroll
    for (int tile = 0; tile < 4; ++tile) {
      const int row = tile * 16 + lrow;
      const int sw = (row & 7) << 4;
      const bf16x8 kf0 = *(const bf16x8*)(ksb + ((row * 128 + lgrp * 16) ^ sw));
      const bf16x8 kf1 = *(const bf16x8*)(ksb + ((row * 128 + 64 + lgrp * 16) ^ sw));
      s[tile] = __builtin_amdgcn_mfma_f32_16x16x32_bf16(qf[0], kf0, s[tile], 0, 0, 0);
      s[tile] = __builtin_amdgcn_mfma_f32_16x16x32_bf16(qf[1], kf1, s[tile], 0, 0, 0);
    }
    __builtin_amdgcn_s_setprio(0);
    // ---- bias + exp + P-write directly from C-layout registers ----
#pragma unroll
    for (int tile = 0; tile < 4; ++tile) {
      const int key = keybase + tile * 16 + lrow;
      const int ki = max(key - 1, 0);
      const int kpart = (ki >> 5) * 63 + (ki & 31);
      const bool kcls = (key == 0);
#pragma unroll
      for (int reg = 0; reg < 4; ++reg) {
        const float bias = (qclsR[reg] || kcls) ? bias0 : bf2f(tab[AlocR[reg] - kpart]);
        const float p = __expf(s[tile][reg] + bias);
        psum[reg] += p;
        pl[lgrp * 4 + reg][tile * 16 + lrow] = f2bf(p);
      }
    }
    // ---- O += P V (V tile from swizzled LDS) ----
    __builtin_amdgcn_s_setprio(1);
#pragma unroll
    for (int ch = 0; ch < 2; ++ch) {
      const bf16x8 pf = *(const bf16x8*)(&pl[lrow][ch * 32 + lgrp * 8]);
#pragma unroll
      for (int dt = 0; dt < 4; ++dt) {
        const int row = dt * 16 + lrow;
        const bf16x8 vf = *(const bf16x8*)(vsb + ((row * 128 + ch * 64 + lgrp * 16) ^ ((row & 7) << 4)));
        o[dt] = __builtin_amdgcn_mfma_f32_16x16x32_bf16(pf, vf, o[dt], 0, 0, 0);
      }
    }
    __builtin_amdgcn_s_setprio(0);
    // all LDS reads of buf must retire before any wave's next stage overwrites it
    asm volatile("s_waitcnt lgkmcnt(0)" ::: "memory");
    __builtin_amdgcn_sched_barrier(0);
    __builtin_amdgcn_s_barrier();
  }

  // ---- deferred row-sum: reduce psum over the 16 lanes of this lgrp ----
#pragma unroll
  for (int reg = 0; reg < 4; ++reg) {
    float v = psum[reg];
    v += __shfl_xor(v, 1);
    v += __shfl_xor(v, 2);
    v += __shfl_xor(v, 4);
    v += __shfl_xor(v, 8);
    psum[reg] = v;
  }

  // ---- tail: key 1024 (image key 1023: ky=31, kx=31) ----
  float ptail;
  {
    const u16* k1p = qkvbf + (size_t)(b * N_ + 1024) * K3_ + 512 + h * D_;
    const bf16x8 k10 = *(const bf16x8*)(k1p + lgrp * 8);
    const bf16x8 k11 = *(const bf16x8*)(k1p + 32 + lgrp * 8);
    float part = 0.f;
#pragma unroll
    for (int i = 0; i < 8; ++i)
      part += bf2f((u16)qf[0][i]) * bf2f((u16)k10[i]) + bf2f((u16)qf[1][i]) * bf2f((u16)k11[i]);
    part += __shfl_xor(part, 16);
    part += __shfl_xor(part, 32);
    // anchor for q-row = this lane's lrow (row-major tail mapping)
    const int q_s = min(qbase + lrow, N_ - 1);
    const int qi_s = max(q_s - 1, 0);
    const int Aloc_s = ((qi_s >> 5) - qymin + 31) * 63 + (qi_s & 31) + 31;
    const float btail = (q_s == 0) ? bias0 : bf2f(tab[Aloc_s - 31 * 63 - 31]);
    ptail = __expf(part + btail);
  }

  float v1024[4];
#pragma unroll
  for (int dt = 0; dt < 4; ++dt)
    v1024[dt] = bf2f(qkvbf[(size_t)(b * N_ + 1024) * K3_ + 1024 + h * D_ + dt * 16 + lrow]);

#pragma unroll
  for (int reg = 0; reg < 4; ++reg) {
    const float pr = __shfl(ptail, lgrp * 4 + reg);
    const int qrow = qbase + lgrp * 4 + reg;
    if (qrow >= N_) continue;
    const float inv = 1.0f / (psum[reg] + pr);
    u16* op = attnout + (size_t)(b * N_ + qrow) * C_ + h * D_ + lrow;
#pragma unroll
    for (int dt = 0; dt < 4; ++dt)
      op[dt * 16] = f2bf((o[dt][reg] + pr * v1024[dt]) * inv);
  }
}

// ---------------------------------------------------------------------------
// Plan path (f64) — exact discrete indices. q0 fused into QKV GEMM; u fused
// into pack_kv; logit fused into attn; softmax fused into proj.
// ---------------------------------------------------------------------------
__global__ __launch_bounds__(256) void plan_cls_kernel(const double* __restrict__ lgt,
                                                       const double* __restrict__ mxz,
                                                       double* __restrict__ cls) {
  const int idx = blockIdx.x * 256 + threadIdx.x;
  const int b = idx >> 10, i = idx & 1023;
  double s = 0.0;
  for (int h = 0; h < 8; ++h) {
    const int bh = b * 8 + h;
    s += exp(lgt[(size_t)bh * N_ + 1 + i] - mxz[bh]) / mxz[64 + bh];
  }
  cls[idx] = s / 8.0;
}

// ---------------------------------------------------------------------------
// JAX threefry2x32 (20 rounds), exact
// ---------------------------------------------------------------------------
__device__ inline void tf2x32(unsigned k0, unsigned k1, unsigned& x0, unsigned& x1) {
  const unsigned ks2 = k0 ^ k1 ^ 0x1BD11BDAu;
  const int r0[4] = {13, 15, 26, 6};
  const int r1[4] = {17, 29, 16, 24};
  x0 += k0; x1 += k1;
#pragma unroll
  for (int i = 0; i < 4; ++i) { x0 += x1; x1 = (x1 << r0[i]) | (x1 >> (32 - r0[i])); x1 ^= x0; }
  x0 += k1; x1 += ks2 + 1u;
#pragma unroll
  for (int i = 0; i < 4; ++i) { x0 += x1; x1 = (x1 << r1[i]) | (x1 >> (32 - r1[i])); x1 ^= x0; }
  x0 += ks2; x1 += k0 + 2u;
#pragma unroll
  for (int i = 0; i < 4; ++i) { x0 += x1; x1 = (x1 << r0[i]) | (x1 >> (32 - r0[i])); x1 ^= x0; }
  x0 += k0; x1 += k1 + 3u;
#pragma unroll
  for (int i = 0; i < 4; ++i) { x0 += x1; x1 = (x1 << r1[i]) | (x1 >> (32 - r1[i])); x1 ^= x0; }
  x0 += k1; x1 += ks2 + 4u;
#pragma unroll
  for (int i = 0; i < 4; ++i) { x0 += x1; x1 = (x1 << r0[i]) | (x1 >> (32 - r0[i])); x1 ^= x0; }
  x0 += ks2; x1 += k0 + 5u;
}

// ---------------------------------------------------------------------------
// Fused plan tail v2: register bitonic sort (wave-internal phases j<64 via
// shfl_xor, comparator EXACTLY preserved -> bit-identical permutation; only
// 10 cross-wave phases touch LDS) + batched counts (per-batch f64 reduction
// TREES preserved exactly; barriers 48 -> 3). Threefry tail unchanged.
// ---------------------------------------------------------------------------
__global__ __launch_bounds__(1024) void plan_tail_kernel(
    const double* __restrict__ cls, const float* __restrict__ tw,
    int* __restrict__ scal, int* __restrict__ sel, int* __restrict__ ii) {
  __shared__ double sv[1024];
  __shared__ int sid[1024];
  __shared__ double dred8[8][16];
  __shared__ double mred8[8][16];
  __shared__ int ired8[8][16];
  __shared__ double stats2[8][2];
  __shared__ int sc3[3];
  const int t = threadIdx.x;
  const int wid = t >> 6, lane = t & 63;

  // ---- bitonic sort (batch 0), values in registers ----
  double v = cls[t];
  int idx = t;
  for (int k = 2; k <= 1024; k <<= 1) {
    for (int j = k >> 1; j > 0; j >>= 1) {
      const bool desc = ((t & k) == 0);     // same for both partners (j < k)
      const bool iAmLow = (t & j) == 0;
      double ov;
      int oi;
      if (j >= 64) {
        sv[t] = v;
        sid[t] = idx;
        __syncthreads();
        ov = sv[t ^ j];
        oi = sid[t ^ j];
        __syncthreads();
      } else {
        ov = __shfl_xor(v, j);
        oi = __shfl_xor(idx, j);
      }
      // myFirst == original aFirst evaluated from this thread's perspective
      const bool myFirst = (v > ov) || (v == ov && idx < oi);
      const bool keepMine = desc ? (iAmLow == myFirst) : (iAmLow != myFirst);
      if (!keepMine) { v = ov; idx = oi; }
    }
  }
  sel[t] = idx;

  // ---- counts: all 8 batches, trees EXACTLY as the split version ----
  double val8[8];
#pragma unroll
  for (int b = 0; b < 8; ++b) val8[b] = cls[b * 1024 + t];
#pragma unroll
  for (int b = 0; b < 8; ++b) {
    double s = val8[b];
#pragma unroll
    for (int o = 32; o; o >>= 1) s += __shfl_down(s, o);
    if (lane == 0) dred8[b][wid] = s;
    double mv = val8[b];
#pragma unroll
    for (int o = 32; o; o >>= 1) mv = fmax(mv, __shfl_down(mv, o));
    if (lane == 0) mred8[b][wid] = mv;
  }
  __syncthreads();
  if (t < 8) {
    double tot = 0;
    for (int i = 0; i < 16; ++i) tot += dred8[t][i];
    stats2[t][0] = tot / 1024.0;
    double mx = mred8[t][0];
    for (int i = 1; i < 16; ++i) mx = fmax(mx, mred8[t][i]);
    stats2[t][1] = mx;
  }
  __syncthreads();
#pragma unroll
  for (int b = 0; b < 8; ++b) {
    int c = (val8[b] >= stats2[b][0] && val8[b] <= stats2[b][1]) ? 1 : 0;
#pragma unroll
    for (int o = 32; o; o >>= 1) c += __shfl_down(c, o);
    if (lane == 0) ired8[b][wid] = c;
  }
  __syncthreads();

  if (t == 0) {
    int maxv = 0;
    double sum = 0.0;
    for (int b = 0; b < 8; ++b) {
      int cc = 0;
      for (int i = 0; i < 16; ++i) cc += ired8[b][i];
      maxv = max(maxv, cc);
      sum += (double)cc;
    }
    const double T = sum / 8.0;
    const double sig = 1.0 / (1.0 + exp(-((double)maxv - T) / 8.0));
    const double keepf = 1024.0 * (0.6 + (1.0 - 0.6) * sig);
    const int keep = __double2int_rn(keepf);
    const int remaining = 1024 - keep;
    const float t0 = tw[0], t1 = tw[1];
    const float mw = fmaxf(t0, t1);
    const float e0 = expf(t0 - mw), e1 = expf(t1 - mw);
    const float w0 = e0 / (e0 + e1);
    const int nt = (int)(w0 * (float)remaining);
    const int ni = remaining - nt;
    scal[0] = keep; scal[1] = nt; scal[2] = ni;
    sc3[0] = keep; sc3[1] = nt; sc3[2] = ni;
  }
  __syncthreads();

  const int ni = sc3[2];
  const int size = 8 * ni;
  const unsigned span = 1023u;
  unsigned mult = 65536u % span;
  mult = (mult * mult) % span;
  unsigned f0 = 0u, f1 = 1u;
  tf2x32(0u, 1234u, f0, f1);
#if PARTITIONABLE
  unsigned k1a = 0u, k1b = 0u;
  tf2x32(f0, f1, k1a, k1b);
  unsigned k2a = 0u, k2b = 1u;
  tf2x32(f0, f1, k2a, k2b);
  for (int i = t; i < size; i += 1024) {
    unsigned h0 = 0u, h1 = (unsigned)i;
    tf2x32(k1a, k1b, h0, h1);
    const unsigned hb = h0 ^ h1;
    unsigned l0 = 0u, l1 = (unsigned)i;
    tf2x32(k2a, k2b, l0, l1);
    const unsigned lb = l0 ^ l1;
    ii[i] = (int)(((hb % span) * mult + (lb % span)) % span);
  }
#else
  unsigned a0 = 0u, a1 = 2u;
  tf2x32(f0, f1, a0, a1);
  unsigned b0 = 1u, b1 = 3u;
  tf2x32(f0, f1, b0, b1);
  const int half = size >> 1;
  for (int i = t; i < half; i += 1024) {
    unsigned h0 = (unsigned)i, h1 = (unsigned)(i + half);
    tf2x32(a0, b0, h0, h1);
    unsigned l0 = (unsigned)i, l1 = (unsigned)(i + half);
    tf2x32(a1, b1, l0, l1);
    ii[i]        = (int)(((h0 % span) * mult + (l0 % span)) % span);
    ii[i + half] = (int)(((h1 % span) * mult + (l1 % span)) % span);
  }
#endif
}

// ---------------------------------------------------------------------------
// Fused assemble + LN2: x1 = x + gathered_src; x1n_bf = LN(x1)
// ---------------------------------------------------------------------------
__global__ __launch_bounds__(256) void assemble_ln_kernel(
    const float* __restrict__ x, const float* __restrict__ xn,
    const float* __restrict__ xo, const int* __restrict__ scal,
    const int* __restrict__ sel, const int* __restrict__ ii,
    const float* __restrict__ w, const float* __restrict__ bb,
    float* __restrict__ x1, u16* __restrict__ ob) {
  __shared__ float red[4];
  const int blk = blockIdx.x;
  const int b = blk / N_, tok = blk % N_;
  const int keep = scal[0], nt = scal[1], ni = scal[2];
  const float* src;
  if (tok == 0) {
    src = xo + (size_t)(b * N_) * C_;
  } else if (tok <= keep) {
    src = xo + (size_t)(b * N_ + 1 + sel[tok - 1]) * C_;
  } else if (tok <= keep + nt) {
    src = xn + (size_t)(b * N_ + 1) * C_;
  } else {
    const int j = tok - 1 - keep - nt;
    src = xn + (size_t)(b * N_ + 2 + ii[b * ni + j]) * C_;
  }
  const int t = threadIdx.x;
  const size_t o = (size_t)blk * C_;
  const float v0 = x[o + t] + src[t];
  const float v1 = x[o + t + 256] + src[t + 256];
  x1[o + t] = v0;
  x1[o + t + 256] = v1;
  float s = v0 + v1;
#pragma unroll
  for (int of = 32; of; of >>= 1) s += __shfl_down(s, of);
  if ((t & 63) == 0) red[t >> 6] = s;
  __syncthreads();
  const float mean = (red[0] + red[1] + red[2] + red[3]) * (1.0f / 512.0f);
  __syncthreads();
  const float d0 = v0 - mean, d1 = v1 - mean;
  float q = d0 * d0 + d1 * d1;
#pragma unroll
  for (int of = 32; of; of >>= 1) q += __shfl_down(q, of);
  if ((t & 63) == 0) red[t >> 6] = q;
  __syncthreads();
  const float var = (red[0] + red[1] + red[2] + red[3]) * (1.0f / 512.0f);
  const float inv = 1.0f / sqrtf(var + 1e-5f);
  ob[o + t] = f2bf(d0 * inv * w[t] + bb[t]);
  ob[o + t + 256] = f2bf(d1 * inv * w[t + 256] + bb[t + 256]);
}

// ---------------------------------------------------------------------------
// Host launcher
// ---------------------------------------------------------------------------
extern "C" void kernel_launch(void* const* d_in, const int* in_sizes, int n_in,
                              void* d_out, int out_size, void* d_ws, size_t ws_size,
                              hipStream_t stream) {
  (void)in_sizes; (void)n_in; (void)out_size; (void)ws_size;
  const float* x     = (const float*)d_in[0];
  const float* ln1w  = (const float*)d_in[1];
  const float* ln1b  = (const float*)d_in[2];
  const float* qkvw  = (const float*)d_in[3];
  const float* rpb   = (const float*)d_in[4];
  const float* projw = (const float*)d_in[5];
  const float* projb = (const float*)d_in[6];
  const float* tw    = (const float*)d_in[7];
  const float* ln2w  = (const float*)d_in[8];
  const float* ln2b  = (const float*)d_in[9];
  const float* fc1w  = (const float*)d_in[10];
  const float* fc1b  = (const float*)d_in[11];
  const float* fc2w  = (const float*)d_in[12];
  const float* fc2b  = (const float*)d_in[13];
  float* out = (float*)d_out;
  char* base = (char*)d_ws;

  float* xn       = (float*)(base + BYTE_XN);
  u16*   qkv_bf   = (u16*)(base + BYTE_QKVBF);
  u16*   xn_bf    = (u16*)(base + BYTE_XNBF);
  u16*   hbuf     = (u16*)(base + BYTE_HBUF);
  u16*   wq_bf    = (u16*)(base + BYTE_WTAIL);
  u16*   wp_bf    = wq_bf + K3_ * C_;
  u16*   w1_bf    = wp_bf + C_ * C_;
  u16*   w2_bf    = w1_bf + F_ * C_;
  u16*   attn_bf  = (u16*)(base + BYTE_ATTNBF);
  u16*   x1n_bf   = (u16*)(base + BYTE_X1NBF);
  float* xo       = (float*)(base + BYTE_XO);
  u16*   kbuf     = (u16*)(base + BYTE_X1);
  u16*   vbuf     = kbuf + (size_t)B_ * NH_ * 1024 * 64;
  float* x1       = (float*)(base + BYTE_X1);

  char* pb = base + PLAN_BYTE;
  double* q0  = (double*)pb;
  double* u   = q0 + 4096;
  double* lgt = u + 32768;
  double* mxz = lgt + 65600;
  double* cls = mxz + 128;
  int* counts = (int*)(cls + 8192);
  int* scal   = counts + 8;
  int* sel    = scal + 4;
  int* iibuf  = sel + 1024;

  // 1. fused LN1 (-> xn f32 + xn_bf) + all weight conversions, one launch
  ln_wconv_kernel<<<ROWS_ + WCONV_BLKS_, 256, 0, stream>>>(
      x, ln1w, ln1b, xn, xn_bf,
      qkvw, projw, fc1w, fc2w, wq_bf, wp_bf, w1_bf, w2_bf);
  // 2. QKV GEMM (BN=128, grid 780) + 16 fused plan_q0 blocks (bit-exact)
  gemm_bf_kernel<128, 0, false, true, true, true, false><<<65 * 12 + 16, 256, 0, stream>>>(
      xn_bf, wq_bf, nullptr, nullptr, qkv_bf, ROWS_, C_, K3_, 65 * 12,
      xn, qkvw, q0, nullptr, nullptr);
  // 3. dense K/V^T packs (1D grid 1024) + 128 fused plan_u blocks (bit-exact)
  pack_kv_kernel<<<1024 + 128, 256, 0, stream>>>(
      qkv_bf, kbuf, vbuf, qkvw, q0, u, 1024);
  // 4. MFMA flash attention v11 (704 blocks) + 48 fused plan_logit blocks
  //    (head-split threads halve the serial f64 chain; 752 <= 768 single fill)
  attn_mfma_kernel<<<11 * NH_ * B_ + 48, 384, 0, stream>>>(
      qkv_bf, kbuf, vbuf, rpb, attn_bf, xn, u, lgt, 11 * NH_ * B_);
  // 5. proj (BN=64, grid 520) + 64 fused plan_softmax blocks (bit-exact;
  //    584 <= 768 single fill)
  gemm_bf_kernel<64, 0, false, false, false, false, true><<<65 * 8 + 64, 256, 0, stream>>>(
      attn_bf, wp_bf, projb, nullptr, xo, ROWS_, C_, C_, 65 * 8,
      nullptr, nullptr, nullptr, lgt, mxz);
  // 6. plan cls (needs mxz) -> cls  [32 blocks: parallelism-preserving]
  plan_cls_kernel<<<32, 256, 0, stream>>>(lgt, mxz, cls);
  // 7. plan tail (sort + counts + threefry) -> scal/sel/ii
  plan_tail_kernel<<<1, 1024, 0, stream>>>(cls, tw, scal, sel, iibuf);
  // 8. fused assemble + residual + LN2 -> x1 f32 + x1n_bf
  assemble_ln_kernel<<<ROWS_, 256, 0, stream>>>(
      x, xn, xo, scal, sel, iibuf, ln2w, ln2b, x1, x1n_bf);
  // 9. FC1 + exact GELU -> hbuf bf16 — BN=128, grid 1040
  gemm_bf_kernel<128, 1, false, true, false, false, false><<<65 * 16, 256, 0, stream>>>(
      x1n_bf, w1_bf, fc1b, nullptr, hbuf, ROWS_, C_, F_, 65 * 16,
      nullptr, nullptr, nullptr, nullptr, nullptr);
  // 10. FC2 + bias + residual -> out f32 — BN=64, grid 520
  gemm_bf_kernel<64, 0, true, false, false, false, false><<<65 * 8, 256, 0, stream>>>(
      hbuf, w2_bf, fc2b, x1, out, ROWS_, F_, C_, 65 * 8,
      nullptr, nullptr, nullptr, nullptr, nullptr);
}

// Round 22
// 302.792 us; speedup vs baseline: 1.0746x; 1.0034x over previous
//
#include <hip/hip_runtime.h>
#include <cmath>

#define PARTITIONABLE 1

// ---------------------------------------------------------------------------
// Problem constants (B=8, S=32 -> N=1025, C=512, NH=8, D=64)
// ---------------------------------------------------------------------------
constexpr int B_ = 8;
constexpr int N_ = 1025;
constexpr int C_ = 512;
constexpr int NH_ = 8;
constexpr int D_ = 64;
constexpr int K3_ = 1536;   // 3*C
constexpr int F_ = 2048;    // 4*C
constexpr int ROWS_ = B_ * N_;  // 8200
constexpr int NXCD_ = 8;
constexpr int WQ_BLKS_ = (K3_ * C_) / 1024;                      // 768 (qkv w only)
constexpr int WTAIL_BLKS_ = (C_ * C_ + F_ * C_ + C_ * F_) / 1024;  // 2304 (proj/fc1/fc2)

// ---------------------------------------------------------------------------
// Workspace byte offsets — round-2-proven envelope [0, ~118.5MB)
// ---------------------------------------------------------------------------
constexpr size_t BYTE_XN      = 0;              // xn f32            16,793,600
constexpr size_t BYTE_QKVBF   = 16793600;       // qkv bf16          25,190,400
constexpr size_t BYTE_XNBF    = 41984000;       // xn bf16            8,396,800
constexpr size_t BYTE_HBUF    = 16793600;       // h bf16 (aliases qkv_bf+xn_bf)
constexpr size_t BYTE_WTAIL   = 60882944;       // bf16 weights       6,291,456
constexpr size_t BYTE_ATTNBF  = 67174400;       // attn out bf16      8,396,800
constexpr size_t BYTE_X1NBF   = 75571200;       // ln2 out bf16       8,396,800
constexpr size_t BYTE_XO      = 83968000;       // xo f32            16,793,600
constexpr size_t BYTE_X1      = 100761600;      // kb+vb (attn) then x1 f32  16,793,600
constexpr size_t PLAN_BYTE    = 117555200;      // plan scratch ~0.9 MB

typedef unsigned short u16;
typedef __attribute__((ext_vector_type(4))) unsigned short u16x4;
typedef __attribute__((ext_vector_type(8))) short bf16x8;
typedef __attribute__((ext_vector_type(4))) float f32x4;

__device__ inline u16 f2bf(float f) {
  unsigned u = __float_as_uint(f);
  u = (u + 0x7FFFu + ((u >> 16) & 1u)) >> 16;
  return (u16)u;
}
__device__ inline float bf2f(u16 u) { return __uint_as_float(((unsigned)u) << 16); }

// Bijective XCD-aware block remap: each XCD gets a contiguous logical chunk.
__device__ inline int xcd_swz(int bid, int nwg) {
  const int xcd = bid % NXCD_, i = bid / NXCD_;
  const int q = nwg / NXCD_, r = nwg % NXCD_;
  const int base = (xcd < r) ? xcd * (q + 1) : r * (q + 1) + (xcd - r) * q;
  return base + i;
}

// async global->LDS, 16B per lane (lds dst must be wave-uniform base)
__device__ inline void gload_lds16(const void* g, void* l) {
  __builtin_amdgcn_global_load_lds(
      (const __attribute__((address_space(1))) void*)g,
      (__attribute__((address_space(3))) void*)l, 16, 0, 0);
}

// ---------------------------------------------------------------------------
// Fused LN1 + QKV-weight bf16 conversion (r22: proj/fc1/fc2 weight conv
// relocated into the QKV GEMM launch — only wq must precede launch 2).
// Blocks [0, ROWS_): LayerNorm row; blocks [ROWS_, ROWS_+768): wq conv.
// ---------------------------------------------------------------------------
__global__ __launch_bounds__(256) void ln_wconv_kernel(
    const float* __restrict__ x, const float* __restrict__ w,
    const float* __restrict__ b, float* __restrict__ of, u16* __restrict__ ob,
    const float* __restrict__ w0, u16* __restrict__ o0) {
  __shared__ float red[4];
  if (blockIdx.x >= ROWS_) {
    const int idx4 = ((blockIdx.x - ROWS_) * 256 + threadIdx.x) * 4;
    const float4 v = *(const float4*)(w0 + idx4);
    u16x4 r;
    r.x = f2bf(v.x); r.y = f2bf(v.y); r.z = f2bf(v.z); r.w = f2bf(v.w);
    *(u16x4*)(o0 + idx4) = r;
    return;
  }
  const int r = blockIdx.x;
  const int t = threadIdx.x;
  const float* xr = x + (size_t)r * C_;
  float v0 = xr[t], v1 = xr[t + 256];
  float s = v0 + v1;
#pragma unroll
  for (int o = 32; o; o >>= 1) s += __shfl_down(s, o);
  if ((t & 63) == 0) red[t >> 6] = s;
  __syncthreads();
  const float mean = (red[0] + red[1] + red[2] + red[3]) * (1.0f / 512.0f);
  __syncthreads();
  const float d0 = v0 - mean, d1 = v1 - mean;
  float q = d0 * d0 + d1 * d1;
#pragma unroll
  for (int o = 32; o; o >>= 1) q += __shfl_down(q, o);
  if ((t & 63) == 0) red[t >> 6] = q;
  __syncthreads();
  const float var = (red[0] + red[1] + red[2] + red[3]) * (1.0f / 512.0f);
  const float inv = 1.0f / sqrtf(var + 1e-5f);
  const float r0 = d0 * inv * w[t] + b[t];
  const float r1 = d1 * inv * w[t + 256] + b[t + 256];
  of[(size_t)r * C_ + t] = r0;
  of[(size_t)r * C_ + t + 256] = r1;
  ob[(size_t)r * C_ + t] = f2bf(r0);
  ob[(size_t)r * C_ + t + 256] = f2bf(r1);
}

// ---------------------------------------------------------------------------
// bf16 MFMA GEMM: out[M,N] = A[M,K](bf16) @ W[N,K](bf16)^T (+bias)(+gelu)(+res)
// 128xBN tile (BN=128 or 64), BK=64, 4 waves (2x2), 64x(BN/2) per wave.
// Double-buffered LDS + counted-vmcnt pipeline (T3+T4).
// BN=128 for large-N GEMMs (QKV/FC1); BN=64 ONLY for N=512 outputs.
// PLANQ0 (QKV): guests [ngemm,ngemm+16) run plan_q0 verbatim (bit-exact);
//               guests [ngemm+16, ...) convert proj/fc1/fc2 weights to bf16
//               (independent work; consumed only by later launches).
// SMAX (proj): guest blocks run plan_softmax verbatim (bit-exact relocation).
// ---------------------------------------------------------------------------
template <int BN, int ACT, bool RES, bool OUTBF, bool QSCALE, bool PLANQ0, bool SMAX>
__global__ __launch_bounds__(256) void gemm_bf_kernel(
    const u16* __restrict__ A, const u16* __restrict__ W,
    const float* __restrict__ bias, const float* __restrict__ resid,
    void* __restrict__ outp, int M, int K, int Nout, int ngemm,
    const float* __restrict__ xnf, const float* __restrict__ qkvwf,
    double* __restrict__ q0o,
    const double* __restrict__ lgtp, double* __restrict__ mxzp,
    const float* __restrict__ ws1, const float* __restrict__ ws2,
    const float* __restrict__ ws3, u16* __restrict__ wd1,
    u16* __restrict__ wd2, u16* __restrict__ wd3) {
  constexpr int WN = BN / 2;       // wave cols: 64 or 32
  constexpr int NJ = WN / 16;      // j-tiles: 4 or 2
  constexpr int BPW = (BN / 8) / 4;  // B chunks per wave: 4 or 2
  __shared__ alignas(16) u16 As[2][128][64];
  __shared__ alignas(16) u16 Bs[2][BN][64];
  if (PLANQ0 && (int)blockIdx.x >= ngemm + 16) {
    // weight-conversion guests (proj/fc1/fc2), parallelism-preserving
    constexpr int n1 = C_ * C_, n2 = F_ * C_;
    const int idx4 = (((int)blockIdx.x - ngemm - 16) * 256 + threadIdx.x) * 4;
    const float* src;
    u16* dst;
    int off;
    if (idx4 < n1) { src = ws1; dst = wd1; off = idx4; }
    else if (idx4 < n1 + n2) { src = ws2; dst = wd2; off = idx4 - n1; }
    else { src = ws3; dst = wd3; off = idx4 - n1 - n2; }
    const float4 v = *(const float4*)(src + off);
    u16x4 r;
    r.x = f2bf(v.x); r.y = f2bf(v.y); r.z = f2bf(v.z); r.w = f2bf(v.w);
    *(u16x4*)(dst + off) = r;
    return;
  }
  if (PLANQ0 && (int)blockIdx.x >= ngemm) {
    const int idx = ((int)blockIdx.x - ngemm) * 256 + threadIdx.x;
    const int b = idx >> 9, hd = idx & 511;
    const float* xr = xnf + (size_t)(b * N_) * C_;
    const float* wr = qkvwf + (size_t)hd * C_;
    double s = 0.0;
    for (int c = 0; c < C_; c += 4) {
      const float4 xv = *(const float4*)(xr + c);
      const float4 wv = *(const float4*)(wr + c);
      s += (double)xv.x * (double)wv.x;
      s += (double)xv.y * (double)wv.y;
      s += (double)xv.z * (double)wv.z;
      s += (double)xv.w * (double)wv.w;
    }
    q0o[idx] = s * 0.125;
    return;
  }
  if (SMAX && (int)blockIdx.x >= ngemm) {
    // plan_softmax body, verbatim (bit-exact relocation)
    __shared__ double red[4];
    const int bh = (int)blockIdx.x - ngemm;
    const int t = threadIdx.x;
    const double* row = lgtp + (size_t)bh * N_;
    double m = -1e300;
    for (int i = t; i < N_; i += 256) m = fmax(m, row[i]);
#pragma unroll
    for (int o = 32; o; o >>= 1) m = fmax(m, __shfl_down(m, o));
    if ((t & 63) == 0) red[t >> 6] = m;
    __syncthreads();
    const double mx = fmax(fmax(red[0], red[1]), fmax(red[2], red[3]));
    __syncthreads();
    double z = 0.0;
    for (int i = t; i < N_; i += 256) z += exp(row[i] - mx);
#pragma unroll
    for (int o = 32; o; o >>= 1) z += __shfl_down(z, o);
    if ((t & 63) == 0) red[t >> 6] = z;
    __syncthreads();
    if (t == 0) {
      mxzp[bh] = mx;
      mxzp[64 + bh] = red[0] + red[1] + red[2] + red[3];
    }
    return;
  }
  const int tid = threadIdx.x;
  const int ny = Nout / BN;
  const int l = xcd_swz(blockIdx.x, ngemm);
  const int m0 = (l / ny) * 128, n0 = (l % ny) * BN;
  const int wave = tid >> 6, lane = tid & 63;
  const int wr = wave >> 1, wc = wave & 1;
  const int lrow = lane & 15, lgrp = lane >> 4;
  const int srow = lane >> 3;                              // row within chunk
  const int soff = (16 * (lane & 7)) ^ (16 * srow);        // swizzled src byte
  const int nk = K >> 6;

  auto stage = [&](int k0, int bufi) {
#pragma unroll
    for (int c = 0; c < 4; ++c) {
      const int q = wave * 4 + c;
      const int row = q * 8 + srow;
      int gm = m0 + row;
      if (gm >= M) gm = M - 1;
      gload_lds16((const char*)(A + (size_t)gm * K + k0) + soff,
                  (char*)&As[bufi][0][0] + (q << 10));
    }
#pragma unroll
    for (int c = 0; c < BPW; ++c) {
      const int q = wave * BPW + c;
      const int row = q * 8 + srow;
      gload_lds16((const char*)(W + (size_t)(n0 + row) * K + k0) + soff,
                  (char*)&Bs[bufi][0][0] + (q << 10));
    }
  };

  f32x4 acc[4][NJ] = {};
  stage(0, 0);
  int buf = 0;
  for (int t = 0; t < nk; ++t) {
    if (t + 1 < nk) {
      stage((t + 1) << 6, buf ^ 1);
      // outstanding = 2*(4+BPW); retire the oldest (4+BPW) = tile t
      if constexpr (BN == 128) asm volatile("s_waitcnt vmcnt(8)" ::: "memory");
      else                     asm volatile("s_waitcnt vmcnt(6)" ::: "memory");
    } else {
      asm volatile("s_waitcnt vmcnt(0)" ::: "memory");
    }
    __builtin_amdgcn_sched_barrier(0);
    __builtin_amdgcn_s_barrier();
    const char* asb = (const char*)&As[buf][0][0];
    const char* bsb = (const char*)&Bs[buf][0][0];
    __builtin_amdgcn_s_setprio(1);
#pragma unroll
    for (int ch = 0; ch < 2; ++ch) {
      bf16x8 af[4], bfv[NJ];
#pragma unroll
      for (int i = 0; i < 4; ++i) {
        const int ra = wr * 64 + i * 16 + lrow;
        const int cb = ch * 64 + lgrp * 16;
        af[i] = *(const bf16x8*)(asb + (ra << 7) + (cb ^ ((ra & 7) << 4)));
      }
#pragma unroll
      for (int j = 0; j < NJ; ++j) {
        const int rb = wc * WN + j * 16 + lrow;
        const int cb = ch * 64 + lgrp * 16;
        bfv[j] = *(const bf16x8*)(bsb + (rb << 7) + (cb ^ ((rb & 7) << 4)));
      }
#pragma unroll
      for (int i = 0; i < 4; ++i)
#pragma unroll
        for (int j = 0; j < NJ; ++j)
          acc[i][j] = __builtin_amdgcn_mfma_f32_16x16x32_bf16(af[i], bfv[j], acc[i][j], 0, 0, 0);
    }
    __builtin_amdgcn_s_setprio(0);
    asm volatile("s_waitcnt lgkmcnt(0)" ::: "memory");
    __builtin_amdgcn_sched_barrier(0);
    __builtin_amdgcn_s_barrier();
    buf ^= 1;
  }
#pragma unroll
  for (int i = 0; i < 4; ++i) {
#pragma unroll
    for (int j = 0; j < NJ; ++j) {
#pragma unroll
      for (int reg = 0; reg < 4; ++reg) {
        const int gm = m0 + wr * 64 + i * 16 + lgrp * 4 + reg;
        if (gm >= M) continue;
        const int gn = n0 + wc * WN + j * 16 + lrow;
        float v = acc[i][j][reg];
        if (bias) v += bias[gn];
        if (ACT == 1) v = 0.5f * v * (1.0f + erff(v * 0.70710678118654752440f));
        if (QSCALE) { if (gn < 512) v *= 0.125f; }
        if (RES) v += resid[(size_t)gm * Nout + gn];
        if (OUTBF) ((u16*)outp)[(size_t)gm * Nout + gn] = f2bf(v);
        else       ((float*)outp)[(size_t)gm * Nout + gn] = v;
      }
    }
  }
}

// ---------------------------------------------------------------------------
// Pack dense K [b][h][1024][64] and V^T [b][h][64][1024] from qkv_bf.
// 1D grid (blocks independent -> order-free flatten). Blocks >= npack run the
// plan_u body verbatim (bit-exact relocation), overlapping the pack.
// ---------------------------------------------------------------------------
__global__ __launch_bounds__(256) void pack_kv_kernel(const u16* __restrict__ qkvbf,
                                                      u16* __restrict__ kb,
                                                      u16* __restrict__ vb,
                                                      const float* __restrict__ qkvwf,
                                                      const double* __restrict__ q0,
                                                      double* __restrict__ u,
                                                      int npack) {
  if ((int)blockIdx.x >= npack) {
    const int idx = ((int)blockIdx.x - npack) * 256 + threadIdx.x;
    const int b = idx >> 12, h = (idx >> 9) & 7, c = idx & 511;
    double s = 0.0;
    for (int d = 0; d < D_; ++d)
      s += q0[b * 512 + h * 64 + d] * (double)qkvwf[(size_t)(512 + h * 64 + d) * C_ + c];
    u[idx] = s;
    return;
  }
  const int tile = blockIdx.x & 15, h = (blockIdx.x >> 4) & 7, b = (int)blockIdx.x >> 7;
  const int t = threadIdx.x;
  __shared__ u16 Vt[64][72];
  const int krow = tile * 64 + (t >> 2);
  const int dseg = (t & 3) * 16;
  const u16* p = qkvbf + (size_t)(b * N_ + krow) * K3_ + 512 + h * D_ + dseg;
  const bf16x8 k0 = *(const bf16x8*)p;
  const bf16x8 k1 = *(const bf16x8*)(p + 8);
  u16* kp = kb + ((size_t)(b * NH_ + h) * 1024 + krow) * 64 + dseg;
  *(bf16x8*)kp = k0;
  *(bf16x8*)(kp + 8) = k1;
  const bf16x8 v0 = *(const bf16x8*)(p + 512);
  const bf16x8 v1 = *(const bf16x8*)(p + 520);
  *(bf16x8*)(&Vt[t >> 2][dseg]) = v0;
  *(bf16x8*)(&Vt[t >> 2][dseg + 8]) = v1;
  __syncthreads();
  const int d = t >> 2, kseg = (t & 3) * 16;
  bf16x8 o0, o1;
#pragma unroll
  for (int i = 0; i < 8; ++i) o0[i] = (short)Vt[kseg + i][d];
#pragma unroll
  for (int i = 0; i < 8; ++i) o1[i] = (short)Vt[kseg + 8 + i][d];
  u16* vp = vb + ((size_t)(b * NH_ + h) * 64 + d) * 1024 + tile * 64 + kseg;
  *(bf16x8*)vp = o0;
  *(bf16x8*)(vp + 8) = o1;
}

// ---------------------------------------------------------------------------
// MFMA flash attention v11 + fused plan_logit guest blocks (r19: heads split
// across threads — each thread computes 4 heads for one row, halving the
// serial f64 chain; per-head c-loop order unchanged -> bit-exact. 48 guests
// (6/batch), hg = t/192 wave-uniform -> LDS reads stay broadcast).
// attn: 704 blocks, LDS 51.5KB, 3 blocks/CU; 704+48=752 <= 768 single fill.
// ---------------------------------------------------------------------------
__global__ __launch_bounds__(384) void attn_mfma_kernel(
    const u16* __restrict__ qkvbf, const u16* __restrict__ kb,
    const u16* __restrict__ vb, const float* __restrict__ rpb,
    u16* __restrict__ attnout,
    const float* __restrict__ xnf, const double* __restrict__ uu,
    double* __restrict__ lgt, int nattn) {
  __shared__ alignas(16) u16 Ks[2][64][64];   // 16KB, XOR-swizzled storage
  __shared__ alignas(16) u16 Vs[2][64][64];   // 16KB, XOR-swizzled storage
  __shared__ alignas(16) u16 Pl[6][16][74];   // 14.2KB; stride 74 breaks conflicts
  __shared__ u16 tab[36 * 63];                // 4.5KB bf16 bias table
  if ((int)blockIdx.x >= nattn) {
    // plan_logit guest: 6 blocks/batch; thread = (row rloc, head-group hg)
    double* ul = (double*)&Ks[0][0][0];       // 4096 f64 = 32KB (aliases Ks)
    const int lb = (int)blockIdx.x - nattn;   // [0, 48)
    const int b = lb / 6, part = lb % 6;
    for (int i = threadIdx.x; i < 4096; i += 384)
      ul[i] = uu[(size_t)b * 4096 + i];
    __syncthreads();
    const int rloc = threadIdx.x % 192;
    const int hg = threadIdx.x / 192;         // 0 or 1 (wave-uniform)
    const int m = part * 192 + rloc;
    if (m >= N_) return;
    const float* xr = xnf + (size_t)(b * N_ + m) * C_;
    const double* ulh = ul + hg * 4 * 512;
    double s[4] = {};
    for (int c = 0; c < C_; c += 4) {
      const float4 xv = *(const float4*)(xr + c);
#pragma unroll
      for (int hh = 0; hh < 4; ++hh) {
        s[hh] += (double)xv.x * ulh[hh * 512 + c];
        s[hh] += (double)xv.y * ulh[hh * 512 + c + 1];
        s[hh] += (double)xv.z * ulh[hh * 512 + c + 2];
        s[hh] += (double)xv.w * ulh[hh * 512 + c + 3];
      }
    }
#pragma unroll
    for (int hh = 0; hh < 4; ++hh)
      lgt[(size_t)(b * 8 + hg * 4 + hh) * N_ + m] = s[hh];
    return;
  }
  const int l = xcd_swz(blockIdx.x, nattn);  // logical = (b*8+h)*11 + qt
  const int qt = l % 11;
  const int bh = l / 11;
  const int h = bh & 7, b = bh >> 3;
  const int wave = threadIdx.x >> 6, lane = threadIdx.x & 63;
  const int lrow = lane & 15, lgrp = lane >> 4;
  const int qblk = qt * 96;
  const int qbase = qblk + wave * 16;

  const u16* kpan = kb + (size_t)(b * NH_ + h) * 1024 * 64;
  const u16* vpan = vb + (size_t)(b * NH_ + h) * 64 * 1024;

  // ---- issue async stage of tile 0 (waves 0-3: K, waves 4-5: V) ----
  if (wave < 4) {
#pragma unroll
    for (int c = 0; c < 2; ++c) {
      const int q = wave * 2 + c;
      const int Y = (q << 10) | (lane << 4);
      const int Ys = Y ^ (((Y >> 7) & 7) << 4);
      gload_lds16((const char*)kpan + Ys, (char*)&Ks[0][0][0] + (q << 10));
    }
  } else {
#pragma unroll
    for (int c = 0; c < 4; ++c) {
      const int q = (wave - 4) * 4 + c;
      const int Y = (q << 10) | (lane << 4);
      const int Ys = Y ^ (((Y >> 7) & 7) << 4);
      const int row = Y >> 7;
      gload_lds16((const char*)vpan + (size_t)row * 2048 + (Ys & 127),
                  (char*)&Vs[0][0][0] + (q << 10));
    }
  }

  // ---- stage rpb sub-table (all threads; bf16) ----
  const int qimin = max(qblk - 1, 0);
  const int qimax = min(qblk + 94, 1023);
  const int qymin = qimin >> 5;
  const int qymax = qimax >> 5;
  const int nrows = qymax - qymin + 32;   // dy in [qymin-31, qymax]  (<=36)
  for (int i = threadIdx.x; i < nrows * 63; i += 384)
    tab[i] = f2bf(rpb[(size_t)(qymin * 63 + i) * NH_ + h]);

  u16 (*pl)[74] = Pl[wave];

  // Q fragments (pre-scaled by 1/8 in the QKV GEMM epilogue)
  bf16x8 qf[2];
  {
    const int qrow = min(qbase + lrow, N_ - 1);
    const u16* qp = qkvbf + (size_t)(b * N_ + qrow) * K3_ + h * D_;
    qf[0] = *(const bf16x8*)(qp + lgrp * 8);
    qf[1] = *(const bf16x8*)(qp + 32 + lgrp * 8);
  }

  const float bias0 = rpb[h];

  // Per-owned-q-row (C-layout rows lgrp*4+reg) bias table anchors
  int AlocR[4];
  bool qclsR[4];
#pragma unroll
  for (int reg = 0; reg < 4; ++reg) {
    const int qr = min(qbase + lgrp * 4 + reg, N_ - 1);
    const int qi = max(qr - 1, 0);
    AlocR[reg] = ((qi >> 5) - qymin + 31) * 63 + (qi & 31) + 31;
    qclsR[reg] = (qr == 0);
  }

  f32x4 psum = {0.f, 0.f, 0.f, 0.f};
  f32x4 o[4] = {};

  __syncthreads();  // full drain: tile-0 stage + tab complete, visible to all

  for (int t = 0; t < 16; ++t) {
    const int buf = t & 1;
    // ---- issue async stage of tile t+1 into buf^1 (role-split) ----
    if (t < 15) {
      const int keybase2 = (t + 1) * 64;
      if (wave < 4) {
#pragma unroll
        for (int c = 0; c < 2; ++c) {
          const int q = wave * 2 + c;
          const int Y = (q << 10) | (lane << 4);
          const int Ys = Y ^ (((Y >> 7) & 7) << 4);
          gload_lds16((const char*)kpan + ((size_t)keybase2 << 7) + Ys,
                      (char*)&Ks[buf ^ 1][0][0] + (q << 10));
        }
        // outstanding: K(t) 2 + K(t+1) 2 -> retire the 2 oldest = K(t)
        asm volatile("s_waitcnt vmcnt(2)" ::: "memory");
      } else {
#pragma unroll
        for (int c = 0; c < 4; ++c) {
          const int q = (wave - 4) * 4 + c;
          const int Y = (q << 10) | (lane << 4);
          const int Ys = Y ^ (((Y >> 7) & 7) << 4);
          const int row = Y >> 7;
          gload_lds16((const char*)vpan + (size_t)row * 2048 + ((size_t)keybase2 << 1) + (Ys & 127),
                      (char*)&Vs[buf ^ 1][0][0] + (q << 10));
        }
        // outstanding: V(t) 4 + V(t+1) 4 -> retire the 4 oldest = V(t)
        asm volatile("s_waitcnt vmcnt(4)" ::: "memory");
      }
    } else {
      asm volatile("s_waitcnt vmcnt(0)" ::: "memory");
    }
    __builtin_amdgcn_sched_barrier(0);
    __builtin_amdgcn_s_barrier();

    const int keybase = t * 64;
    const char* ksb = (const char*)&Ks[buf][0][0];
    const char* vsb = (const char*)&Vs[buf][0][0];

    // ---- S = Q K^T (K tile from swizzled LDS) ----
    f32x4 s[4] = {};
    __builtin_amdgcn_s_setprio(1);
#pragma unroll
    for (int tile = 0; tile < 4; ++tile) {
      const int row = tile * 16 + lrow;
      const int sw = (row & 7) << 4;
      const bf16x8 kf0 = *(const bf16x8*)(ksb + ((row * 128 + lgrp * 16) ^ sw));
      const bf16x8 kf1 = *(const bf16x8*)(ksb + ((row * 128 + 64 + lgrp * 16) ^ sw));
      s[tile] = __builtin_amdgcn_mfma_f32_16x16x32_bf16(qf[0], kf0, s[tile], 0, 0, 0);
      s[tile] = __builtin_amdgcn_mfma_f32_16x16x32_bf16(qf[1], kf1, s[tile], 0, 0, 0);
    }
    __builtin_amdgcn_s_setprio(0);
    // ---- bias + exp + P-write directly from C-layout registers ----
#pragma unroll
    for (int tile = 0; tile < 4; ++tile) {
      const int key = keybase + tile * 16 + lrow;
      const int ki = max(key - 1, 0);
      const int kpart = (ki >> 5) * 63 + (ki & 31);
      const bool kcls = (key == 0);
#pragma unroll
      for (int reg = 0; reg < 4; ++reg) {
        const float bias = (qclsR[reg] || kcls) ? bias0 : bf2f(tab[AlocR[reg] - kpart]);
        const float p = __expf(s[tile][reg] + bias);
        psum[reg] += p;
        pl[lgrp * 4 + reg][tile * 16 + lrow] = f2bf(p);
      }
    }
    // ---- O += P V (V tile from swizzled LDS) ----
    __builtin_amdgcn_s_setprio(1);
#pragma unroll
    for (int ch = 0; ch < 2; ++ch) {
      const bf16x8 pf = *(const bf16x8*)(&pl[lrow][ch * 32 + lgrp * 8]);
#pragma unroll
      for (int dt = 0; dt < 4; ++dt) {
        const int row = dt * 16 + lrow;
        const bf16x8 vf = *(const bf16x8*)(vsb + ((row * 128 + ch * 64 + lgrp * 16) ^ ((row & 7) << 4)));
        o[dt] = __builtin_amdgcn_mfma_f32_16x16x32_bf16(pf, vf, o[dt], 0, 0, 0);
      }
    }
    __builtin_amdgcn_s_setprio(0);
    // all LDS reads of buf must retire before any wave's next stage overwrites it
    asm volatile("s_waitcnt lgkmcnt(0)" ::: "memory");
    __builtin_amdgcn_sched_barrier(0);
    __builtin_amdgcn_s_barrier();
  }

  // ---- deferred row-sum: reduce psum over the 16 lanes of this lgrp ----
#pragma unroll
  for (int reg = 0; reg < 4; ++reg) {
    float v = psum[reg];
    v += __shfl_xor(v, 1);
    v += __shfl_xor(v, 2);
    v += __shfl_xor(v, 4);
    v += __shfl_xor(v, 8);
    psum[reg] = v;
  }

  // ---- tail: key 1024 (image key 1023: ky=31, kx=31) ----
  float ptail;
  {
    const u16* k1p = qkvbf + (size_t)(b * N_ + 1024) * K3_ + 512 + h * D_;
    const bf16x8 k10 = *(const bf16x8*)(k1p + lgrp * 8);
    const bf16x8 k11 = *(const bf16x8*)(k1p + 32 + lgrp * 8);
    float part = 0.f;
#pragma unroll
    for (int i = 0; i < 8; ++i)
      part += bf2f((u16)qf[0][i]) * bf2f((u16)k10[i]) + bf2f((u16)qf[1][i]) * bf2f((u16)k11[i]);
    part += __shfl_xor(part, 16);
    part += __shfl_xor(part, 32);
    // anchor for q-row = this lane's lrow (row-major tail mapping)
    const int q_s = min(qbase + lrow, N_ - 1);
    const int qi_s = max(q_s - 1, 0);
    const int Aloc_s = ((qi_s >> 5) - qymin + 31) * 63 + (qi_s & 31) + 31;
    const float btail = (q_s == 0) ? bias0 : bf2f(tab[Aloc_s - 31 * 63 - 31]);
    ptail = __expf(part + btail);
  }

  float v1024[4];
#pragma unroll
  for (int dt = 0; dt < 4; ++dt)
    v1024[dt] = bf2f(qkvbf[(size_t)(b * N_ + 1024) * K3_ + 1024 + h * D_ + dt * 16 + lrow]);

#pragma unroll
  for (int reg = 0; reg < 4; ++reg) {
    const float pr = __shfl(ptail, lgrp * 4 + reg);
    const int qrow = qbase + lgrp * 4 + reg;
    if (qrow >= N_) continue;
    const float inv = 1.0f / (psum[reg] + pr);
    u16* op = attnout + (size_t)(b * N_ + qrow) * C_ + h * D_ + lrow;
#pragma unroll
    for (int dt = 0; dt < 4; ++dt)
      op[dt * 16] = f2bf((o[dt][reg] + pr * v1024[dt]) * inv);
  }
}

// ---------------------------------------------------------------------------
// Plan path (f64) — exact discrete indices. q0 fused into QKV GEMM; u fused
// into pack_kv; logit fused into attn; softmax fused into proj.
// ---------------------------------------------------------------------------
__global__ __launch_bounds__(256) void plan_cls_kernel(const double* __restrict__ lgt,
                                                       const double* __restrict__ mxz,
                                                       double* __restrict__ cls) {
  const int idx = blockIdx.x * 256 + threadIdx.x;
  const int b = idx >> 10, i = idx & 1023;
  double s = 0.0;
  for (int h = 0; h < 8; ++h) {
    const int bh = b * 8 + h;
    s += exp(lgt[(size_t)bh * N_ + 1 + i] - mxz[bh]) / mxz[64 + bh];
  }
  cls[idx] = s / 8.0;
}

// ---------------------------------------------------------------------------
// JAX threefry2x32 (20 rounds), exact
// ---------------------------------------------------------------------------
__device__ inline void tf2x32(unsigned k0, unsigned k1, unsigned& x0, unsigned& x1) {
  const unsigned ks2 = k0 ^ k1 ^ 0x1BD11BDAu;
  const int r0[4] = {13, 15, 26, 6};
  const int r1[4] = {17, 29, 16, 24};
  x0 += k0; x1 += k1;
#pragma unroll
  for (int i = 0; i < 4; ++i) { x0 += x1; x1 = (x1 << r0[i]) | (x1 >> (32 - r0[i])); x1 ^= x0; }
  x0 += k1; x1 += ks2 + 1u;
#pragma unroll
  for (int i = 0; i < 4; ++i) { x0 += x1; x1 = (x1 << r1[i]) | (x1 >> (32 - r1[i])); x1 ^= x0; }
  x0 += ks2; x1 += k0 + 2u;
#pragma unroll
  for (int i = 0; i < 4; ++i) { x0 += x1; x1 = (x1 << r0[i]) | (x1 >> (32 - r0[i])); x1 ^= x0; }
  x0 += k0; x1 += k1 + 3u;
#pragma unroll
  for (int i = 0; i < 4; ++i) { x0 += x1; x1 = (x1 << r1[i]) | (x1 >> (32 - r1[i])); x1 ^= x0; }
  x0 += k1; x1 += ks2 + 4u;
#pragma unroll
  for (int i = 0; i < 4; ++i) { x0 += x1; x1 = (x1 << r0[i]) | (x1 >> (32 - r0[i])); x1 ^= x0; }
  x0 += ks2; x1 += k0 + 5u;
}

// ---------------------------------------------------------------------------
// Fused plan tail v2: register bitonic sort (wave-internal phases j<64 via
// shfl_xor, comparator EXACTLY preserved -> bit-identical permutation; only
// 10 cross-wave phases touch LDS) + batched counts (per-batch f64 reduction
// TREES preserved exactly; barriers 48 -> 3). Threefry tail unchanged.
// ---------------------------------------------------------------------------
__global__ __launch_bounds__(1024) void plan_tail_kernel(
    const double* __restrict__ cls, const float* __restrict__ tw,
    int* __restrict__ scal, int* __restrict__ sel, int* __restrict__ ii) {
  __shared__ double sv[1024];
  __shared__ int sid[1024];
  __shared__ double dred8[8][16];
  __shared__ double mred8[8][16];
  __shared__ int ired8[8][16];
  __shared__ double stats2[8][2];
  __shared__ int sc3[3];
  const int t = threadIdx.x;
  const int wid = t >> 6, lane = t & 63;

  // ---- bitonic sort (batch 0), values in registers ----
  double v = cls[t];
  int idx = t;
  for (int k = 2; k <= 1024; k <<= 1) {
    for (int j = k >> 1; j > 0; j >>= 1) {
      const bool desc = ((t & k) == 0);     // same for both partners (j < k)
      const bool iAmLow = (t & j) == 0;
      double ov;
      int oi;
      if (j >= 64) {
        sv[t] = v;
        sid[t] = idx;
        __syncthreads();
        ov = sv[t ^ j];
        oi = sid[t ^ j];
        __syncthreads();
      } else {
        ov = __shfl_xor(v, j);
        oi = __shfl_xor(idx, j);
      }
      // myFirst == original aFirst evaluated from this thread's perspective
      const bool myFirst = (v > ov) || (v == ov && idx < oi);
      const bool keepMine = desc ? (iAmLow == myFirst) : (iAmLow != myFirst);
      if (!keepMine) { v = ov; idx = oi; }
    }
  }
  sel[t] = idx;

  // ---- counts: all 8 batches, trees EXACTLY as the split version ----
  double val8[8];
#pragma unroll
  for (int b = 0; b < 8; ++b) val8[b] = cls[b * 1024 + t];
#pragma unroll
  for (int b = 0; b < 8; ++b) {
    double s = val8[b];
#pragma unroll
    for (int o = 32; o; o >>= 1) s += __shfl_down(s, o);
    if (lane == 0) dred8[b][wid] = s;
    double mv = val8[b];
#pragma unroll
    for (int o = 32; o; o >>= 1) mv = fmax(mv, __shfl_down(mv, o));
    if (lane == 0) mred8[b][wid] = mv;
  }
  __syncthreads();
  if (t < 8) {
    double tot = 0;
    for (int i = 0; i < 16; ++i) tot += dred8[t][i];
    stats2[t][0] = tot / 1024.0;
    double mx = mred8[t][0];
    for (int i = 1; i < 16; ++i) mx = fmax(mx, mred8[t][i]);
    stats2[t][1] = mx;
  }
  __syncthreads();
#pragma unroll
  for (int b = 0; b < 8; ++b) {
    int c = (val8[b] >= stats2[b][0] && val8[b] <= stats2[b][1]) ? 1 : 0;
#pragma unroll
    for (int o = 32; o; o >>= 1) c += __shfl_down(c, o);
    if (lane == 0) ired8[b][wid] = c;
  }
  __syncthreads();

  if (t == 0) {
    int maxv = 0;
    double sum = 0.0;
    for (int b = 0; b < 8; ++b) {
      int cc = 0;
      for (int i = 0; i < 16; ++i) cc += ired8[b][i];
      maxv = max(maxv, cc);
      sum += (double)cc;
    }
    const double T = sum / 8.0;
    const double sig = 1.0 / (1.0 + exp(-((double)maxv - T) / 8.0));
    const double keepf = 1024.0 * (0.6 + (1.0 - 0.6) * sig);
    const int keep = __double2int_rn(keepf);
    const int remaining = 1024 - keep;
    const float t0 = tw[0], t1 = tw[1];
    const float mw = fmaxf(t0, t1);
    const float e0 = expf(t0 - mw), e1 = expf(t1 - mw);
    const float w0 = e0 / (e0 + e1);
    const int nt = (int)(w0 * (float)remaining);
    const int ni = remaining - nt;
    scal[0] = keep; scal[1] = nt; scal[2] = ni;
    sc3[0] = keep; sc3[1] = nt; sc3[2] = ni;
  }
  __syncthreads();

  const int ni = sc3[2];
  const int size = 8 * ni;
  const unsigned span = 1023u;
  unsigned mult = 65536u % span;
  mult = (mult * mult) % span;
  unsigned f0 = 0u, f1 = 1u;
  tf2x32(0u, 1234u, f0, f1);
#if PARTITIONABLE
  unsigned k1a = 0u, k1b = 0u;
  tf2x32(f0, f1, k1a, k1b);
  unsigned k2a = 0u, k2b = 1u;
  tf2x32(f0, f1, k2a, k2b);
  for (int i = t; i < size; i += 1024) {
    unsigned h0 = 0u, h1 = (unsigned)i;
    tf2x32(k1a, k1b, h0, h1);
    const unsigned hb = h0 ^ h1;
    unsigned l0 = 0u, l1 = (unsigned)i;
    tf2x32(k2a, k2b, l0, l1);
    const unsigned lb = l0 ^ l1;
    ii[i] = (int)(((hb % span) * mult + (lb % span)) % span);
  }
#else
  unsigned a0 = 0u, a1 = 2u;
  tf2x32(f0, f1, a0, a1);
  unsigned b0 = 1u, b1 = 3u;
  tf2x32(f0, f1, b0, b1);
  const int half = size >> 1;
  for (int i = t; i < half; i += 1024) {
    unsigned h0 = (unsigned)i, h1 = (unsigned)(i + half);
    tf2x32(a0, b0, h0, h1);
    unsigned l0 = (unsigned)i, l1 = (unsigned)(i + half);
    tf2x32(a1, b1, l0, l1);
    ii[i]        = (int)(((h0 % span) * mult + (l0 % span)) % span);
    ii[i + half] = (int)(((h1 % span) * mult + (l1 % span)) % span);
  }
#endif
}

// ---------------------------------------------------------------------------
// Fused assemble + LN2: x1 = x + gathered_src; x1n_bf = LN(x1)
// ---------------------------------------------------------------------------
__global__ __launch_bounds__(256) void assemble_ln_kernel(
    const float* __restrict__ x, const float* __restrict__ xn,
    const float* __restrict__ xo, const int* __restrict__ scal,
    const int* __restrict__ sel, const int* __restrict__ ii,
    const float* __restrict__ w, const float* __restrict__ bb,
    float* __restrict__ x1, u16* __restrict__ ob) {
  __shared__ float red[4];
  const int blk = blockIdx.x;
  const int b = blk / N_, tok = blk % N_;
  const int keep = scal[0], nt = scal[1], ni = scal[2];
  const float* src;
  if (tok == 0) {
    src = xo + (size_t)(b * N_) * C_;
  } else if (tok <= keep) {
    src = xo + (size_t)(b * N_ + 1 + sel[tok - 1]) * C_;
  } else if (tok <= keep + nt) {
    src = xn + (size_t)(b * N_ + 1) * C_;
  } else {
    const int j = tok - 1 - keep - nt;
    src = xn + (size_t)(b * N_ + 2 + ii[b * ni + j]) * C_;
  }
  const int t = threadIdx.x;
  const size_t o = (size_t)blk * C_;
  const float v0 = x[o + t] + src[t];
  const float v1 = x[o + t + 256] + src[t + 256];
  x1[o + t] = v0;
  x1[o + t + 256] = v1;
  float s = v0 + v1;
#pragma unroll
  for (int of = 32; of; of >>= 1) s += __shfl_down(s, of);
  if ((t & 63) == 0) red[t >> 6] = s;
  __syncthreads();
  const float mean = (red[0] + red[1] + red[2] + red[3]) * (1.0f / 512.0f);
  __syncthreads();
  const float d0 = v0 - mean, d1 = v1 - mean;
  float q = d0 * d0 + d1 * d1;
#pragma unroll
  for (int of = 32; of; of >>= 1) q += __shfl_down(q, of);
  if ((t & 63) == 0) red[t >> 6] = q;
  __syncthreads();
  const float var = (red[0] + red[1] + red[2] + red[3]) * (1.0f / 512.0f);
  const float inv = 1.0f / sqrtf(var + 1e-5f);
  ob[o + t] = f2bf(d0 * inv * w[t] + bb[t]);
  ob[o + t + 256] = f2bf(d1 * inv * w[t + 256] + bb[t + 256]);
}

// ---------------------------------------------------------------------------
// Host launcher
// ---------------------------------------------------------------------------
extern "C" void kernel_launch(void* const* d_in, const int* in_sizes, int n_in,
                              void* d_out, int out_size, void* d_ws, size_t ws_size,
                              hipStream_t stream) {
  (void)in_sizes; (void)n_in; (void)out_size; (void)ws_size;
  const float* x     = (const float*)d_in[0];
  const float* ln1w  = (const float*)d_in[1];
  const float* ln1b  = (const float*)d_in[2];
  const float* qkvw  = (const float*)d_in[3];
  const float* rpb   = (const float*)d_in[4];
  const float* projw = (const float*)d_in[5];
  const float* projb = (const float*)d_in[6];
  const float* tw    = (const float*)d_in[7];
  const float* ln2w  = (const float*)d_in[8];
  const float* ln2b  = (const float*)d_in[9];
  const float* fc1w  = (const float*)d_in[10];
  const float* fc1b  = (const float*)d_in[11];
  const float* fc2w  = (const float*)d_in[12];
  const float* fc2b  = (const float*)d_in[13];
  float* out = (float*)d_out;
  char* base = (char*)d_ws;

  float* xn       = (float*)(base + BYTE_XN);
  u16*   qkv_bf   = (u16*)(base + BYTE_QKVBF);
  u16*   xn_bf    = (u16*)(base + BYTE_XNBF);
  u16*   hbuf     = (u16*)(base + BYTE_HBUF);
  u16*   wq_bf    = (u16*)(base + BYTE_WTAIL);
  u16*   wp_bf    = wq_bf + K3_ * C_;
  u16*   w1_bf    = wp_bf + C_ * C_;
  u16*   w2_bf    = w1_bf + F_ * C_;
  u16*   attn_bf  = (u16*)(base + BYTE_ATTNBF);
  u16*   x1n_bf   = (u16*)(base + BYTE_X1NBF);
  float* xo       = (float*)(base + BYTE_XO);
  u16*   kbuf     = (u16*)(base + BYTE_X1);
  u16*   vbuf     = kbuf + (size_t)B_ * NH_ * 1024 * 64;
  float* x1       = (float*)(base + BYTE_X1);

  char* pb = base + PLAN_BYTE;
  double* q0  = (double*)pb;
  double* u   = q0 + 4096;
  double* lgt = u + 32768;
  double* mxz = lgt + 65600;
  double* cls = mxz + 128;
  int* counts = (int*)(cls + 8192);
  int* scal   = counts + 8;
  int* sel    = scal + 4;
  int* iibuf  = sel + 1024;

  // 1. fused LN1 (-> xn f32 + xn_bf) + QKV-weight conversion only (r22)
  ln_wconv_kernel<<<ROWS_ + WQ_BLKS_, 256, 0, stream>>>(
      x, ln1w, ln1b, xn, xn_bf, qkvw, wq_bf);
  // 2. QKV GEMM (BN=128, grid 780) + 16 plan_q0 guests + 2304 weight-conv
  //    guests (proj/fc1/fc2 -> bf16; consumed only by later launches)
  gemm_bf_kernel<128, 0, false, true, true, true, false>
      <<<65 * 12 + 16 + WTAIL_BLKS_, 256, 0, stream>>>(
      xn_bf, wq_bf, nullptr, nullptr, qkv_bf, ROWS_, C_, K3_, 65 * 12,
      xn, qkvw, q0, nullptr, nullptr,
      projw, fc1w, fc2w, wp_bf, w1_bf, w2_bf);
  // 3. dense K/V^T packs (1D grid 1024) + 128 fused plan_u blocks (bit-exact)
  pack_kv_kernel<<<1024 + 128, 256, 0, stream>>>(
      qkv_bf, kbuf, vbuf, qkvw, q0, u, 1024);
  // 4. MFMA flash attention v11 (704 blocks) + 48 fused plan_logit blocks
  //    (head-split threads halve the serial f64 chain; 752 <= 768 single fill)
  attn_mfma_kernel<<<11 * NH_ * B_ + 48, 384, 0, stream>>>(
      qkv_bf, kbuf, vbuf, rpb, attn_bf, xn, u, lgt, 11 * NH_ * B_);
  // 5. proj (BN=64, grid 520) + 64 fused plan_softmax blocks (bit-exact;
  //    584 <= 768 single fill)
  gemm_bf_kernel<64, 0, false, false, false, false, true><<<65 * 8 + 64, 256, 0, stream>>>(
      attn_bf, wp_bf, projb, nullptr, xo, ROWS_, C_, C_, 65 * 8,
      nullptr, nullptr, nullptr, lgt, mxz,
      nullptr, nullptr, nullptr, nullptr, nullptr, nullptr);
  // 6. plan cls (needs mxz) -> cls  [32 blocks: parallelism-preserving]
  plan_cls_kernel<<<32, 256, 0, stream>>>(lgt, mxz, cls);
  // 7. plan tail (sort + counts + threefry) -> scal/sel/ii
  plan_tail_kernel<<<1, 1024, 0, stream>>>(cls, tw, scal, sel, iibuf);
  // 8. fused assemble + residual + LN2 -> x1 f32 + x1n_bf
  assemble_ln_kernel<<<ROWS_, 256, 0, stream>>>(
      x, xn, xo, scal, sel, iibuf, ln2w, ln2b, x1, x1n_bf);
  // 9. FC1 + exact GELU -> hbuf bf16 — BN=128, grid 1040
  gemm_bf_kernel<128, 1, false, true, false, false, false><<<65 * 16, 256, 0, stream>>>(
      x1n_bf, w1_bf, fc1b, nullptr, hbuf, ROWS_, C_, F_, 65 * 16,
      nullptr, nullptr, nullptr, nullptr, nullptr,
      nullptr, nullptr, nullptr, nullptr, nullptr, nullptr);
  // 10. FC2 + bias + residual -> out f32 — BN=64, grid 520
  gemm_bf_kernel<64, 0, true, false, false, false, false><<<65 * 8, 256, 0, stream>>>(
      hbuf, w2_bf, fc2b, x1, out, ROWS_, F_, C_, 65 * 8,
      nullptr, nullptr, nullptr, nullptr, nullptr,
      nullptr, nullptr, nullptr, nullptr, nullptr, nullptr);
}

// Round 23
// 302.539 us; speedup vs baseline: 1.0755x; 1.0008x over previous
//
#include <hip/hip_runtime.h>
#include <cmath>

#define PARTITIONABLE 1

// ---------------------------------------------------------------------------
// Problem constants (B=8, S=32 -> N=1025, C=512, NH=8, D=64)
// ---------------------------------------------------------------------------
constexpr int B_ = 8;
constexpr int N_ = 1025;
constexpr int C_ = 512;
constexpr int NH_ = 8;
constexpr int D_ = 64;
constexpr int K3_ = 1536;   // 3*C
constexpr int F_ = 2048;    // 4*C
constexpr int ROWS_ = B_ * N_;  // 8200
constexpr int NXCD_ = 8;
constexpr int WQ_BLKS_ = (K3_ * C_) / 1024;                      // 768 (qkv w only)
constexpr int WTAIL_BLKS_ = (C_ * C_ + F_ * C_ + C_ * F_) / 1024;  // 2304 (proj/fc1/fc2)

// ---------------------------------------------------------------------------
// Workspace byte offsets — round-2-proven envelope [0, ~118.5MB)
// ---------------------------------------------------------------------------
constexpr size_t BYTE_XN      = 0;              // xn f32            16,793,600
constexpr size_t BYTE_QKVBF   = 16793600;       // qkv bf16          25,190,400
constexpr size_t BYTE_XNBF    = 41984000;       // xn bf16            8,396,800
constexpr size_t BYTE_HBUF    = 16793600;       // h bf16 (aliases qkv_bf+xn_bf)
constexpr size_t BYTE_WTAIL   = 60882944;       // bf16 weights       6,291,456
constexpr size_t BYTE_ATTNBF  = 67174400;       // attn out bf16      8,396,800
constexpr size_t BYTE_X1NBF   = 75571200;       // ln2 out bf16       8,396,800
constexpr size_t BYTE_XO      = 83968000;       // xo f32            16,793,600
constexpr size_t BYTE_X1      = 100761600;      // kb+vb (attn) then x1 f32  16,793,600
constexpr size_t PLAN_BYTE    = 117555200;      // plan scratch ~0.9 MB

typedef unsigned short u16;
typedef __attribute__((ext_vector_type(4))) unsigned short u16x4;
typedef __attribute__((ext_vector_type(8))) short bf16x8;
typedef __attribute__((ext_vector_type(4))) float f32x4;

__device__ inline u16 f2bf(float f) {
  unsigned u = __float_as_uint(f);
  u = (u + 0x7FFFu + ((u >> 16) & 1u)) >> 16;
  return (u16)u;
}
__device__ inline float bf2f(u16 u) { return __uint_as_float(((unsigned)u) << 16); }

// Bijective XCD-aware block remap: each XCD gets a contiguous logical chunk.
__device__ inline int xcd_swz(int bid, int nwg) {
  const int xcd = bid % NXCD_, i = bid / NXCD_;
  const int q = nwg / NXCD_, r = nwg % NXCD_;
  const int base = (xcd < r) ? xcd * (q + 1) : r * (q + 1) + (xcd - r) * q;
  return base + i;
}

// async global->LDS, 16B per lane (lds dst must be wave-uniform base)
__device__ inline void gload_lds16(const void* g, void* l) {
  __builtin_amdgcn_global_load_lds(
      (const __attribute__((address_space(1))) void*)g,
      (__attribute__((address_space(3))) void*)l, 16, 0, 0);
}

// ---------------------------------------------------------------------------
// Fused LN1 + QKV-weight bf16 conversion.
// Blocks [0, ROWS_): LayerNorm row; blocks [ROWS_, ROWS_+768): wq conv.
// ---------------------------------------------------------------------------
__global__ __launch_bounds__(256) void ln_wconv_kernel(
    const float* __restrict__ x, const float* __restrict__ w,
    const float* __restrict__ b, float* __restrict__ of, u16* __restrict__ ob,
    const float* __restrict__ w0, u16* __restrict__ o0) {
  __shared__ float red[4];
  if (blockIdx.x >= ROWS_) {
    const int idx4 = ((blockIdx.x - ROWS_) * 256 + threadIdx.x) * 4;
    const float4 v = *(const float4*)(w0 + idx4);
    u16x4 r;
    r.x = f2bf(v.x); r.y = f2bf(v.y); r.z = f2bf(v.z); r.w = f2bf(v.w);
    *(u16x4*)(o0 + idx4) = r;
    return;
  }
  const int r = blockIdx.x;
  const int t = threadIdx.x;
  const float* xr = x + (size_t)r * C_;
  float v0 = xr[t], v1 = xr[t + 256];
  float s = v0 + v1;
#pragma unroll
  for (int o = 32; o; o >>= 1) s += __shfl_down(s, o);
  if ((t & 63) == 0) red[t >> 6] = s;
  __syncthreads();
  const float mean = (red[0] + red[1] + red[2] + red[3]) * (1.0f / 512.0f);
  __syncthreads();
  const float d0 = v0 - mean, d1 = v1 - mean;
  float q = d0 * d0 + d1 * d1;
#pragma unroll
  for (int o = 32; o; o >>= 1) q += __shfl_down(q, o);
  if ((t & 63) == 0) red[t >> 6] = q;
  __syncthreads();
  const float var = (red[0] + red[1] + red[2] + red[3]) * (1.0f / 512.0f);
  const float inv = 1.0f / sqrtf(var + 1e-5f);
  const float r0 = d0 * inv * w[t] + b[t];
  const float r1 = d1 * inv * w[t + 256] + b[t + 256];
  of[(size_t)r * C_ + t] = r0;
  of[(size_t)r * C_ + t + 256] = r1;
  ob[(size_t)r * C_ + t] = f2bf(r0);
  ob[(size_t)r * C_ + t + 256] = f2bf(r1);
}

// ---------------------------------------------------------------------------
// bf16 MFMA GEMM: out[M,N] = A[M,K](bf16) @ W[N,K](bf16)^T (+bias)(+gelu)(+res)
// 128xBN tile (BN=128 or 64), BK=64, 4 waves (2x2), 64x(BN/2) per wave.
// Double-buffered LDS + counted-vmcnt pipeline (T3+T4).
// PLANQ0 (QKV): guests [ngemm,ngemm+16) run plan_q0 verbatim; guests
//               [ngemm+16,...) convert proj/fc1/fc2 weights to bf16.
// SMAX (proj): guest blocks run plan_softmax verbatim (bit-exact relocation).
// KPACK (QKV, r23): epilogue additionally writes the dense-K panel kb for
//               gn in [512,1024), tok < 1024 — same bf16 values pack_kv
//               copied (bit-exact relayout); pack_kv becomes V-only.
// ---------------------------------------------------------------------------
template <int BN, int ACT, bool RES, bool OUTBF, bool QSCALE, bool PLANQ0, bool SMAX, bool KPACK>
__global__ __launch_bounds__(256) void gemm_bf_kernel(
    const u16* __restrict__ A, const u16* __restrict__ W,
    const float* __restrict__ bias, const float* __restrict__ resid,
    void* __restrict__ outp, int M, int K, int Nout, int ngemm,
    const float* __restrict__ xnf, const float* __restrict__ qkvwf,
    double* __restrict__ q0o,
    const double* __restrict__ lgtp, double* __restrict__ mxzp,
    const float* __restrict__ ws1, const float* __restrict__ ws2,
    const float* __restrict__ ws3, u16* __restrict__ wd1,
    u16* __restrict__ wd2, u16* __restrict__ wd3,
    u16* __restrict__ kbp) {
  constexpr int WN = BN / 2;       // wave cols: 64 or 32
  constexpr int NJ = WN / 16;      // j-tiles: 4 or 2
  constexpr int BPW = (BN / 8) / 4;  // B chunks per wave: 4 or 2
  __shared__ alignas(16) u16 As[2][128][64];
  __shared__ alignas(16) u16 Bs[2][BN][64];
  if (PLANQ0 && (int)blockIdx.x >= ngemm + 16) {
    // weight-conversion guests (proj/fc1/fc2), parallelism-preserving
    constexpr int n1 = C_ * C_, n2 = F_ * C_;
    const int idx4 = (((int)blockIdx.x - ngemm - 16) * 256 + threadIdx.x) * 4;
    const float* src;
    u16* dst;
    int off;
    if (idx4 < n1) { src = ws1; dst = wd1; off = idx4; }
    else if (idx4 < n1 + n2) { src = ws2; dst = wd2; off = idx4 - n1; }
    else { src = ws3; dst = wd3; off = idx4 - n1 - n2; }
    const float4 v = *(const float4*)(src + off);
    u16x4 r;
    r.x = f2bf(v.x); r.y = f2bf(v.y); r.z = f2bf(v.z); r.w = f2bf(v.w);
    *(u16x4*)(dst + off) = r;
    return;
  }
  if (PLANQ0 && (int)blockIdx.x >= ngemm) {
    const int idx = ((int)blockIdx.x - ngemm) * 256 + threadIdx.x;
    const int b = idx >> 9, hd = idx & 511;
    const float* xr = xnf + (size_t)(b * N_) * C_;
    const float* wr = qkvwf + (size_t)hd * C_;
    double s = 0.0;
    for (int c = 0; c < C_; c += 4) {
      const float4 xv = *(const float4*)(xr + c);
      const float4 wv = *(const float4*)(wr + c);
      s += (double)xv.x * (double)wv.x;
      s += (double)xv.y * (double)wv.y;
      s += (double)xv.z * (double)wv.z;
      s += (double)xv.w * (double)wv.w;
    }
    q0o[idx] = s * 0.125;
    return;
  }
  if (SMAX && (int)blockIdx.x >= ngemm) {
    // plan_softmax body, verbatim (bit-exact relocation)
    __shared__ double red[4];
    const int bh = (int)blockIdx.x - ngemm;
    const int t = threadIdx.x;
    const double* row = lgtp + (size_t)bh * N_;
    double m = -1e300;
    for (int i = t; i < N_; i += 256) m = fmax(m, row[i]);
#pragma unroll
    for (int o = 32; o; o >>= 1) m = fmax(m, __shfl_down(m, o));
    if ((t & 63) == 0) red[t >> 6] = m;
    __syncthreads();
    const double mx = fmax(fmax(red[0], red[1]), fmax(red[2], red[3]));
    __syncthreads();
    double z = 0.0;
    for (int i = t; i < N_; i += 256) z += exp(row[i] - mx);
#pragma unroll
    for (int o = 32; o; o >>= 1) z += __shfl_down(z, o);
    if ((t & 63) == 0) red[t >> 6] = z;
    __syncthreads();
    if (t == 0) {
      mxzp[bh] = mx;
      mxzp[64 + bh] = red[0] + red[1] + red[2] + red[3];
    }
    return;
  }
  const int tid = threadIdx.x;
  const int ny = Nout / BN;
  const int l = xcd_swz(blockIdx.x, ngemm);
  const int m0 = (l / ny) * 128, n0 = (l % ny) * BN;
  const int wave = tid >> 6, lane = tid & 63;
  const int wr = wave >> 1, wc = wave & 1;
  const int lrow = lane & 15, lgrp = lane >> 4;
  const int srow = lane >> 3;                              // row within chunk
  const int soff = (16 * (lane & 7)) ^ (16 * srow);        // swizzled src byte
  const int nk = K >> 6;

  auto stage = [&](int k0, int bufi) {
#pragma unroll
    for (int c = 0; c < 4; ++c) {
      const int q = wave * 4 + c;
      const int row = q * 8 + srow;
      int gm = m0 + row;
      if (gm >= M) gm = M - 1;
      gload_lds16((const char*)(A + (size_t)gm * K + k0) + soff,
                  (char*)&As[bufi][0][0] + (q << 10));
    }
#pragma unroll
    for (int c = 0; c < BPW; ++c) {
      const int q = wave * BPW + c;
      const int row = q * 8 + srow;
      gload_lds16((const char*)(W + (size_t)(n0 + row) * K + k0) + soff,
                  (char*)&Bs[bufi][0][0] + (q << 10));
    }
  };

  f32x4 acc[4][NJ] = {};
  stage(0, 0);
  int buf = 0;
  for (int t = 0; t < nk; ++t) {
    if (t + 1 < nk) {
      stage((t + 1) << 6, buf ^ 1);
      // outstanding = 2*(4+BPW); retire the oldest (4+BPW) = tile t
      if constexpr (BN == 128) asm volatile("s_waitcnt vmcnt(8)" ::: "memory");
      else                     asm volatile("s_waitcnt vmcnt(6)" ::: "memory");
    } else {
      asm volatile("s_waitcnt vmcnt(0)" ::: "memory");
    }
    __builtin_amdgcn_sched_barrier(0);
    __builtin_amdgcn_s_barrier();
    const char* asb = (const char*)&As[buf][0][0];
    const char* bsb = (const char*)&Bs[buf][0][0];
    __builtin_amdgcn_s_setprio(1);
#pragma unroll
    for (int ch = 0; ch < 2; ++ch) {
      bf16x8 af[4], bfv[NJ];
#pragma unroll
      for (int i = 0; i < 4; ++i) {
        const int ra = wr * 64 + i * 16 + lrow;
        const int cb = ch * 64 + lgrp * 16;
        af[i] = *(const bf16x8*)(asb + (ra << 7) + (cb ^ ((ra & 7) << 4)));
      }
#pragma unroll
      for (int j = 0; j < NJ; ++j) {
        const int rb = wc * WN + j * 16 + lrow;
        const int cb = ch * 64 + lgrp * 16;
        bfv[j] = *(const bf16x8*)(bsb + (rb << 7) + (cb ^ ((rb & 7) << 4)));
      }
#pragma unroll
      for (int i = 0; i < 4; ++i)
#pragma unroll
        for (int j = 0; j < NJ; ++j)
          acc[i][j] = __builtin_amdgcn_mfma_f32_16x16x32_bf16(af[i], bfv[j], acc[i][j], 0, 0, 0);
    }
    __builtin_amdgcn_s_setprio(0);
    asm volatile("s_waitcnt lgkmcnt(0)" ::: "memory");
    __builtin_amdgcn_sched_barrier(0);
    __builtin_amdgcn_s_barrier();
    buf ^= 1;
  }
#pragma unroll
  for (int i = 0; i < 4; ++i) {
#pragma unroll
    for (int j = 0; j < NJ; ++j) {
#pragma unroll
      for (int reg = 0; reg < 4; ++reg) {
        const int gm = m0 + wr * 64 + i * 16 + lgrp * 4 + reg;
        if (gm >= M) continue;
        const int gn = n0 + wc * WN + j * 16 + lrow;
        float v = acc[i][j][reg];
        if (bias) v += bias[gn];
        if (ACT == 1) v = 0.5f * v * (1.0f + erff(v * 0.70710678118654752440f));
        if (QSCALE) { if (gn < 512) v *= 0.125f; }
        if (RES) v += resid[(size_t)gm * Nout + gn];
        if (OUTBF) {
          const u16 bv = f2bf(v);
          ((u16*)outp)[(size_t)gm * Nout + gn] = bv;
          if (KPACK) {
            // dense-K panel: same bf16 value, token rows 0..1023 only
            if (gn >= 512 && gn < 1024) {
              const int bb = gm / N_;
              const int tok = gm - bb * N_;
              if (tok < 1024) {
                const int hh = (gn - 512) >> 6, dd = (gn - 512) & 63;
                kbp[((size_t)(bb * NH_ + hh) * 1024 + tok) * 64 + dd] = bv;
              }
            }
          }
        } else {
          ((float*)outp)[(size_t)gm * Nout + gn] = v;
        }
      }
    }
  }
}

// ---------------------------------------------------------------------------
// Pack dense V^T [b][h][64][1024] from qkv_bf (r23: V-only — K now packed in
// the QKV GEMM epilogue). 1D grid; blocks >= npack run the plan_u body
// verbatim (bit-exact relocation), overlapping the pack.
// ---------------------------------------------------------------------------
__global__ __launch_bounds__(256) void pack_kv_kernel(const u16* __restrict__ qkvbf,
                                                      u16* __restrict__ vb,
                                                      const float* __restrict__ qkvwf,
                                                      const double* __restrict__ q0,
                                                      double* __restrict__ u,
                                                      int npack) {
  if ((int)blockIdx.x >= npack) {
    const int idx = ((int)blockIdx.x - npack) * 256 + threadIdx.x;
    const int b = idx >> 12, h = (idx >> 9) & 7, c = idx & 511;
    double s = 0.0;
    for (int d = 0; d < D_; ++d)
      s += q0[b * 512 + h * 64 + d] * (double)qkvwf[(size_t)(512 + h * 64 + d) * C_ + c];
    u[idx] = s;
    return;
  }
  const int tile = blockIdx.x & 15, h = (blockIdx.x >> 4) & 7, b = (int)blockIdx.x >> 7;
  const int t = threadIdx.x;
  __shared__ u16 Vt[64][72];
  const int krow = tile * 64 + (t >> 2);
  const int dseg = (t & 3) * 16;
  const u16* p = qkvbf + (size_t)(b * N_ + krow) * K3_ + 1024 + h * D_ + dseg;
  const bf16x8 v0 = *(const bf16x8*)p;
  const bf16x8 v1 = *(const bf16x8*)(p + 8);
  *(bf16x8*)(&Vt[t >> 2][dseg]) = v0;
  *(bf16x8*)(&Vt[t >> 2][dseg + 8]) = v1;
  __syncthreads();
  const int d = t >> 2, kseg = (t & 3) * 16;
  bf16x8 o0, o1;
#pragma unroll
  for (int i = 0; i < 8; ++i) o0[i] = (short)Vt[kseg + i][d];
#pragma unroll
  for (int i = 0; i < 8; ++i) o1[i] = (short)Vt[kseg + 8 + i][d];
  u16* vp = vb + ((size_t)(b * NH_ + h) * 64 + d) * 1024 + tile * 64 + kseg;
  *(bf16x8*)vp = o0;
  *(bf16x8*)(vp + 8) = o1;
}

// ---------------------------------------------------------------------------
// MFMA flash attention v11 + fused plan_logit guest blocks (r19: heads split
// across threads — each thread computes 4 heads for one row; per-head c-loop
// order unchanged -> bit-exact. 48 guests, hg wave-uniform -> LDS broadcast).
// attn: 704 blocks, LDS 51.5KB, 3 blocks/CU; 704+48=752 <= 768 single fill.
// ---------------------------------------------------------------------------
__global__ __launch_bounds__(384) void attn_mfma_kernel(
    const u16* __restrict__ qkvbf, const u16* __restrict__ kb,
    const u16* __restrict__ vb, const float* __restrict__ rpb,
    u16* __restrict__ attnout,
    const float* __restrict__ xnf, const double* __restrict__ uu,
    double* __restrict__ lgt, int nattn) {
  __shared__ alignas(16) u16 Ks[2][64][64];   // 16KB, XOR-swizzled storage
  __shared__ alignas(16) u16 Vs[2][64][64];   // 16KB, XOR-swizzled storage
  __shared__ alignas(16) u16 Pl[6][16][74];   // 14.2KB; stride 74 breaks conflicts
  __shared__ u16 tab[36 * 63];                // 4.5KB bf16 bias table
  if ((int)blockIdx.x >= nattn) {
    // plan_logit guest: 6 blocks/batch; thread = (row rloc, head-group hg)
    double* ul = (double*)&Ks[0][0][0];       // 4096 f64 = 32KB (aliases Ks)
    const int lb = (int)blockIdx.x - nattn;   // [0, 48)
    const int b = lb / 6, part = lb % 6;
    for (int i = threadIdx.x; i < 4096; i += 384)
      ul[i] = uu[(size_t)b * 4096 + i];
    __syncthreads();
    const int rloc = threadIdx.x % 192;
    const int hg = threadIdx.x / 192;         // 0 or 1 (wave-uniform)
    const int m = part * 192 + rloc;
    if (m >= N_) return;
    const float* xr = xnf + (size_t)(b * N_ + m) * C_;
    const double* ulh = ul + hg * 4 * 512;
    double s[4] = {};
    for (int c = 0; c < C_; c += 4) {
      const float4 xv = *(const float4*)(xr + c);
#pragma unroll
      for (int hh = 0; hh < 4; ++hh) {
        s[hh] += (double)xv.x * ulh[hh * 512 + c];
        s[hh] += (double)xv.y * ulh[hh * 512 + c + 1];
        s[hh] += (double)xv.z * ulh[hh * 512 + c + 2];
        s[hh] += (double)xv.w * ulh[hh * 512 + c + 3];
      }
    }
#pragma unroll
    for (int hh = 0; hh < 4; ++hh)
      lgt[(size_t)(b * 8 + hg * 4 + hh) * N_ + m] = s[hh];
    return;
  }
  const int l = xcd_swz(blockIdx.x, nattn);  // logical = (b*8+h)*11 + qt
  const int qt = l % 11;
  const int bh = l / 11;
  const int h = bh & 7, b = bh >> 3;
  const int wave = threadIdx.x >> 6, lane = threadIdx.x & 63;
  const int lrow = lane & 15, lgrp = lane >> 4;
  const int qblk = qt * 96;
  const int qbase = qblk + wave * 16;

  const u16* kpan = kb + (size_t)(b * NH_ + h) * 1024 * 64;
  const u16* vpan = vb + (size_t)(b * NH_ + h) * 64 * 1024;

  // ---- issue async stage of tile 0 (waves 0-3: K, waves 4-5: V) ----
  if (wave < 4) {
#pragma unroll
    for (int c = 0; c < 2; ++c) {
      const int q = wave * 2 + c;
      const int Y = (q << 10) | (lane << 4);
      const int Ys = Y ^ (((Y >> 7) & 7) << 4);
      gload_lds16((const char*)kpan + Ys, (char*)&Ks[0][0][0] + (q << 10));
    }
  } else {
#pragma unroll
    for (int c = 0; c < 4; ++c) {
      const int q = (wave - 4) * 4 + c;
      const int Y = (q << 10) | (lane << 4);
      const int Ys = Y ^ (((Y >> 7) & 7) << 4);
      const int row = Y >> 7;
      gload_lds16((const char*)vpan + (size_t)row * 2048 + (Ys & 127),
                  (char*)&Vs[0][0][0] + (q << 10));
    }
  }

  // ---- stage rpb sub-table (all threads; bf16) ----
  const int qimin = max(qblk - 1, 0);
  const int qimax = min(qblk + 94, 1023);
  const int qymin = qimin >> 5;
  const int qymax = qimax >> 5;
  const int nrows = qymax - qymin + 32;   // dy in [qymin-31, qymax]  (<=36)
  for (int i = threadIdx.x; i < nrows * 63; i += 384)
    tab[i] = f2bf(rpb[(size_t)(qymin * 63 + i) * NH_ + h]);

  u16 (*pl)[74] = Pl[wave];

  // Q fragments (pre-scaled by 1/8 in the QKV GEMM epilogue)
  bf16x8 qf[2];
  {
    const int qrow = min(qbase + lrow, N_ - 1);
    const u16* qp = qkvbf + (size_t)(b * N_ + qrow) * K3_ + h * D_;
    qf[0] = *(const bf16x8*)(qp + lgrp * 8);
    qf[1] = *(const bf16x8*)(qp + 32 + lgrp * 8);
  }

  const float bias0 = rpb[h];

  // Per-owned-q-row (C-layout rows lgrp*4+reg) bias table anchors
  int AlocR[4];
  bool qclsR[4];
#pragma unroll
  for (int reg = 0; reg < 4; ++reg) {
    const int qr = min(qbase + lgrp * 4 + reg, N_ - 1);
    const int qi = max(qr - 1, 0);
    AlocR[reg] = ((qi >> 5) - qymin + 31) * 63 + (qi & 31) + 31;
    qclsR[reg] = (qr == 0);
  }

  f32x4 psum = {0.f, 0.f, 0.f, 0.f};
  f32x4 o[4] = {};

  __syncthreads();  // full drain: tile-0 stage + tab complete, visible to all

  for (int t = 0; t < 16; ++t) {
    const int buf = t & 1;
    // ---- issue async stage of tile t+1 into buf^1 (role-split) ----
    if (t < 15) {
      const int keybase2 = (t + 1) * 64;
      if (wave < 4) {
#pragma unroll
        for (int c = 0; c < 2; ++c) {
          const int q = wave * 2 + c;
          const int Y = (q << 10) | (lane << 4);
          const int Ys = Y ^ (((Y >> 7) & 7) << 4);
          gload_lds16((const char*)kpan + ((size_t)keybase2 << 7) + Ys,
                      (char*)&Ks[buf ^ 1][0][0] + (q << 10));
        }
        // outstanding: K(t) 2 + K(t+1) 2 -> retire the 2 oldest = K(t)
        asm volatile("s_waitcnt vmcnt(2)" ::: "memory");
      } else {
#pragma unroll
        for (int c = 0; c < 4; ++c) {
          const int q = (wave - 4) * 4 + c;
          const int Y = (q << 10) | (lane << 4);
          const int Ys = Y ^ (((Y >> 7) & 7) << 4);
          const int row = Y >> 7;
          gload_lds16((const char*)vpan + (size_t)row * 2048 + ((size_t)keybase2 << 1) + (Ys & 127),
                      (char*)&Vs[buf ^ 1][0][0] + (q << 10));
        }
        // outstanding: V(t) 4 + V(t+1) 4 -> retire the 4 oldest = V(t)
        asm volatile("s_waitcnt vmcnt(4)" ::: "memory");
      }
    } else {
      asm volatile("s_waitcnt vmcnt(0)" ::: "memory");
    }
    __builtin_amdgcn_sched_barrier(0);
    __builtin_amdgcn_s_barrier();

    const int keybase = t * 64;
    const char* ksb = (const char*)&Ks[buf][0][0];
    const char* vsb = (const char*)&Vs[buf][0][0];

    // ---- S = Q K^T (K tile from swizzled LDS) ----
    f32x4 s[4] = {};
    __builtin_amdgcn_s_setprio(1);
#pragma unroll
    for (int tile = 0; tile < 4; ++tile) {
      const int row = tile * 16 + lrow;
      const int sw = (row & 7) << 4;
      const bf16x8 kf0 = *(const bf16x8*)(ksb + ((row * 128 + lgrp * 16) ^ sw));
      const bf16x8 kf1 = *(const bf16x8*)(ksb + ((row * 128 + 64 + lgrp * 16) ^ sw));
      s[tile] = __builtin_amdgcn_mfma_f32_16x16x32_bf16(qf[0], kf0, s[tile], 0, 0, 0);
      s[tile] = __builtin_amdgcn_mfma_f32_16x16x32_bf16(qf[1], kf1, s[tile], 0, 0, 0);
    }
    __builtin_amdgcn_s_setprio(0);
    // ---- bias + exp + P-write directly from C-layout registers ----
#pragma unroll
    for (int tile = 0; tile < 4; ++tile) {
      const int key = keybase + tile * 16 + lrow;
      const int ki = max(key - 1, 0);
      const int kpart = (ki >> 5) * 63 + (ki & 31);
      const bool kcls = (key == 0);
#pragma unroll
      for (int reg = 0; reg < 4; ++reg) {
        const float bias = (qclsR[reg] || kcls) ? bias0 : bf2f(tab[AlocR[reg] - kpart]);
        const float p = __expf(s[tile][reg] + bias);
        psum[reg] += p;
        pl[lgrp * 4 + reg][tile * 16 + lrow] = f2bf(p);
      }
    }
    // ---- O += P V (V tile from swizzled LDS) ----
    __builtin_amdgcn_s_setprio(1);
#pragma unroll
    for (int ch = 0; ch < 2; ++ch) {
      const bf16x8 pf = *(const bf16x8*)(&pl[lrow][ch * 32 + lgrp * 8]);
#pragma unroll
      for (int dt = 0; dt < 4; ++dt) {
        const int row = dt * 16 + lrow;
        const bf16x8 vf = *(const bf16x8*)(vsb + ((row * 128 + ch * 64 + lgrp * 16) ^ ((row & 7) << 4)));
        o[dt] = __builtin_amdgcn_mfma_f32_16x16x32_bf16(pf, vf, o[dt], 0, 0, 0);
      }
    }
    __builtin_amdgcn_s_setprio(0);
    // all LDS reads of buf must retire before any wave's next stage overwrites it
    asm volatile("s_waitcnt lgkmcnt(0)" ::: "memory");
    __builtin_amdgcn_sched_barrier(0);
    __builtin_amdgcn_s_barrier();
  }

  // ---- deferred row-sum: reduce psum over the 16 lanes of this lgrp ----
#pragma unroll
  for (int reg = 0; reg < 4; ++reg) {
    float v = psum[reg];
    v += __shfl_xor(v, 1);
    v += __shfl_xor(v, 2);
    v += __shfl_xor(v, 4);
    v += __shfl_xor(v, 8);
    psum[reg] = v;
  }

  // ---- tail: key 1024 (image key 1023: ky=31, kx=31) ----
  float ptail;
  {
    const u16* k1p = qkvbf + (size_t)(b * N_ + 1024) * K3_ + 512 + h * D_;
    const bf16x8 k10 = *(const bf16x8*)(k1p + lgrp * 8);
    const bf16x8 k11 = *(const bf16x8*)(k1p + 32 + lgrp * 8);
    float part = 0.f;
#pragma unroll
    for (int i = 0; i < 8; ++i)
      part += bf2f((u16)qf[0][i]) * bf2f((u16)k10[i]) + bf2f((u16)qf[1][i]) * bf2f((u16)k11[i]);
    part += __shfl_xor(part, 16);
    part += __shfl_xor(part, 32);
    // anchor for q-row = this lane's lrow (row-major tail mapping)
    const int q_s = min(qbase + lrow, N_ - 1);
    const int qi_s = max(q_s - 1, 0);
    const int Aloc_s = ((qi_s >> 5) - qymin + 31) * 63 + (qi_s & 31) + 31;
    const float btail = (q_s == 0) ? bias0 : bf2f(tab[Aloc_s - 31 * 63 - 31]);
    ptail = __expf(part + btail);
  }

  float v1024[4];
#pragma unroll
  for (int dt = 0; dt < 4; ++dt)
    v1024[dt] = bf2f(qkvbf[(size_t)(b * N_ + 1024) * K3_ + 1024 + h * D_ + dt * 16 + lrow]);

#pragma unroll
  for (int reg = 0; reg < 4; ++reg) {
    const float pr = __shfl(ptail, lgrp * 4 + reg);
    const int qrow = qbase + lgrp * 4 + reg;
    if (qrow >= N_) continue;
    const float inv = 1.0f / (psum[reg] + pr);
    u16* op = attnout + (size_t)(b * N_ + qrow) * C_ + h * D_ + lrow;
#pragma unroll
    for (int dt = 0; dt < 4; ++dt)
      op[dt * 16] = f2bf((o[dt][reg] + pr * v1024[dt]) * inv);
  }
}

// ---------------------------------------------------------------------------
// Plan path (f64) — exact discrete indices. q0 fused into QKV GEMM; u fused
// into pack_kv; logit fused into attn; softmax fused into proj.
// ---------------------------------------------------------------------------
__global__ __launch_bounds__(256) void plan_cls_kernel(const double* __restrict__ lgt,
                                                       const double* __restrict__ mxz,
                                                       double* __restrict__ cls) {
  const int idx = blockIdx.x * 256 + threadIdx.x;
  const int b = idx >> 10, i = idx & 1023;
  double s = 0.0;
  for (int h = 0; h < 8; ++h) {
    const int bh = b * 8 + h;
    s += exp(lgt[(size_t)bh * N_ + 1 + i] - mxz[bh]) / mxz[64 + bh];
  }
  cls[idx] = s / 8.0;
}

// ---------------------------------------------------------------------------
// JAX threefry2x32 (20 rounds), exact
// ---------------------------------------------------------------------------
__device__ inline void tf2x32(unsigned k0, unsigned k1, unsigned& x0, unsigned& x1) {
  const unsigned ks2 = k0 ^ k1 ^ 0x1BD11BDAu;
  const int r0[4] = {13, 15, 26, 6};
  const int r1[4] = {17, 29, 16, 24};
  x0 += k0; x1 += k1;
#pragma unroll
  for (int i = 0; i < 4; ++i) { x0 += x1; x1 = (x1 << r0[i]) | (x1 >> (32 - r0[i])); x1 ^= x0; }
  x0 += k1; x1 += ks2 + 1u;
#pragma unroll
  for (int i = 0; i < 4; ++i) { x0 += x1; x1 = (x1 << r1[i]) | (x1 >> (32 - r1[i])); x1 ^= x0; }
  x0 += ks2; x1 += k0 + 2u;
#pragma unroll
  for (int i = 0; i < 4; ++i) { x0 += x1; x1 = (x1 << r0[i]) | (x1 >> (32 - r0[i])); x1 ^= x0; }
  x0 += k0; x1 += k1 + 3u;
#pragma unroll
  for (int i = 0; i < 4; ++i) { x0 += x1; x1 = (x1 << r1[i]) | (x1 >> (32 - r1[i])); x1 ^= x0; }
  x0 += k1; x1 += ks2 + 4u;
#pragma unroll
  for (int i = 0; i < 4; ++i) { x0 += x1; x1 = (x1 << r0[i]) | (x1 >> (32 - r0[i])); x1 ^= x0; }
  x0 += ks2; x1 += k0 + 5u;
}

// ---------------------------------------------------------------------------
// Fused plan tail v2: register bitonic sort (wave-internal phases j<64 via
// shfl_xor, comparator EXACTLY preserved -> bit-identical permutation; only
// 10 cross-wave phases touch LDS) + batched counts (per-batch f64 reduction
// TREES preserved exactly; barriers 48 -> 3). Threefry tail unchanged.
// ---------------------------------------------------------------------------
__global__ __launch_bounds__(1024) void plan_tail_kernel(
    const double* __restrict__ cls, const float* __restrict__ tw,
    int* __restrict__ scal, int* __restrict__ sel, int* __restrict__ ii) {
  __shared__ double sv[1024];
  __shared__ int sid[1024];
  __shared__ double dred8[8][16];
  __shared__ double mred8[8][16];
  __shared__ int ired8[8][16];
  __shared__ double stats2[8][2];
  __shared__ int sc3[3];
  const int t = threadIdx.x;
  const int wid = t >> 6, lane = t & 63;

  // ---- bitonic sort (batch 0), values in registers ----
  double v = cls[t];
  int idx = t;
  for (int k = 2; k <= 1024; k <<= 1) {
    for (int j = k >> 1; j > 0; j >>= 1) {
      const bool desc = ((t & k) == 0);     // same for both partners (j < k)
      const bool iAmLow = (t & j) == 0;
      double ov;
      int oi;
      if (j >= 64) {
        sv[t] = v;
        sid[t] = idx;
        __syncthreads();
        ov = sv[t ^ j];
        oi = sid[t ^ j];
        __syncthreads();
      } else {
        ov = __shfl_xor(v, j);
        oi = __shfl_xor(idx, j);
      }
      // myFirst == original aFirst evaluated from this thread's perspective
      const bool myFirst = (v > ov) || (v == ov && idx < oi);
      const bool keepMine = desc ? (iAmLow == myFirst) : (iAmLow != myFirst);
      if (!keepMine) { v = ov; idx = oi; }
    }
  }
  sel[t] = idx;

  // ---- counts: all 8 batches, trees EXACTLY as the split version ----
  double val8[8];
#pragma unroll
  for (int b = 0; b < 8; ++b) val8[b] = cls[b * 1024 + t];
#pragma unroll
  for (int b = 0; b < 8; ++b) {
    double s = val8[b];
#pragma unroll
    for (int o = 32; o; o >>= 1) s += __shfl_down(s, o);
    if (lane == 0) dred8[b][wid] = s;
    double mv = val8[b];
#pragma unroll
    for (int o = 32; o; o >>= 1) mv = fmax(mv, __shfl_down(mv, o));
    if (lane == 0) mred8[b][wid] = mv;
  }
  __syncthreads();
  if (t < 8) {
    double tot = 0;
    for (int i = 0; i < 16; ++i) tot += dred8[t][i];
    stats2[t][0] = tot / 1024.0;
    double mx = mred8[t][0];
    for (int i = 1; i < 16; ++i) mx = fmax(mx, mred8[t][i]);
    stats2[t][1] = mx;
  }
  __syncthreads();
#pragma unroll
  for (int b = 0; b < 8; ++b) {
    int c = (val8[b] >= stats2[b][0] && val8[b] <= stats2[b][1]) ? 1 : 0;
#pragma unroll
    for (int o = 32; o; o >>= 1) c += __shfl_down(c, o);
    if (lane == 0) ired8[b][wid] = c;
  }
  __syncthreads();

  if (t == 0) {
    int maxv = 0;
    double sum = 0.0;
    for (int b = 0; b < 8; ++b) {
      int cc = 0;
      for (int i = 0; i < 16; ++i) cc += ired8[b][i];
      maxv = max(maxv, cc);
      sum += (double)cc;
    }
    const double T = sum / 8.0;
    const double sig = 1.0 / (1.0 + exp(-((double)maxv - T) / 8.0));
    const double keepf = 1024.0 * (0.6 + (1.0 - 0.6) * sig);
    const int keep = __double2int_rn(keepf);
    const int remaining = 1024 - keep;
    const float t0 = tw[0], t1 = tw[1];
    const float mw = fmaxf(t0, t1);
    const float e0 = expf(t0 - mw), e1 = expf(t1 - mw);
    const float w0 = e0 / (e0 + e1);
    const int nt = (int)(w0 * (float)remaining);
    const int ni = remaining - nt;
    scal[0] = keep; scal[1] = nt; scal[2] = ni;
    sc3[0] = keep; sc3[1] = nt; sc3[2] = ni;
  }
  __syncthreads();

  const int ni = sc3[2];
  const int size = 8 * ni;
  const unsigned span = 1023u;
  unsigned mult = 65536u % span;
  mult = (mult * mult) % span;
  unsigned f0 = 0u, f1 = 1u;
  tf2x32(0u, 1234u, f0, f1);
#if PARTITIONABLE
  unsigned k1a = 0u, k1b = 0u;
  tf2x32(f0, f1, k1a, k1b);
  unsigned k2a = 0u, k2b = 1u;
  tf2x32(f0, f1, k2a, k2b);
  for (int i = t; i < size; i += 1024) {
    unsigned h0 = 0u, h1 = (unsigned)i;
    tf2x32(k1a, k1b, h0, h1);
    const unsigned hb = h0 ^ h1;
    unsigned l0 = 0u, l1 = (unsigned)i;
    tf2x32(k2a, k2b, l0, l1);
    const unsigned lb = l0 ^ l1;
    ii[i] = (int)(((hb % span) * mult + (lb % span)) % span);
  }
#else
  unsigned a0 = 0u, a1 = 2u;
  tf2x32(f0, f1, a0, a1);
  unsigned b0 = 1u, b1 = 3u;
  tf2x32(f0, f1, b0, b1);
  const int half = size >> 1;
  for (int i = t; i < half; i += 1024) {
    unsigned h0 = (unsigned)i, h1 = (unsigned)(i + half);
    tf2x32(a0, b0, h0, h1);
    unsigned l0 = (unsigned)i, l1 = (unsigned)(i + half);
    tf2x32(a1, b1, l0, l1);
    ii[i]        = (int)(((h0 % span) * mult + (l0 % span)) % span);
    ii[i + half] = (int)(((h1 % span) * mult + (l1 % span)) % span);
  }
#endif
}

// ---------------------------------------------------------------------------
// Fused assemble + LN2: x1 = x + gathered_src; x1n_bf = LN(x1)
// ---------------------------------------------------------------------------
__global__ __launch_bounds__(256) void assemble_ln_kernel(
    const float* __restrict__ x, const float* __restrict__ xn,
    const float* __restrict__ xo, const int* __restrict__ scal,
    const int* __restrict__ sel, const int* __restrict__ ii,
    const float* __restrict__ w, const float* __restrict__ bb,
    float* __restrict__ x1, u16* __restrict__ ob) {
  __shared__ float red[4];
  const int blk = blockIdx.x;
  const int b = blk / N_, tok = blk % N_;
  const int keep = scal[0], nt = scal[1], ni = scal[2];
  const float* src;
  if (tok == 0) {
    src = xo + (size_t)(b * N_) * C_;
  } else if (tok <= keep) {
    src = xo + (size_t)(b * N_ + 1 + sel[tok - 1]) * C_;
  } else if (tok <= keep + nt) {
    src = xn + (size_t)(b * N_ + 1) * C_;
  } else {
    const int j = tok - 1 - keep - nt;
    src = xn + (size_t)(b * N_ + 2 + ii[b * ni + j]) * C_;
  }
  const int t = threadIdx.x;
  const size_t o = (size_t)blk * C_;
  const float v0 = x[o + t] + src[t];
  const float v1 = x[o + t + 256] + src[t + 256];
  x1[o + t] = v0;
  x1[o + t + 256] = v1;
  float s = v0 + v1;
#pragma unroll
  for (int of = 32; of; of >>= 1) s += __shfl_down(s, of);
  if ((t & 63) == 0) red[t >> 6] = s;
  __syncthreads();
  const float mean = (red[0] + red[1] + red[2] + red[3]) * (1.0f / 512.0f);
  __syncthreads();
  const float d0 = v0 - mean, d1 = v1 - mean;
  float q = d0 * d0 + d1 * d1;
#pragma unroll
  for (int of = 32; of; of >>= 1) q += __shfl_down(q, of);
  if ((t & 63) == 0) red[t >> 6] = q;
  __syncthreads();
  const float var = (red[0] + red[1] + red[2] + red[3]) * (1.0f / 512.0f);
  const float inv = 1.0f / sqrtf(var + 1e-5f);
  ob[o + t] = f2bf(d0 * inv * w[t] + bb[t]);
  ob[o + t + 256] = f2bf(d1 * inv * w[t + 256] + bb[t + 256]);
}

// ---------------------------------------------------------------------------
// Host launcher
// ---------------------------------------------------------------------------
extern "C" void kernel_launch(void* const* d_in, const int* in_sizes, int n_in,
                              void* d_out, int out_size, void* d_ws, size_t ws_size,
                              hipStream_t stream) {
  (void)in_sizes; (void)n_in; (void)out_size; (void)ws_size;
  const float* x     = (const float*)d_in[0];
  const float* ln1w  = (const float*)d_in[1];
  const float* ln1b  = (const float*)d_in[2];
  const float* qkvw  = (const float*)d_in[3];
  const float* rpb   = (const float*)d_in[4];
  const float* projw = (const float*)d_in[5];
  const float* projb = (const float*)d_in[6];
  const float* tw    = (const float*)d_in[7];
  const float* ln2w  = (const float*)d_in[8];
  const float* ln2b  = (const float*)d_in[9];
  const float* fc1w  = (const float*)d_in[10];
  const float* fc1b  = (const float*)d_in[11];
  const float* fc2w  = (const float*)d_in[12];
  const float* fc2b  = (const float*)d_in[13];
  float* out = (float*)d_out;
  char* base = (char*)d_ws;

  float* xn       = (float*)(base + BYTE_XN);
  u16*   qkv_bf   = (u16*)(base + BYTE_QKVBF);
  u16*   xn_bf    = (u16*)(base + BYTE_XNBF);
  u16*   hbuf     = (u16*)(base + BYTE_HBUF);
  u16*   wq_bf    = (u16*)(base + BYTE_WTAIL);
  u16*   wp_bf    = wq_bf + K3_ * C_;
  u16*   w1_bf    = wp_bf + C_ * C_;
  u16*   w2_bf    = w1_bf + F_ * C_;
  u16*   attn_bf  = (u16*)(base + BYTE_ATTNBF);
  u16*   x1n_bf   = (u16*)(base + BYTE_X1NBF);
  float* xo       = (float*)(base + BYTE_XO);
  u16*   kbuf     = (u16*)(base + BYTE_X1);
  u16*   vbuf     = kbuf + (size_t)B_ * NH_ * 1024 * 64;
  float* x1       = (float*)(base + BYTE_X1);

  char* pb = base + PLAN_BYTE;
  double* q0  = (double*)pb;
  double* u   = q0 + 4096;
  double* lgt = u + 32768;
  double* mxz = lgt + 65600;
  double* cls = mxz + 128;
  int* counts = (int*)(cls + 8192);
  int* scal   = counts + 8;
  int* sel    = scal + 4;
  int* iibuf  = sel + 1024;

  // 1. fused LN1 (-> xn f32 + xn_bf) + QKV-weight conversion only
  ln_wconv_kernel<<<ROWS_ + WQ_BLKS_, 256, 0, stream>>>(
      x, ln1w, ln1b, xn, xn_bf, qkvw, wq_bf);
  // 2. QKV GEMM (BN=128, grid 780, KPACK: dense-K written from epilogue)
  //    + 16 plan_q0 guests + 2304 weight-conv guests (proj/fc1/fc2)
  gemm_bf_kernel<128, 0, false, true, true, true, false, true>
      <<<65 * 12 + 16 + WTAIL_BLKS_, 256, 0, stream>>>(
      xn_bf, wq_bf, nullptr, nullptr, qkv_bf, ROWS_, C_, K3_, 65 * 12,
      xn, qkvw, q0, nullptr, nullptr,
      projw, fc1w, fc2w, wp_bf, w1_bf, w2_bf, kbuf);
  // 3. dense V^T pack (V-only, r23) + 128 fused plan_u blocks (bit-exact)
  pack_kv_kernel<<<1024 + 128, 256, 0, stream>>>(
      qkv_bf, vbuf, qkvw, q0, u, 1024);
  // 4. MFMA flash attention v11 (704 blocks) + 48 fused plan_logit blocks
  //    (head-split threads halve the serial f64 chain; 752 <= 768 single fill)
  attn_mfma_kernel<<<11 * NH_ * B_ + 48, 384, 0, stream>>>(
      qkv_bf, kbuf, vbuf, rpb, attn_bf, xn, u, lgt, 11 * NH_ * B_);
  // 5. proj (BN=64, grid 520) + 64 fused plan_softmax blocks (bit-exact;
  //    584 <= 768 single fill)
  gemm_bf_kernel<64, 0, false, false, false, false, true, false><<<65 * 8 + 64, 256, 0, stream>>>(
      attn_bf, wp_bf, projb, nullptr, xo, ROWS_, C_, C_, 65 * 8,
      nullptr, nullptr, nullptr, lgt, mxz,
      nullptr, nullptr, nullptr, nullptr, nullptr, nullptr, nullptr);
  // 6. plan cls (needs mxz) -> cls  [32 blocks: parallelism-preserving]
  plan_cls_kernel<<<32, 256, 0, stream>>>(lgt, mxz, cls);
  // 7. plan tail (sort + counts + threefry) -> scal/sel/ii
  plan_tail_kernel<<<1, 1024, 0, stream>>>(cls, tw, scal, sel, iibuf);
  // 8. fused assemble + residual + LN2 -> x1 f32 + x1n_bf
  assemble_ln_kernel<<<ROWS_, 256, 0, stream>>>(
      x, xn, xo, scal, sel, iibuf, ln2w, ln2b, x1, x1n_bf);
  // 9. FC1 + exact GELU -> hbuf bf16 — BN=128, grid 1040
  gemm_bf_kernel<128, 1, false, true, false, false, false, false><<<65 * 16, 256, 0, stream>>>(
      x1n_bf, w1_bf, fc1b, nullptr, hbuf, ROWS_, C_, F_, 65 * 16,
      nullptr, nullptr, nullptr, nullptr, nullptr,
      nullptr, nullptr, nullptr, nullptr, nullptr, nullptr, nullptr);
  // 10. FC2 + bias + residual -> out f32 — BN=64, grid 520
  gemm_bf_kernel<64, 0, true, false, false, false, false, false><<<65 * 8, 256, 0, stream>>>(
      hbuf, w2_bf, fc2b, x1, out, ROWS_, F_, C_, 65 * 8,
      nullptr, nullptr, nullptr, nullptr, nullptr,
      nullptr, nullptr, nullptr, nullptr, nullptr, nullptr, nullptr);
}

// Round 24
// 300.064 us; speedup vs baseline: 1.0844x; 1.0082x over previous
//
#include <hip/hip_runtime.h>
#include <cmath>

#define PARTITIONABLE 1

// ---------------------------------------------------------------------------
// Problem constants (B=8, S=32 -> N=1025, C=512, NH=8, D=64)
// ---------------------------------------------------------------------------
constexpr int B_ = 8;
constexpr int N_ = 1025;
constexpr int C_ = 512;
constexpr int NH_ = 8;
constexpr int D_ = 64;
constexpr int K3_ = 1536;   // 3*C
constexpr int F_ = 2048;    // 4*C
constexpr int ROWS_ = B_ * N_;  // 8200
constexpr int NXCD_ = 8;
constexpr int WQ_BLKS_ = (K3_ * C_) / 1024;                      // 768 (qkv w only)
constexpr int WTAIL_BLKS_ = (C_ * C_ + F_ * C_ + C_ * F_) / 1024;  // 2304 (proj/fc1/fc2)

// ---------------------------------------------------------------------------
// Workspace byte offsets — round-2-proven envelope [0, ~118.5MB)
// ---------------------------------------------------------------------------
constexpr size_t BYTE_XN      = 0;              // xn f32            16,793,600
constexpr size_t BYTE_QKVBF   = 16793600;       // qkv bf16          25,190,400
constexpr size_t BYTE_XNBF    = 41984000;       // xn bf16            8,396,800
constexpr size_t BYTE_HBUF    = 16793600;       // h bf16 (aliases qkv_bf+xn_bf)
constexpr size_t BYTE_WTAIL   = 60882944;       // bf16 weights       6,291,456
constexpr size_t BYTE_ATTNBF  = 67174400;       // attn out bf16      8,396,800
constexpr size_t BYTE_X1NBF   = 75571200;       // ln2 out bf16       8,396,800
constexpr size_t BYTE_XO      = 83968000;       // xo f32            16,793,600
constexpr size_t BYTE_X1      = 100761600;      // kb+vb (attn) then x1 f32  16,793,600
constexpr size_t PLAN_BYTE    = 117555200;      // plan scratch ~0.9 MB

typedef unsigned short u16;
typedef __attribute__((ext_vector_type(4))) unsigned short u16x4;
typedef __attribute__((ext_vector_type(8))) short bf16x8;
typedef __attribute__((ext_vector_type(4))) float f32x4;

__device__ inline u16 f2bf(float f) {
  unsigned u = __float_as_uint(f);
  u = (u + 0x7FFFu + ((u >> 16) & 1u)) >> 16;
  return (u16)u;
}
__device__ inline float bf2f(u16 u) { return __uint_as_float(((unsigned)u) << 16); }

// Bijective XCD-aware block remap: each XCD gets a contiguous logical chunk.
__device__ inline int xcd_swz(int bid, int nwg) {
  const int xcd = bid % NXCD_, i = bid / NXCD_;
  const int q = nwg / NXCD_, r = nwg % NXCD_;
  const int base = (xcd < r) ? xcd * (q + 1) : r * (q + 1) + (xcd - r) * q;
  return base + i;
}

// async global->LDS, 16B per lane (lds dst must be wave-uniform base)
__device__ inline void gload_lds16(const void* g, void* l) {
  __builtin_amdgcn_global_load_lds(
      (const __attribute__((address_space(1))) void*)g,
      (__attribute__((address_space(3))) void*)l, 16, 0, 0);
}

// ---------------------------------------------------------------------------
// Fused LN1 + QKV-weight bf16 conversion.
// Blocks [0, ROWS_): LayerNorm row; blocks [ROWS_, ROWS_+768): wq conv.
// ---------------------------------------------------------------------------
__global__ __launch_bounds__(256) void ln_wconv_kernel(
    const float* __restrict__ x, const float* __restrict__ w,
    const float* __restrict__ b, float* __restrict__ of, u16* __restrict__ ob,
    const float* __restrict__ w0, u16* __restrict__ o0) {
  __shared__ float red[4];
  if (blockIdx.x >= ROWS_) {
    const int idx4 = ((blockIdx.x - ROWS_) * 256 + threadIdx.x) * 4;
    const float4 v = *(const float4*)(w0 + idx4);
    u16x4 r;
    r.x = f2bf(v.x); r.y = f2bf(v.y); r.z = f2bf(v.z); r.w = f2bf(v.w);
    *(u16x4*)(o0 + idx4) = r;
    return;
  }
  const int r = blockIdx.x;
  const int t = threadIdx.x;
  const float* xr = x + (size_t)r * C_;
  float v0 = xr[t], v1 = xr[t + 256];
  float s = v0 + v1;
#pragma unroll
  for (int o = 32; o; o >>= 1) s += __shfl_down(s, o);
  if ((t & 63) == 0) red[t >> 6] = s;
  __syncthreads();
  const float mean = (red[0] + red[1] + red[2] + red[3]) * (1.0f / 512.0f);
  __syncthreads();
  const float d0 = v0 - mean, d1 = v1 - mean;
  float q = d0 * d0 + d1 * d1;
#pragma unroll
  for (int o = 32; o; o >>= 1) q += __shfl_down(q, o);
  if ((t & 63) == 0) red[t >> 6] = q;
  __syncthreads();
  const float var = (red[0] + red[1] + red[2] + red[3]) * (1.0f / 512.0f);
  const float inv = 1.0f / sqrtf(var + 1e-5f);
  const float r0 = d0 * inv * w[t] + b[t];
  const float r1 = d1 * inv * w[t + 256] + b[t + 256];
  of[(size_t)r * C_ + t] = r0;
  of[(size_t)r * C_ + t + 256] = r1;
  ob[(size_t)r * C_ + t] = f2bf(r0);
  ob[(size_t)r * C_ + t + 256] = f2bf(r1);
}

// ---------------------------------------------------------------------------
// bf16 MFMA GEMM: out[M,N] = A[M,K](bf16) @ W[N,K](bf16)^T (+bias)(+gelu)(+res)
// 128xBN tile (BN=128 or 64), BK=64, 4 waves (2x2), 64x(BN/2) per wave.
// Double-buffered LDS + counted-vmcnt pipeline (T3+T4).
// PLANQ0 (QKV): guests [ngemm,ngemm+16) run plan_q0 verbatim; guests
//               [ngemm+16,...) convert proj/fc1/fc2 weights to bf16.
// SMAX (proj): guest blocks run plan_softmax verbatim (bit-exact relocation).
// KPACK (QKV): epilogue additionally writes the dense-K panel kb for
//               gn in [512,1024), tok < 1024 (bit-exact relayout).
// ---------------------------------------------------------------------------
template <int BN, int ACT, bool RES, bool OUTBF, bool QSCALE, bool PLANQ0, bool SMAX, bool KPACK>
__global__ __launch_bounds__(256) void gemm_bf_kernel(
    const u16* __restrict__ A, const u16* __restrict__ W,
    const float* __restrict__ bias, const float* __restrict__ resid,
    void* __restrict__ outp, int M, int K, int Nout, int ngemm,
    const float* __restrict__ xnf, const float* __restrict__ qkvwf,
    double* __restrict__ q0o,
    const double* __restrict__ lgtp, double* __restrict__ mxzp,
    const float* __restrict__ ws1, const float* __restrict__ ws2,
    const float* __restrict__ ws3, u16* __restrict__ wd1,
    u16* __restrict__ wd2, u16* __restrict__ wd3,
    u16* __restrict__ kbp) {
  constexpr int WN = BN / 2;       // wave cols: 64 or 32
  constexpr int NJ = WN / 16;      // j-tiles: 4 or 2
  constexpr int BPW = (BN / 8) / 4;  // B chunks per wave: 4 or 2
  __shared__ alignas(16) u16 As[2][128][64];
  __shared__ alignas(16) u16 Bs[2][BN][64];
  if (PLANQ0 && (int)blockIdx.x >= ngemm + 16) {
    // weight-conversion guests (proj/fc1/fc2), parallelism-preserving
    constexpr int n1 = C_ * C_, n2 = F_ * C_;
    const int idx4 = (((int)blockIdx.x - ngemm - 16) * 256 + threadIdx.x) * 4;
    const float* src;
    u16* dst;
    int off;
    if (idx4 < n1) { src = ws1; dst = wd1; off = idx4; }
    else if (idx4 < n1 + n2) { src = ws2; dst = wd2; off = idx4 - n1; }
    else { src = ws3; dst = wd3; off = idx4 - n1 - n2; }
    const float4 v = *(const float4*)(src + off);
    u16x4 r;
    r.x = f2bf(v.x); r.y = f2bf(v.y); r.z = f2bf(v.z); r.w = f2bf(v.w);
    *(u16x4*)(dst + off) = r;
    return;
  }
  if (PLANQ0 && (int)blockIdx.x >= ngemm) {
    const int idx = ((int)blockIdx.x - ngemm) * 256 + threadIdx.x;
    const int b = idx >> 9, hd = idx & 511;
    const float* xr = xnf + (size_t)(b * N_) * C_;
    const float* wr = qkvwf + (size_t)hd * C_;
    double s = 0.0;
    for (int c = 0; c < C_; c += 4) {
      const float4 xv = *(const float4*)(xr + c);
      const float4 wv = *(const float4*)(wr + c);
      s += (double)xv.x * (double)wv.x;
      s += (double)xv.y * (double)wv.y;
      s += (double)xv.z * (double)wv.z;
      s += (double)xv.w * (double)wv.w;
    }
    q0o[idx] = s * 0.125;
    return;
  }
  if (SMAX && (int)blockIdx.x >= ngemm) {
    // plan_softmax body, verbatim (bit-exact relocation)
    __shared__ double red[4];
    const int bh = (int)blockIdx.x - ngemm;
    const int t = threadIdx.x;
    const double* row = lgtp + (size_t)bh * N_;
    double m = -1e300;
    for (int i = t; i < N_; i += 256) m = fmax(m, row[i]);
#pragma unroll
    for (int o = 32; o; o >>= 1) m = fmax(m, __shfl_down(m, o));
    if ((t & 63) == 0) red[t >> 6] = m;
    __syncthreads();
    const double mx = fmax(fmax(red[0], red[1]), fmax(red[2], red[3]));
    __syncthreads();
    double z = 0.0;
    for (int i = t; i < N_; i += 256) z += exp(row[i] - mx);
#pragma unroll
    for (int o = 32; o; o >>= 1) z += __shfl_down(z, o);
    if ((t & 63) == 0) red[t >> 6] = z;
    __syncthreads();
    if (t == 0) {
      mxzp[bh] = mx;
      mxzp[64 + bh] = red[0] + red[1] + red[2] + red[3];
    }
    return;
  }
  const int tid = threadIdx.x;
  const int ny = Nout / BN;
  const int l = xcd_swz(blockIdx.x, ngemm);
  const int m0 = (l / ny) * 128, n0 = (l % ny) * BN;
  const int wave = tid >> 6, lane = tid & 63;
  const int wr = wave >> 1, wc = wave & 1;
  const int lrow = lane & 15, lgrp = lane >> 4;
  const int srow = lane >> 3;                              // row within chunk
  const int soff = (16 * (lane & 7)) ^ (16 * srow);        // swizzled src byte
  const int nk = K >> 6;

  auto stage = [&](int k0, int bufi) {
#pragma unroll
    for (int c = 0; c < 4; ++c) {
      const int q = wave * 4 + c;
      const int row = q * 8 + srow;
      int gm = m0 + row;
      if (gm >= M) gm = M - 1;
      gload_lds16((const char*)(A + (size_t)gm * K + k0) + soff,
                  (char*)&As[bufi][0][0] + (q << 10));
    }
#pragma unroll
    for (int c = 0; c < BPW; ++c) {
      const int q = wave * BPW + c;
      const int row = q * 8 + srow;
      gload_lds16((const char*)(W + (size_t)(n0 + row) * K + k0) + soff,
                  (char*)&Bs[bufi][0][0] + (q << 10));
    }
  };

  f32x4 acc[4][NJ] = {};
  stage(0, 0);
  int buf = 0;
  for (int t = 0; t < nk; ++t) {
    if (t + 1 < nk) {
      stage((t + 1) << 6, buf ^ 1);
      // outstanding = 2*(4+BPW); retire the oldest (4+BPW) = tile t
      if constexpr (BN == 128) asm volatile("s_waitcnt vmcnt(8)" ::: "memory");
      else                     asm volatile("s_waitcnt vmcnt(6)" ::: "memory");
    } else {
      asm volatile("s_waitcnt vmcnt(0)" ::: "memory");
    }
    __builtin_amdgcn_sched_barrier(0);
    __builtin_amdgcn_s_barrier();
    const char* asb = (const char*)&As[buf][0][0];
    const char* bsb = (const char*)&Bs[buf][0][0];
    __builtin_amdgcn_s_setprio(1);
#pragma unroll
    for (int ch = 0; ch < 2; ++ch) {
      bf16x8 af[4], bfv[NJ];
#pragma unroll
      for (int i = 0; i < 4; ++i) {
        const int ra = wr * 64 + i * 16 + lrow;
        const int cb = ch * 64 + lgrp * 16;
        af[i] = *(const bf16x8*)(asb + (ra << 7) + (cb ^ ((ra & 7) << 4)));
      }
#pragma unroll
      for (int j = 0; j < NJ; ++j) {
        const int rb = wc * WN + j * 16 + lrow;
        const int cb = ch * 64 + lgrp * 16;
        bfv[j] = *(const bf16x8*)(bsb + (rb << 7) + (cb ^ ((rb & 7) << 4)));
      }
#pragma unroll
      for (int i = 0; i < 4; ++i)
#pragma unroll
        for (int j = 0; j < NJ; ++j)
          acc[i][j] = __builtin_amdgcn_mfma_f32_16x16x32_bf16(af[i], bfv[j], acc[i][j], 0, 0, 0);
    }
    __builtin_amdgcn_s_setprio(0);
    asm volatile("s_waitcnt lgkmcnt(0)" ::: "memory");
    __builtin_amdgcn_sched_barrier(0);
    __builtin_amdgcn_s_barrier();
    buf ^= 1;
  }
#pragma unroll
  for (int i = 0; i < 4; ++i) {
#pragma unroll
    for (int j = 0; j < NJ; ++j) {
#pragma unroll
      for (int reg = 0; reg < 4; ++reg) {
        const int gm = m0 + wr * 64 + i * 16 + lgrp * 4 + reg;
        if (gm >= M) continue;
        const int gn = n0 + wc * WN + j * 16 + lrow;
        float v = acc[i][j][reg];
        if (bias) v += bias[gn];
        if (ACT == 1) v = 0.5f * v * (1.0f + erff(v * 0.70710678118654752440f));
        if (QSCALE) { if (gn < 512) v *= 0.125f; }
        if (RES) v += resid[(size_t)gm * Nout + gn];
        if (OUTBF) {
          const u16 bv = f2bf(v);
          ((u16*)outp)[(size_t)gm * Nout + gn] = bv;
          if (KPACK) {
            // dense-K panel: same bf16 value, token rows 0..1023 only
            if (gn >= 512 && gn < 1024) {
              const int bb = gm / N_;
              const int tok = gm - bb * N_;
              if (tok < 1024) {
                const int hh = (gn - 512) >> 6, dd = (gn - 512) & 63;
                kbp[((size_t)(bb * NH_ + hh) * 1024 + tok) * 64 + dd] = bv;
              }
            }
          }
        } else {
          ((float*)outp)[(size_t)gm * Nout + gn] = v;
        }
      }
    }
  }
}

// ---------------------------------------------------------------------------
// Pack dense V^T [b][h][64][1024] from qkv_bf (V-only — K packed in the QKV
// GEMM epilogue). 1D grid; blocks >= npack run the plan_u body verbatim.
// ---------------------------------------------------------------------------
__global__ __launch_bounds__(256) void pack_kv_kernel(const u16* __restrict__ qkvbf,
                                                      u16* __restrict__ vb,
                                                      const float* __restrict__ qkvwf,
                                                      const double* __restrict__ q0,
                                                      double* __restrict__ u,
                                                      int npack) {
  if ((int)blockIdx.x >= npack) {
    const int idx = ((int)blockIdx.x - npack) * 256 + threadIdx.x;
    const int b = idx >> 12, h = (idx >> 9) & 7, c = idx & 511;
    double s = 0.0;
    for (int d = 0; d < D_; ++d)
      s += q0[b * 512 + h * 64 + d] * (double)qkvwf[(size_t)(512 + h * 64 + d) * C_ + c];
    u[idx] = s;
    return;
  }
  const int tile = blockIdx.x & 15, h = (blockIdx.x >> 4) & 7, b = (int)blockIdx.x >> 7;
  const int t = threadIdx.x;
  __shared__ u16 Vt[64][72];
  const int krow = tile * 64 + (t >> 2);
  const int dseg = (t & 3) * 16;
  const u16* p = qkvbf + (size_t)(b * N_ + krow) * K3_ + 1024 + h * D_ + dseg;
  const bf16x8 v0 = *(const bf16x8*)p;
  const bf16x8 v1 = *(const bf16x8*)(p + 8);
  *(bf16x8*)(&Vt[t >> 2][dseg]) = v0;
  *(bf16x8*)(&Vt[t >> 2][dseg + 8]) = v1;
  __syncthreads();
  const int d = t >> 2, kseg = (t & 3) * 16;
  bf16x8 o0, o1;
#pragma unroll
  for (int i = 0; i < 8; ++i) o0[i] = (short)Vt[kseg + i][d];
#pragma unroll
  for (int i = 0; i < 8; ++i) o1[i] = (short)Vt[kseg + 8 + i][d];
  u16* vp = vb + ((size_t)(b * NH_ + h) * 64 + d) * 1024 + tile * 64 + kseg;
  *(bf16x8*)vp = o0;
  *(bf16x8*)(vp + 8) = o1;
}

// ---------------------------------------------------------------------------
// MFMA flash attention v12 (r24): swapped QK^T (mfma(K,Q) -> S^T in C-layout)
// puts each thread's P values on its OWN q-row (lrow); the PV A-fragment is
// assembled in-register from 2 neighbor lanes via 16 shfl + 8 selects, so the
// Pl LDS buffer (14.2KB) is GONE: LDS 51.5 -> 37.3KB => 4 blocks/CU
// (24 waves/CU, +33% latency hiding for this latency-bound kernel).
// pf content is bit-identical to the old Pl read; S/O bit-exact (operand-swap
// products identical); only psum's f32 reduction order changes (tolerance
// path). Guest plan_logit unchanged (ul aliases Ks+Vs = 32KB).
// ---------------------------------------------------------------------------
__global__ __launch_bounds__(384) void attn_mfma_kernel(
    const u16* __restrict__ qkvbf, const u16* __restrict__ kb,
    const u16* __restrict__ vb, const float* __restrict__ rpb,
    u16* __restrict__ attnout,
    const float* __restrict__ xnf, const double* __restrict__ uu,
    double* __restrict__ lgt, int nattn) {
  __shared__ alignas(16) u16 Ks[2][64][64];   // 16KB, XOR-swizzled storage
  __shared__ alignas(16) u16 Vs[2][64][64];   // 16KB, XOR-swizzled storage
  __shared__ u16 tab[36 * 63];                // 4.5KB bf16 bias table
  if ((int)blockIdx.x >= nattn) {
    // plan_logit guest: 6 blocks/batch; thread = (row rloc, head-group hg)
    double* ul = (double*)&Ks[0][0][0];       // 4096 f64 = 32KB (Ks+Vs)
    const int lb = (int)blockIdx.x - nattn;   // [0, 48)
    const int b = lb / 6, part = lb % 6;
    for (int i = threadIdx.x; i < 4096; i += 384)
      ul[i] = uu[(size_t)b * 4096 + i];
    __syncthreads();
    const int rloc = threadIdx.x % 192;
    const int hg = threadIdx.x / 192;         // 0 or 1 (wave-uniform)
    const int m = part * 192 + rloc;
    if (m >= N_) return;
    const float* xr = xnf + (size_t)(b * N_ + m) * C_;
    const double* ulh = ul + hg * 4 * 512;
    double s[4] = {};
    for (int c = 0; c < C_; c += 4) {
      const float4 xv = *(const float4*)(xr + c);
#pragma unroll
      for (int hh = 0; hh < 4; ++hh) {
        s[hh] += (double)xv.x * ulh[hh * 512 + c];
        s[hh] += (double)xv.y * ulh[hh * 512 + c + 1];
        s[hh] += (double)xv.z * ulh[hh * 512 + c + 2];
        s[hh] += (double)xv.w * ulh[hh * 512 + c + 3];
      }
    }
#pragma unroll
    for (int hh = 0; hh < 4; ++hh)
      lgt[(size_t)(b * 8 + hg * 4 + hh) * N_ + m] = s[hh];
    return;
  }
  const int l = xcd_swz(blockIdx.x, nattn);  // logical = (b*8+h)*11 + qt
  const int qt = l % 11;
  const int bh = l / 11;
  const int h = bh & 7, b = bh >> 3;
  const int wave = threadIdx.x >> 6, lane = threadIdx.x & 63;
  const int lrow = lane & 15, lgrp = lane >> 4;
  const int qblk = qt * 96;
  const int qbase = qblk + wave * 16;

  const u16* kpan = kb + (size_t)(b * NH_ + h) * 1024 * 64;
  const u16* vpan = vb + (size_t)(b * NH_ + h) * 64 * 1024;

  // ---- issue async stage of tile 0 (waves 0-3: K, waves 4-5: V) ----
  if (wave < 4) {
#pragma unroll
    for (int c = 0; c < 2; ++c) {
      const int q = wave * 2 + c;
      const int Y = (q << 10) | (lane << 4);
      const int Ys = Y ^ (((Y >> 7) & 7) << 4);
      gload_lds16((const char*)kpan + Ys, (char*)&Ks[0][0][0] + (q << 10));
    }
  } else {
#pragma unroll
    for (int c = 0; c < 4; ++c) {
      const int q = (wave - 4) * 4 + c;
      const int Y = (q << 10) | (lane << 4);
      const int Ys = Y ^ (((Y >> 7) & 7) << 4);
      const int row = Y >> 7;
      gload_lds16((const char*)vpan + (size_t)row * 2048 + (Ys & 127),
                  (char*)&Vs[0][0][0] + (q << 10));
    }
  }

  // ---- stage rpb sub-table (all threads; bf16) ----
  const int qimin = max(qblk - 1, 0);
  const int qimax = min(qblk + 94, 1023);
  const int qymin = qimin >> 5;
  const int qymax = qimax >> 5;
  const int nrows = qymax - qymin + 32;   // dy in [qymin-31, qymax]  (<=36)
  for (int i = threadIdx.x; i < nrows * 63; i += 384)
    tab[i] = f2bf(rpb[(size_t)(qymin * 63 + i) * NH_ + h]);

  // Q fragments (pre-scaled by 1/8 in the QKV GEMM epilogue)
  bf16x8 qf[2];
  {
    const int qrow = min(qbase + lrow, N_ - 1);
    const u16* qp = qkvbf + (size_t)(b * N_ + qrow) * K3_ + h * D_;
    qf[0] = *(const bf16x8*)(qp + lgrp * 8);
    qf[1] = *(const bf16x8*)(qp + 32 + lgrp * 8);
  }

  const float bias0 = rpb[h];

  // Per-thread q-row anchor (S^T layout: this thread's P row is lrow)
  const int qrow_t = min(qbase + lrow, N_ - 1);
  const bool qcls_t = (qrow_t == 0);
  const int qi_t = max(qrow_t - 1, 0);
  const int Aloc_t = ((qi_t >> 5) - qymin + 31) * 63 + (qi_t & 31) + 31;

  // P-redistribution source lanes (4-block owners for this dest lane)
  const int srcA = (2 * (lgrp & 1)) * 16 + lrow;
  const int srcB = srcA + 16;
  const bool hiT = (lgrp & 2) != 0;

  float psum_t = 0.f;
  f32x4 o[4] = {};

  __syncthreads();  // full drain: tile-0 stage + tab complete, visible to all

  for (int t = 0; t < 16; ++t) {
    const int buf = t & 1;
    // ---- issue async stage of tile t+1 into buf^1 (role-split) ----
    if (t < 15) {
      const int keybase2 = (t + 1) * 64;
      if (wave < 4) {
#pragma unroll
        for (int c = 0; c < 2; ++c) {
          const int q = wave * 2 + c;
          const int Y = (q << 10) | (lane << 4);
          const int Ys = Y ^ (((Y >> 7) & 7) << 4);
          gload_lds16((const char*)kpan + ((size_t)keybase2 << 7) + Ys,
                      (char*)&Ks[buf ^ 1][0][0] + (q << 10));
        }
        // outstanding: K(t) 2 + K(t+1) 2 -> retire the 2 oldest = K(t)
        asm volatile("s_waitcnt vmcnt(2)" ::: "memory");
      } else {
#pragma unroll
        for (int c = 0; c < 4; ++c) {
          const int q = (wave - 4) * 4 + c;
          const int Y = (q << 10) | (lane << 4);
          const int Ys = Y ^ (((Y >> 7) & 7) << 4);
          const int row = Y >> 7;
          gload_lds16((const char*)vpan + (size_t)row * 2048 + ((size_t)keybase2 << 1) + (Ys & 127),
                      (char*)&Vs[buf ^ 1][0][0] + (q << 10));
        }
        // outstanding: V(t) 4 + V(t+1) 4 -> retire the 4 oldest = V(t)
        asm volatile("s_waitcnt vmcnt(4)" ::: "memory");
      }
    } else {
      asm volatile("s_waitcnt vmcnt(0)" ::: "memory");
    }
    __builtin_amdgcn_sched_barrier(0);
    __builtin_amdgcn_s_barrier();

    const int keybase = t * 64;
    const char* ksb = (const char*)&Ks[buf][0][0];
    const char* vsb = (const char*)&Vs[buf][0][0];

    // ---- S^T = K Q^T (swapped operands; K tile from swizzled LDS) ----
    f32x4 s[4] = {};
    __builtin_amdgcn_s_setprio(1);
#pragma unroll
    for (int tile = 0; tile < 4; ++tile) {
      const int row = tile * 16 + lrow;
      const int sw = (row & 7) << 4;
      const bf16x8 kf0 = *(const bf16x8*)(ksb + ((row * 128 + lgrp * 16) ^ sw));
      const bf16x8 kf1 = *(const bf16x8*)(ksb + ((row * 128 + 64 + lgrp * 16) ^ sw));
      s[tile] = __builtin_amdgcn_mfma_f32_16x16x32_bf16(kf0, qf[0], s[tile], 0, 0, 0);
      s[tile] = __builtin_amdgcn_mfma_f32_16x16x32_bf16(kf1, qf[1], s[tile], 0, 0, 0);
    }
    __builtin_amdgcn_s_setprio(0);
    // ---- bias + exp: thread holds P[q=lrow][key=tile*16+lgrp*4+reg] ----
    unsigned pk[4][2];
#pragma unroll
    for (int tile = 0; tile < 4; ++tile) {
      float p4[4];
#pragma unroll
      for (int reg = 0; reg < 4; ++reg) {
        const int key = keybase + tile * 16 + lgrp * 4 + reg;
        const int ki = max(key - 1, 0);
        const int kpart = (ki >> 5) * 63 + (ki & 31);
        const bool kcls = (key == 0);
        const float bias = (qcls_t || kcls) ? bias0 : bf2f(tab[Aloc_t - kpart]);
        const float p = __expf(s[tile][reg] + bias);
        psum_t += p;
        p4[reg] = p;
      }
      pk[tile][0] = (unsigned)f2bf(p4[0]) | ((unsigned)f2bf(p4[1]) << 16);
      pk[tile][1] = (unsigned)f2bf(p4[2]) | ((unsigned)f2bf(p4[3]) << 16);
    }
    // ---- redistribute 4-key packs to PV A-fragment owners (16 shfl) ----
    unsigned oA[4][2], oB[4][2];
#pragma unroll
    for (int T = 0; T < 4; ++T) {
#pragma unroll
      for (int p = 0; p < 2; ++p) {
        oA[T][p] = (unsigned)__shfl((int)pk[T][p], srcA);
        oB[T][p] = (unsigned)__shfl((int)pk[T][p], srcB);
      }
    }
    // ---- O += P V (pf assembled in-register; V from swizzled LDS) ----
    __builtin_amdgcn_s_setprio(1);
#pragma unroll
    for (int ch = 0; ch < 2; ++ch) {
      const unsigned w0 = hiT ? oA[ch * 2 + 1][0] : oA[ch * 2][0];
      const unsigned w1 = hiT ? oA[ch * 2 + 1][1] : oA[ch * 2][1];
      const unsigned w2 = hiT ? oB[ch * 2 + 1][0] : oB[ch * 2][0];
      const unsigned w3 = hiT ? oB[ch * 2 + 1][1] : oB[ch * 2][1];
      bf16x8 pf;
      pf[0] = (short)(w0 & 0xffff); pf[1] = (short)(w0 >> 16);
      pf[2] = (short)(w1 & 0xffff); pf[3] = (short)(w1 >> 16);
      pf[4] = (short)(w2 & 0xffff); pf[5] = (short)(w2 >> 16);
      pf[6] = (short)(w3 & 0xffff); pf[7] = (short)(w3 >> 16);
#pragma unroll
      for (int dt = 0; dt < 4; ++dt) {
        const int row = dt * 16 + lrow;
        const bf16x8 vf = *(const bf16x8*)(vsb + ((row * 128 + ch * 64 + lgrp * 16) ^ ((row & 7) << 4)));
        o[dt] = __builtin_amdgcn_mfma_f32_16x16x32_bf16(pf, vf, o[dt], 0, 0, 0);
      }
    }
    __builtin_amdgcn_s_setprio(0);
    // all LDS reads of buf must retire before any wave's next stage overwrites it
    asm volatile("s_waitcnt lgkmcnt(0)" ::: "memory");
    __builtin_amdgcn_sched_barrier(0);
    __builtin_amdgcn_s_barrier();
  }

  // ---- row-sum: reduce psum over the 4 lgrp lanes sharing this lrow ----
  psum_t += __shfl_xor(psum_t, 16);
  psum_t += __shfl_xor(psum_t, 32);

  // ---- tail: key 1024 (image key 1023: ky=31, kx=31) ----
  float ptail;
  {
    const u16* k1p = qkvbf + (size_t)(b * N_ + 1024) * K3_ + 512 + h * D_;
    const bf16x8 k10 = *(const bf16x8*)(k1p + lgrp * 8);
    const bf16x8 k11 = *(const bf16x8*)(k1p + 32 + lgrp * 8);
    float part = 0.f;
#pragma unroll
    for (int i = 0; i < 8; ++i)
      part += bf2f((u16)qf[0][i]) * bf2f((u16)k10[i]) + bf2f((u16)qf[1][i]) * bf2f((u16)k11[i]);
    part += __shfl_xor(part, 16);
    part += __shfl_xor(part, 32);
    // anchor for q-row = this lane's lrow (row-major tail mapping)
    const float btail = (qrow_t == 0) ? bias0 : bf2f(tab[Aloc_t - 31 * 63 - 31]);
    ptail = __expf(part + btail);
  }

  float v1024[4];
#pragma unroll
  for (int dt = 0; dt < 4; ++dt)
    v1024[dt] = bf2f(qkvbf[(size_t)(b * N_ + 1024) * K3_ + 1024 + h * D_ + dt * 16 + lrow]);

#pragma unroll
  for (int reg = 0; reg < 4; ++reg) {
    const float pr = __shfl(ptail, lgrp * 4 + reg);
    const float ps = __shfl(psum_t, lgrp * 4 + reg);
    const int qrow = qbase + lgrp * 4 + reg;
    if (qrow >= N_) continue;
    const float inv = 1.0f / (ps + pr);
    u16* op = attnout + (size_t)(b * N_ + qrow) * C_ + h * D_ + lrow;
#pragma unroll
    for (int dt = 0; dt < 4; ++dt)
      op[dt * 16] = f2bf((o[dt][reg] + pr * v1024[dt]) * inv);
  }
}

// ---------------------------------------------------------------------------
// Plan path (f64) — exact discrete indices. q0 fused into QKV GEMM; u fused
// into pack_kv; logit fused into attn; softmax fused into proj.
// ---------------------------------------------------------------------------
__global__ __launch_bounds__(256) void plan_cls_kernel(const double* __restrict__ lgt,
                                                       const double* __restrict__ mxz,
                                                       double* __restrict__ cls) {
  const int idx = blockIdx.x * 256 + threadIdx.x;
  const int b = idx >> 10, i = idx & 1023;
  double s = 0.0;
  for (int h = 0; h < 8; ++h) {
    const int bh = b * 8 + h;
    s += exp(lgt[(size_t)bh * N_ + 1 + i] - mxz[bh]) / mxz[64 + bh];
  }
  cls[idx] = s / 8.0;
}

// ---------------------------------------------------------------------------
// JAX threefry2x32 (20 rounds), exact
// ---------------------------------------------------------------------------
__device__ inline void tf2x32(unsigned k0, unsigned k1, unsigned& x0, unsigned& x1) {
  const unsigned ks2 = k0 ^ k1 ^ 0x1BD11BDAu;
  const int r0[4] = {13, 15, 26, 6};
  const int r1[4] = {17, 29, 16, 24};
  x0 += k0; x1 += k1;
#pragma unroll
  for (int i = 0; i < 4; ++i) { x0 += x1; x1 = (x1 << r0[i]) | (x1 >> (32 - r0[i])); x1 ^= x0; }
  x0 += k1; x1 += ks2 + 1u;
#pragma unroll
  for (int i = 0; i < 4; ++i) { x0 += x1; x1 = (x1 << r1[i]) | (x1 >> (32 - r1[i])); x1 ^= x0; }
  x0 += ks2; x1 += k0 + 2u;
#pragma unroll
  for (int i = 0; i < 4; ++i) { x0 += x1; x1 = (x1 << r0[i]) | (x1 >> (32 - r0[i])); x1 ^= x0; }
  x0 += k0; x1 += k1 + 3u;
#pragma unroll
  for (int i = 0; i < 4; ++i) { x0 += x1; x1 = (x1 << r1[i]) | (x1 >> (32 - r1[i])); x1 ^= x0; }
  x0 += k1; x1 += ks2 + 4u;
#pragma unroll
  for (int i = 0; i < 4; ++i) { x0 += x1; x1 = (x1 << r0[i]) | (x1 >> (32 - r0[i])); x1 ^= x0; }
  x0 += ks2; x1 += k0 + 5u;
}

// ---------------------------------------------------------------------------
// Fused plan tail v2: register bitonic sort (wave-internal phases j<64 via
// shfl_xor, comparator EXACTLY preserved -> bit-identical permutation; only
// 10 cross-wave phases touch LDS) + batched counts (per-batch f64 reduction
// TREES preserved exactly; barriers 48 -> 3). Threefry tail unchanged.
// ---------------------------------------------------------------------------
__global__ __launch_bounds__(1024) void plan_tail_kernel(
    const double* __restrict__ cls, const float* __restrict__ tw,
    int* __restrict__ scal, int* __restrict__ sel, int* __restrict__ ii) {
  __shared__ double sv[1024];
  __shared__ int sid[1024];
  __shared__ double dred8[8][16];
  __shared__ double mred8[8][16];
  __shared__ int ired8[8][16];
  __shared__ double stats2[8][2];
  __shared__ int sc3[3];
  const int t = threadIdx.x;
  const int wid = t >> 6, lane = t & 63;

  // ---- bitonic sort (batch 0), values in registers ----
  double v = cls[t];
  int idx = t;
  for (int k = 2; k <= 1024; k <<= 1) {
    for (int j = k >> 1; j > 0; j >>= 1) {
      const bool desc = ((t & k) == 0);     // same for both partners (j < k)
      const bool iAmLow = (t & j) == 0;
      double ov;
      int oi;
      if (j >= 64) {
        sv[t] = v;
        sid[t] = idx;
        __syncthreads();
        ov = sv[t ^ j];
        oi = sid[t ^ j];
        __syncthreads();
      } else {
        ov = __shfl_xor(v, j);
        oi = __shfl_xor(idx, j);
      }
      // myFirst == original aFirst evaluated from this thread's perspective
      const bool myFirst = (v > ov) || (v == ov && idx < oi);
      const bool keepMine = desc ? (iAmLow == myFirst) : (iAmLow != myFirst);
      if (!keepMine) { v = ov; idx = oi; }
    }
  }
  sel[t] = idx;

  // ---- counts: all 8 batches, trees EXACTLY as the split version ----
  double val8[8];
#pragma unroll
  for (int b = 0; b < 8; ++b) val8[b] = cls[b * 1024 + t];
#pragma unroll
  for (int b = 0; b < 8; ++b) {
    double s = val8[b];
#pragma unroll
    for (int o = 32; o; o >>= 1) s += __shfl_down(s, o);
    if (lane == 0) dred8[b][wid] = s;
    double mv = val8[b];
#pragma unroll
    for (int o = 32; o; o >>= 1) mv = fmax(mv, __shfl_down(mv, o));
    if (lane == 0) mred8[b][wid] = mv;
  }
  __syncthreads();
  if (t < 8) {
    double tot = 0;
    for (int i = 0; i < 16; ++i) tot += dred8[t][i];
    stats2[t][0] = tot / 1024.0;
    double mx = mred8[t][0];
    for (int i = 1; i < 16; ++i) mx = fmax(mx, mred8[t][i]);
    stats2[t][1] = mx;
  }
  __syncthreads();
#pragma unroll
  for (int b = 0; b < 8; ++b) {
    int c = (val8[b] >= stats2[b][0] && val8[b] <= stats2[b][1]) ? 1 : 0;
#pragma unroll
    for (int o = 32; o; o >>= 1) c += __shfl_down(c, o);
    if (lane == 0) ired8[b][wid] = c;
  }
  __syncthreads();

  if (t == 0) {
    int maxv = 0;
    double sum = 0.0;
    for (int b = 0; b < 8; ++b) {
      int cc = 0;
      for (int i = 0; i < 16; ++i) cc += ired8[b][i];
      maxv = max(maxv, cc);
      sum += (double)cc;
    }
    const double T = sum / 8.0;
    const double sig = 1.0 / (1.0 + exp(-((double)maxv - T) / 8.0));
    const double keepf = 1024.0 * (0.6 + (1.0 - 0.6) * sig);
    const int keep = __double2int_rn(keepf);
    const int remaining = 1024 - keep;
    const float t0 = tw[0], t1 = tw[1];
    const float mw = fmaxf(t0, t1);
    const float e0 = expf(t0 - mw), e1 = expf(t1 - mw);
    const float w0 = e0 / (e0 + e1);
    const int nt = (int)(w0 * (float)remaining);
    const int ni = remaining - nt;
    scal[0] = keep; scal[1] = nt; scal[2] = ni;
    sc3[0] = keep; sc3[1] = nt; sc3[2] = ni;
  }
  __syncthreads();

  const int ni = sc3[2];
  const int size = 8 * ni;
  const unsigned span = 1023u;
  unsigned mult = 65536u % span;
  mult = (mult * mult) % span;
  unsigned f0 = 0u, f1 = 1u;
  tf2x32(0u, 1234u, f0, f1);
#if PARTITIONABLE
  unsigned k1a = 0u, k1b = 0u;
  tf2x32(f0, f1, k1a, k1b);
  unsigned k2a = 0u, k2b = 1u;
  tf2x32(f0, f1, k2a, k2b);
  for (int i = t; i < size; i += 1024) {
    unsigned h0 = 0u, h1 = (unsigned)i;
    tf2x32(k1a, k1b, h0, h1);
    const unsigned hb = h0 ^ h1;
    unsigned l0 = 0u, l1 = (unsigned)i;
    tf2x32(k2a, k2b, l0, l1);
    const unsigned lb = l0 ^ l1;
    ii[i] = (int)(((hb % span) * mult + (lb % span)) % span);
  }
#else
  unsigned a0 = 0u, a1 = 2u;
  tf2x32(f0, f1, a0, a1);
  unsigned b0 = 1u, b1 = 3u;
  tf2x32(f0, f1, b0, b1);
  const int half = size >> 1;
  for (int i = t; i < half; i += 1024) {
    unsigned h0 = (unsigned)i, h1 = (unsigned)(i + half);
    tf2x32(a0, b0, h0, h1);
    unsigned l0 = (unsigned)i, l1 = (unsigned)(i + half);
    tf2x32(a1, b1, l0, l1);
    ii[i]        = (int)(((h0 % span) * mult + (l0 % span)) % span);
    ii[i + half] = (int)(((h1 % span) * mult + (l1 % span)) % span);
  }
#endif
}

// ---------------------------------------------------------------------------
// Fused assemble + LN2: x1 = x + gathered_src; x1n_bf = LN(x1)
// ---------------------------------------------------------------------------
__global__ __launch_bounds__(256) void assemble_ln_kernel(
    const float* __restrict__ x, const float* __restrict__ xn,
    const float* __restrict__ xo, const int* __restrict__ scal,
    const int* __restrict__ sel, const int* __restrict__ ii,
    const float* __restrict__ w, const float* __restrict__ bb,
    float* __restrict__ x1, u16* __restrict__ ob) {
  __shared__ float red[4];
  const int blk = blockIdx.x;
  const int b = blk / N_, tok = blk % N_;
  const int keep = scal[0], nt = scal[1], ni = scal[2];
  const float* src;
  if (tok == 0) {
    src = xo + (size_t)(b * N_) * C_;
  } else if (tok <= keep) {
    src = xo + (size_t)(b * N_ + 1 + sel[tok - 1]) * C_;
  } else if (tok <= keep + nt) {
    src = xn + (size_t)(b * N_ + 1) * C_;
  } else {
    const int j = tok - 1 - keep - nt;
    src = xn + (size_t)(b * N_ + 2 + ii[b * ni + j]) * C_;
  }
  const int t = threadIdx.x;
  const size_t o = (size_t)blk * C_;
  const float v0 = x[o + t] + src[t];
  const float v1 = x[o + t + 256] + src[t + 256];
  x1[o + t] = v0;
  x1[o + t + 256] = v1;
  float s = v0 + v1;
#pragma unroll
  for (int of = 32; of; of >>= 1) s += __shfl_down(s, of);
  if ((t & 63) == 0) red[t >> 6] = s;
  __syncthreads();
  const float mean = (red[0] + red[1] + red[2] + red[3]) * (1.0f / 512.0f);
  __syncthreads();
  const float d0 = v0 - mean, d1 = v1 - mean;
  float q = d0 * d0 + d1 * d1;
#pragma unroll
  for (int of = 32; of; of >>= 1) q += __shfl_down(q, of);
  if ((t & 63) == 0) red[t >> 6] = q;
  __syncthreads();
  const float var = (red[0] + red[1] + red[2] + red[3]) * (1.0f / 512.0f);
  const float inv = 1.0f / sqrtf(var + 1e-5f);
  ob[o + t] = f2bf(d0 * inv * w[t] + bb[t]);
  ob[o + t + 256] = f2bf(d1 * inv * w[t + 256] + bb[t + 256]);
}

// ---------------------------------------------------------------------------
// Host launcher
// ---------------------------------------------------------------------------
extern "C" void kernel_launch(void* const* d_in, const int* in_sizes, int n_in,
                              void* d_out, int out_size, void* d_ws, size_t ws_size,
                              hipStream_t stream) {
  (void)in_sizes; (void)n_in; (void)out_size; (void)ws_size;
  const float* x     = (const float*)d_in[0];
  const float* ln1w  = (const float*)d_in[1];
  const float* ln1b  = (const float*)d_in[2];
  const float* qkvw  = (const float*)d_in[3];
  const float* rpb   = (const float*)d_in[4];
  const float* projw = (const float*)d_in[5];
  const float* projb = (const float*)d_in[6];
  const float* tw    = (const float*)d_in[7];
  const float* ln2w  = (const float*)d_in[8];
  const float* ln2b  = (const float*)d_in[9];
  const float* fc1w  = (const float*)d_in[10];
  const float* fc1b  = (const float*)d_in[11];
  const float* fc2w  = (const float*)d_in[12];
  const float* fc2b  = (const float*)d_in[13];
  float* out = (float*)d_out;
  char* base = (char*)d_ws;

  float* xn       = (float*)(base + BYTE_XN);
  u16*   qkv_bf   = (u16*)(base + BYTE_QKVBF);
  u16*   xn_bf    = (u16*)(base + BYTE_XNBF);
  u16*   hbuf     = (u16*)(base + BYTE_HBUF);
  u16*   wq_bf    = (u16*)(base + BYTE_WTAIL);
  u16*   wp_bf    = wq_bf + K3_ * C_;
  u16*   w1_bf    = wp_bf + C_ * C_;
  u16*   w2_bf    = w1_bf + F_ * C_;
  u16*   attn_bf  = (u16*)(base + BYTE_ATTNBF);
  u16*   x1n_bf   = (u16*)(base + BYTE_X1NBF);
  float* xo       = (float*)(base + BYTE_XO);
  u16*   kbuf     = (u16*)(base + BYTE_X1);
  u16*   vbuf     = kbuf + (size_t)B_ * NH_ * 1024 * 64;
  float* x1       = (float*)(base + BYTE_X1);

  char* pb = base + PLAN_BYTE;
  double* q0  = (double*)pb;
  double* u   = q0 + 4096;
  double* lgt = u + 32768;
  double* mxz = lgt + 65600;
  double* cls = mxz + 128;
  int* counts = (int*)(cls + 8192);
  int* scal   = counts + 8;
  int* sel    = scal + 4;
  int* iibuf  = sel + 1024;

  // 1. fused LN1 (-> xn f32 + xn_bf) + QKV-weight conversion only
  ln_wconv_kernel<<<ROWS_ + WQ_BLKS_, 256, 0, stream>>>(
      x, ln1w, ln1b, xn, xn_bf, qkvw, wq_bf);
  // 2. QKV GEMM (BN=128, grid 780, KPACK: dense-K written from epilogue)
  //    + 16 plan_q0 guests + 2304 weight-conv guests (proj/fc1/fc2)
  gemm_bf_kernel<128, 0, false, true, true, true, false, true>
      <<<65 * 12 + 16 + WTAIL_BLKS_, 256, 0, stream>>>(
      xn_bf, wq_bf, nullptr, nullptr, qkv_bf, ROWS_, C_, K3_, 65 * 12,
      xn, qkvw, q0, nullptr, nullptr,
      projw, fc1w, fc2w, wp_bf, w1_bf, w2_bf, kbuf);
  // 3. dense V^T pack (V-only) + 128 fused plan_u blocks (bit-exact)
  pack_kv_kernel<<<1024 + 128, 256, 0, stream>>>(
      qkv_bf, vbuf, qkvw, q0, u, 1024);
  // 4. MFMA flash attention v12 (704 blocks, LDS 37.3KB -> 4 blocks/CU)
  //    + 48 fused plan_logit blocks (unchanged)
  attn_mfma_kernel<<<11 * NH_ * B_ + 48, 384, 0, stream>>>(
      qkv_bf, kbuf, vbuf, rpb, attn_bf, xn, u, lgt, 11 * NH_ * B_);
  // 5. proj (BN=64, grid 520) + 64 fused plan_softmax blocks (bit-exact;
  //    584 <= 768 single fill)
  gemm_bf_kernel<64, 0, false, false, false, false, true, false><<<65 * 8 + 64, 256, 0, stream>>>(
      attn_bf, wp_bf, projb, nullptr, xo, ROWS_, C_, C_, 65 * 8,
      nullptr, nullptr, nullptr, lgt, mxz,
      nullptr, nullptr, nullptr, nullptr, nullptr, nullptr, nullptr);
  // 6. plan cls (needs mxz) -> cls  [32 blocks: parallelism-preserving]
  plan_cls_kernel<<<32, 256, 0, stream>>>(lgt, mxz, cls);
  // 7. plan tail (sort + counts + threefry) -> scal/sel/ii
  plan_tail_kernel<<<1, 1024, 0, stream>>>(cls, tw, scal, sel, iibuf);
  // 8. fused assemble + residual + LN2 -> x1 f32 + x1n_bf
  assemble_ln_kernel<<<ROWS_, 256, 0, stream>>>(
      x, xn, xo, scal, sel, iibuf, ln2w, ln2b, x1, x1n_bf);
  // 9. FC1 + exact GELU -> hbuf bf16 — BN=128, grid 1040
  gemm_bf_kernel<128, 1, false, true, false, false, false, false><<<65 * 16, 256, 0, stream>>>(
      x1n_bf, w1_bf, fc1b, nullptr, hbuf, ROWS_, C_, F_, 65 * 16,
      nullptr, nullptr, nullptr, nullptr, nullptr,
      nullptr, nullptr, nullptr, nullptr, nullptr, nullptr, nullptr);
  // 10. FC2 + bias + residual -> out f32 — BN=64, grid 520
  gemm_bf_kernel<64, 0, true, false, false, false, false, false><<<65 * 8, 256, 0, stream>>>(
      hbuf, w2_bf, fc2b, x1, out, ROWS_, F_, C_, 65 * 8,
      nullptr, nullptr, nullptr, nullptr, nullptr,
      nullptr, nullptr, nullptr, nullptr, nullptr, nullptr, nullptr);
}